// Round 1
// baseline (566.397 us; speedup 1.0000x reference)
//
#include <hip/hip_runtime.h>
#include <hip/hip_bf16.h>

typedef __hip_bfloat16 bf16;
typedef unsigned short ushort_t;
typedef __attribute__((ext_vector_type(8))) short short8;
typedef __attribute__((ext_vector_type(4))) float fx4;

#define BB 32
#define NN 128
#define FF 9
#define EE 8
#define HH 128
#define HD 256
#define NHEAD 4
#define DHEAD 64

__device__ __forceinline__ float us2f(ushort_t u) {
    return __uint_as_float(((unsigned int)u) << 16);
}
// truncation split: hi = trunc16(v), lo = v - hi (lo exact in f32)
__device__ __forceinline__ ushort_t f2us_tr(float f) {
    return (ushort_t)(__float_as_uint(f) >> 16);
}

__global__ void TransformerConvNet_85315230367963_kernel() {}

__global__ void k_sent(float* out, float val) {
    out[blockIdx.x * 256 + threadIdx.x] = val;
}

__global__ void k_zero(float* p) {
    p[blockIdx.x * 256 + threadIdx.x] = 0.f;
}

// ---------------- K1: adjv + adjvT (masked) ----------------
__global__ void k_adjv(const float* adj, float* adjv, float* adjvT) {
    int b = blockIdx.x;            // 32
    const float* src = adj + b * NN * NN;
    float* d1 = adjv + b * NN * NN;
    float* d2 = adjvT + b * NN * NN;
    for (int i = threadIdx.x; i < NN * NN; i += 256) {
        float a = src[i];
        d1[i] = (a > 0.f && a < 1.0f) ? a : 0.f;
    }
    for (int i = threadIdx.x; i < NN * NN; i += 256) {
        int t = i >> 7, s = i & 127;
        float a = src[s * NN + t];
        d2[i] = (a > 0.f && a < 1.0f) ? a : 0.f;   // adjvT[t][s]
    }
}

// ---------------- K2: base[bs][c] = src(bs) @ W1[:17] + b1 ----------------
__global__ void k_base(const float* nf, const int* et, const float* emb,
                       const float* W1, const float* b1, float* base) {
    int bs = blockIdx.x;
    int c = threadIdx.x;
    int ty = et[bs];
    float acc = b1[c];
    for (int f = 0; f < FF; f++)
        acc += nf[bs * FF + f] * W1[f * HH + c];
    for (int e = 0; e < EE; e++)
        acc += emb[ty * EE + e] * W1[(FF + e) * HH + c];
    base[bs * HH + c] = acc;
}

// ---------------- K_prep: Wh' = g1*Wh split bf16 hi/lo, swizzled ----------
__global__ void k_prep(const float* Wh, const float* g1, const float* be1,
                       const float* bh, ushort_t* BhiG, ushort_t* BloG,
                       float* W1s, float* cbv) {
    int n = blockIdx.x;      // 0..127
    int t = threadIdx.x;     // 0..63
    int sw = 8 * (n & 15);
    float s1 = 0.f, s2 = 0.f;
    for (int kk = 0; kk < 2; kk++) {
        int k = t + kk * 64;
        float w = Wh[k * HH + n];
        float wp = g1[k] * w;
        ushort_t hb = f2us_tr(wp);
        float lo = wp - us2f(hb);
        BhiG[n * HH + (k ^ sw)] = hb;
        BloG[n * HH + (k ^ sw)] = f2us_tr(lo);
        s1 += wp;
        s2 += be1[k] * w;
    }
    for (int m = 1; m < 64; m <<= 1) {
        s1 += __shfl_xor(s1, m);
        s2 += __shfl_xor(s2, m);
    }
    if (t == 0) { W1s[n] = s1; cbv[n] = s2 + bh[n]; }
}

// ---------------- K_prepw: split 4 qkvs weight mats into bf16 hi/lo -------
__global__ void k_prepw(const float* W0, const float* W1p, const float* W2p,
                        const float* W3p, int IN, ushort_t* Whi, ushort_t* Wlo) {
    int blk = blockIdx.x;             // 4*256
    int mat = blk >> 8, n = blk & 255;
    const float* W = (mat == 0) ? W0 : (mat == 1) ? W1p : (mat == 2) ? W2p : W3p;
    ushort_t* hi = Whi + mat * 256 * IN;
    ushort_t* lo = Wlo + mat * 256 * IN;
    int sw = 8 * (n & 15);
    for (int k = threadIdx.x; k < IN; k += 64) {
        float w = W[k * HD + n];
        ushort_t hb = f2us_tr(w);
        float l = w - us2f(hb);
        hi[n * IN + (k ^ sw)] = hb;
        lo[n * IN + (k ^ sw)] = f2us_tr(l);
    }
}

// ---------------- K3: embed conv, MFMA, SWAPPED operands ------------------
// D[n][t] = Wh'^T (from LDS, A-operand) x  LN1(h1)^T (registers, B-operand).
// B cols = t = nl  -> LN1/LN2 stats live in the right lanes: no broadcasts,
// LN2 reduce = in-lane + 2 shuffles. LN1 folded into B pre-split; cb folded
// into G init; mask/r2/gh/beh folded into running scalars + epilogue.
__global__ void __launch_bounds__(256, 2) k_econv_mfma(
    const float* adjv, const float* base, const float* W1,
    const ushort_t* BhiG, const ushort_t* BloG,
    const float* W1s_unused, const float* cbv,
    const float* ghp, const float* behp, float* x0)
{
    __shared__ __align__(16) ushort_t Phi[HH * HH];
    __shared__ __align__(16) ushort_t Plo[HH * HH];

    int blk = blockIdx.x;
    int b  = blk >> 4;
    int tt = (blk >> 1) & 7;
    int sh = blk & 1;
    int t0 = tt * 16;
    int tid = threadIdx.x;
    int wv  = tid >> 6;
    int lane = tid & 63;
    int nl = lane & 15;
    int quad = lane >> 4;

    {
        const uint4* srcH = (const uint4*)BhiG;
        const uint4* srcL = (const uint4*)BloG;
        uint4* dstH = (uint4*)Phi;
        uint4* dstL = (uint4*)Plo;
        for (int i = tid; i < HH * HH / 8; i += 256) {
            dstH[i] = srcH[i];
            dstL[i] = srcL[i];
        }
    }

    // per-lane constants: cb[n] as float4 per tile (n = tile*16 + quad*4 + r)
    float4 cb4[8];
#pragma unroll
    for (int tile = 0; tile < 8; tile++)
        cb4[tile] = *(const float4*)(cbv + tile * 16 + quad * 4);

    float w17v[4][8];
#pragma unroll
    for (int st = 0; st < 4; st++) {
        const float* p = W1 + 17 * HH + quad * 8 + 32 * st;
        float4 a = *(const float4*)p;
        float4 bq = *(const float4*)(p + 4);
        w17v[st][0] = a.x;  w17v[st][1] = a.y;  w17v[st][2] = a.z;  w17v[st][3] = a.w;
        w17v[st][4] = bq.x; w17v[st][5] = bq.y; w17v[st][6] = bq.z; w17v[st][7] = bq.w;
    }

    fx4 acc1[8];                 // sum_s mask*r2*h2   (per n, per t=nl)
#pragma unroll
    for (int tile = 0; tile < 8; tile++) acc1[tile] = (fx4){0.f, 0.f, 0.f, 0.f};
    float c0 = 0.f;              // sum_s mask
    float c1 = 0.f;              // sum_s mask*r2*mean2

    __syncthreads();

    for (int i = 0; i < 16; i++) {
        int s = sh * 64 + wv * 16 + i;
        const float* brow = base + (b * NN + s) * HH;
        float avv = adjv[(b * NN + s) * NN + t0 + nl];   // t = t0 + nl

        // h1 = relu(base + avv*w17); LN1 stats (per t = nl, reduce over k)
        float v[4][8];
        float sm = 0.f, s2 = 0.f;
#pragma unroll
        for (int st = 0; st < 4; st++) {
            const float* p = brow + quad * 8 + 32 * st;
            float4 b0 = *(const float4*)p;
            float4 b1q = *(const float4*)(p + 4);
            float h[8] = {b0.x, b0.y, b0.z, b0.w, b1q.x, b1q.y, b1q.z, b1q.w};
#pragma unroll
            for (int j = 0; j < 8; j++) {
                float vv = fmaxf(fmaf(avv, w17v[st][j], h[j]), 0.f);
                v[st][j] = vv;
                sm += vv;
                s2 = fmaf(vv, vv, s2);
            }
        }
        sm += __shfl_xor(sm, 16); sm += __shfl_xor(sm, 32);
        s2 += __shfl_xor(s2, 16); s2 += __shfl_xor(s2, 32);
        float m1 = sm * (1.f / 128.f);
        float r1 = rsqrtf(s2 * (1.f / 128.f) - m1 * m1 + 1e-5f);
        float nm = -m1 * r1;

        // B operand = (h1 - m1)*r1, split bf16 hi/lo (col = t = nl)
        short8 Hhi[4], Hlo[4];
#pragma unroll
        for (int st = 0; st < 4; st++) {
            short8 ah, al;
#pragma unroll
            for (int j = 0; j < 8; j++) {
                float vn = fmaf(v[st][j], r1, nm);
                ushort_t hb = f2us_tr(vn);
                float lo = vn - us2f(hb);
                ah[j] = (short)hb;
                al[j] = (short)f2us_tr(lo);
            }
            Hhi[st] = ah; Hlo[st] = al;
        }

        // G init = cb[n]  ->  pre-relu2 = cb + LN1(h1) @ Wh'
        fx4 G[8];
#pragma unroll
        for (int tile = 0; tile < 8; tile++)
            G[tile] = (fx4){cb4[tile].x, cb4[tile].y, cb4[tile].z, cb4[tile].w};

#pragma unroll
        for (int st = 0; st < 4; st++) {
            int koff = quad * 8 + 32 * st;
#pragma unroll
            for (int tile = 0; tile < 8; tile++) {
                int off = (tile * 16 + nl) * HH + (koff ^ (nl * 8));
                short8 ph = *(const short8*)(&Phi[off]);
                short8 pl = *(const short8*)(&Plo[off]);
                G[tile] = __builtin_amdgcn_mfma_f32_16x16x32_bf16(ph, Hhi[st], G[tile], 0, 0, 0);
                G[tile] = __builtin_amdgcn_mfma_f32_16x16x32_bf16(pl, Hhi[st], G[tile], 0, 0, 0);
                G[tile] = __builtin_amdgcn_mfma_f32_16x16x32_bf16(ph, Hlo[st], G[tile], 0, 0, 0);
            }
        }

        // h2 = relu(G); LN2 stats per t=nl (in-lane over 32 n + 2 shuffles)
        float sm2 = 0.f, ss2 = 0.f;
#pragma unroll
        for (int tile = 0; tile < 8; tile++) {
#pragma unroll
            for (int r = 0; r < 4; r++) {
                float h2 = fmaxf(G[tile][r], 0.f);
                G[tile][r] = h2;
                sm2 += h2;
                ss2 = fmaf(h2, h2, ss2);
            }
        }
        sm2 += __shfl_xor(sm2, 16); sm2 += __shfl_xor(sm2, 32);
        ss2 += __shfl_xor(ss2, 16); ss2 += __shfl_xor(ss2, 32);
        float mean2 = sm2 * (1.f / 128.f);
        float r2 = rsqrtf(ss2 * (1.f / 128.f) - mean2 * mean2 + 1e-5f);
        float msk = (avv != 0.f) ? 1.f : 0.f;
        float mr2 = msk * r2;

#pragma unroll
        for (int tile = 0; tile < 8; tile++)
#pragma unroll
            for (int r = 0; r < 4; r++)
                acc1[tile][r] = fmaf(mr2, G[tile][r], acc1[tile][r]);
        c0 += msk;
        c1 = fmaf(mr2, mean2, c1);
    }

    // epilogue: x0[t][n] += gh[n]*(acc1 - c1) + beh[n]*c0
#pragma unroll
    for (int tile = 0; tile < 8; tile++) {
        float4 g4 = *(const float4*)(ghp + tile * 16 + quad * 4);
        float4 be4 = *(const float4*)(behp + tile * 16 + quad * 4);
        float gv[4] = {g4.x, g4.y, g4.z, g4.w};
        float bv[4] = {be4.x, be4.y, be4.z, be4.w};
#pragma unroll
        for (int r = 0; r < 4; r++) {
            float xv = fmaf(gv[r], acc1[tile][r] - c1, bv[r] * c0);
            atomicAdd(&x0[(b * NN + t0 + nl) * HH + tile * 16 + quad * 4 + r], xv);
        }
    }
}

// ---------------- K5: qkvs via MFMA; emits q/skip f32, K planes, vT planes -
template <int IN>
__global__ void __launch_bounds__(256) k_qkvs_mfma(
    const float* x, const ushort_t* Whi, const ushort_t* Wlo,
    const float* b0, const float* b1, const float* b2, const float* b3,
    float* q, float* skipo,
    ushort_t* khi, ushort_t* klo, ushort_t* vThi, ushort_t* vTlo)
{
    const int ST = IN / 32;
    int blk = blockIdx.x;
    int m0 = (blk >> 2) * 64;
    int nsl = blk & 3;
    int tid = threadIdx.x;
    int wv = tid >> 6;
    int lane = tid & 63;
    int nl = lane & 15;
    int quad = lane >> 4;
    int row = m0 + wv * 16 + nl;

    short8 Ahi[ST], Alo[ST];
    const float* xrow = x + (long)row * IN;
#pragma unroll
    for (int st = 0; st < ST; st++) {
        const float* p = xrow + quad * 8 + 32 * st;
        float4 a = *(const float4*)p;
        float4 bq = *(const float4*)(p + 4);
        float h[8] = {a.x, a.y, a.z, a.w, bq.x, bq.y, bq.z, bq.w};
        short8 ah, al;
#pragma unroll
        for (int j = 0; j < 8; j++) {
            float v = h[j];
            ushort_t hb = f2us_tr(v);
            float lo = v - us2f(hb);
            ah[j] = (short)hb;
            al[j] = (short)f2us_tr(lo);
        }
        Ahi[st] = ah; Alo[st] = al;
    }

    const float* bs_[4] = {b0, b1, b2, b3};

#pragma unroll
    for (int mat = 0; mat < 4; mat++) {
        const ushort_t* Bh = Whi + (mat * 256 + nsl * 64) * IN;
        const ushort_t* Bl = Wlo + (mat * 256 + nsl * 64) * IN;
        fx4 G[4];
#pragma unroll
        for (int tile = 0; tile < 4; tile++) {
            float bc = bs_[mat][nsl * 64 + tile * 16 + nl];
            G[tile] = (fx4){bc, bc, bc, bc};
        }
#pragma unroll
        for (int st = 0; st < ST; st++) {
            int koff = quad * 8 + 32 * st;
#pragma unroll
            for (int tile = 0; tile < 4; tile++) {
                int off = (tile * 16 + nl) * IN + (koff ^ (nl * 8));
                short8 bh8 = *(const short8*)(Bh + off);
                short8 bl8 = *(const short8*)(Bl + off);
                G[tile] = __builtin_amdgcn_mfma_f32_16x16x32_bf16(Ahi[st], bh8, G[tile], 0, 0, 0);
                G[tile] = __builtin_amdgcn_mfma_f32_16x16x32_bf16(Alo[st], bh8, G[tile], 0, 0, 0);
                G[tile] = __builtin_amdgcn_mfma_f32_16x16x32_bf16(Ahi[st], bl8, G[tile], 0, 0, 0);
            }
        }
        int row0 = m0 + wv * 16 + quad * 4;          // rows r=0..3
        if (mat == 0 || mat == 3) {
            float* om = (mat == 0) ? q : skipo;
#pragma unroll
            for (int tile = 0; tile < 4; tile++)
#pragma unroll
                for (int r = 0; r < 4; r++)
                    om[(row0 + r) * HD + nsl * 64 + tile * 16 + nl] = G[tile][r];
        } else if (mat == 1) {
            // K planes, layout [row=b*128+s][256]
#pragma unroll
            for (int tile = 0; tile < 4; tile++) {
                int col = nsl * 64 + tile * 16 + nl;
#pragma unroll
                for (int r = 0; r < 4; r++) {
                    float gv = G[tile][r];
                    ushort_t hb = f2us_tr(gv);
                    khi[(row0 + r) * HD + col] = hb;
                    klo[(row0 + r) * HD + col] = f2us_tr(gv - us2f(hb));
                }
            }
        } else {
            // vT planes: vT[dg = b*256 + col][128 s], 4 consecutive s packed
            int bb = row0 >> 7;
            int s0 = row0 & 127;
#pragma unroll
            for (int tile = 0; tile < 4; tile++) {
                int col = nsl * 64 + tile * 16 + nl;
                int dg = bb * 256 + col;
                ushort4 h4, l4;
                float g0 = G[tile][0], g1 = G[tile][1], g2 = G[tile][2], g3 = G[tile][3];
                ushort_t h0 = f2us_tr(g0), h1 = f2us_tr(g1), h2 = f2us_tr(g2), h3 = f2us_tr(g3);
                h4.x = h0; h4.y = h1; h4.z = h2; h4.w = h3;
                l4.x = f2us_tr(g0 - us2f(h0));
                l4.y = f2us_tr(g1 - us2f(h1));
                l4.z = f2us_tr(g2 - us2f(h2));
                l4.w = f2us_tr(g3 - us2f(h3));
                *(ushort4*)&vThi[dg * NN + s0] = h4;
                *(ushort4*)&vTlo[dg * NN + s0] = l4;
            }
        }
    }
}

// ---------------- K6: attention via MFMA, 1 wave per (b,h,16-t tile) -------
__global__ void __launch_bounds__(64) k_attn_mfma(
    const float* qb, const ushort_t* khi, const ushort_t* klo,
    const ushort_t* vThi, const ushort_t* vTlo,
    const float* adjvT, const float* We, const float* skip, float* xout)
{
    __shared__ float aL[16][132];     // alpha C->A round-trip (8.4 KB)
    __shared__ float qeL[16];

    int blk = blockIdx.x;             // 1024 = 32b*4h*8tt
    int b  = blk >> 5;
    int h  = (blk >> 3) & 3;
    int tt = blk & 7;
    int t0 = tt * 16;
    int lane = threadIdx.x;
    int nl = lane & 15;
    int quad = lane >> 4;

    // ---- Q A-frags (split hi/lo) + qe partial (q . we) ----
    short8 Qhi[2], Qlo[2];
    float qe = 0.f;
#pragma unroll
    for (int ks = 0; ks < 2; ks++) {
        const float* p = qb + (b * NN + t0 + nl) * HD + h * DHEAD + quad * 8 + 32 * ks;
        const float* wp = We + h * DHEAD + quad * 8 + 32 * ks;
        float4 a0 = *(const float4*)p;
        float4 a1 = *(const float4*)(p + 4);
        float4 w0 = *(const float4*)wp;
        float4 w1 = *(const float4*)(wp + 4);
        float hv[8] = {a0.x, a0.y, a0.z, a0.w, a1.x, a1.y, a1.z, a1.w};
        float wv8[8] = {w0.x, w0.y, w0.z, w0.w, w1.x, w1.y, w1.z, w1.w};
        short8 ah, al;
#pragma unroll
        for (int j = 0; j < 8; j++) {
            float v = hv[j];
            ushort_t hb = f2us_tr(v);
            ah[j] = (short)hb;
            al[j] = (short)f2us_tr(v - us2f(hb));
            qe += v * wv8[j];
        }
        Qhi[ks] = ah; Qlo[ks] = al;
    }
    qe += __shfl_xor(qe, 16);
    qe += __shfl_xor(qe, 32);
    if (lane < 16) qeL[lane] = qe;    // qe for t = lane
    __syncthreads();
    float qe_r[4];
#pragma unroll
    for (int r = 0; r < 4; r++) qe_r[r] = qeL[quad * 4 + r];
    float we_d[4];
#pragma unroll
    for (int nt = 0; nt < 4; nt++) we_d[nt] = We[h * DHEAD + nt * 16 + nl];

    // ---- QK^T: S[t][s], 8 s-tiles ----
    fx4 S[8];
#pragma unroll
    for (int st = 0; st < 8; st++) S[st] = (fx4){0.f, 0.f, 0.f, 0.f};
#pragma unroll
    for (int ks = 0; ks < 2; ks++) {
#pragma unroll
        for (int st = 0; st < 8; st++) {
            long off = (long)(b * NN + st * 16 + nl) * HD + h * DHEAD + quad * 8 + 32 * ks;
            short8 bh8 = *(const short8*)(khi + off);
            short8 bl8 = *(const short8*)(klo + off);
            S[st] = __builtin_amdgcn_mfma_f32_16x16x32_bf16(Qhi[ks], bh8, S[st], 0, 0, 0);
            S[st] = __builtin_amdgcn_mfma_f32_16x16x32_bf16(Qlo[ks], bh8, S[st], 0, 0, 0);
            S[st] = __builtin_amdgcn_mfma_f32_16x16x32_bf16(Qhi[ks], bl8, S[st], 0, 0, 0);
        }
    }

    // ---- masked logits (D-layout: row t = quad*4+r, col s = st*16+nl) ----
    float av[8][4];
#pragma unroll
    for (int st = 0; st < 8; st++)
#pragma unroll
        for (int r = 0; r < 4; r++)
            av[st][r] = adjvT[(b * NN + t0 + quad * 4 + r) * NN + st * 16 + nl];
#pragma unroll
    for (int st = 0; st < 8; st++)
#pragma unroll
        for (int r = 0; r < 4; r++) {
            float a = av[st][r];
            S[st][r] = (a != 0.f) ? (S[st][r] + a * qe_r[r]) * 0.125f : -1e30f;
        }

    // ---- softmax per row: reduce over s = in-lane stiles + xor{1,2,4,8} ----
    float mx[4], den[4], beta[4];
#pragma unroll
    for (int r = 0; r < 4; r++) {
        float m = S[0][r];
#pragma unroll
        for (int st = 1; st < 8; st++) m = fmaxf(m, S[st][r]);
#pragma unroll
        for (int mm = 1; mm < 16; mm <<= 1) m = fmaxf(m, __shfl_xor(m, mm));
        mx[r] = m;
    }
#pragma unroll
    for (int r = 0; r < 4; r++) den[r] = 0.f;
#pragma unroll
    for (int st = 0; st < 8; st++)
#pragma unroll
        for (int r = 0; r < 4; r++) {
            float e = (av[st][r] != 0.f) ? __expf(S[st][r] - mx[r]) : 0.f;
            S[st][r] = e;
            den[r] += e;
        }
#pragma unroll
    for (int r = 0; r < 4; r++) {
#pragma unroll
        for (int mm = 1; mm < 16; mm <<= 1) den[r] += __shfl_xor(den[r], mm);
        den[r] = 1.f / fmaxf(den[r], 1e-16f);
        beta[r] = 0.f;
    }
#pragma unroll
    for (int st = 0; st < 8; st++)
#pragma unroll
        for (int r = 0; r < 4; r++) {
            float al = S[st][r] * den[r];
            S[st][r] = al;
            beta[r] += al * av[st][r];
        }
#pragma unroll
    for (int r = 0; r < 4; r++)
#pragma unroll
        for (int mm = 1; mm < 16; mm <<= 1) beta[r] += __shfl_xor(beta[r], mm);

    // ---- alpha C-layout -> LDS -> A-layout frags (hi only) ----
#pragma unroll
    for (int st = 0; st < 8; st++)
#pragma unroll
        for (int r = 0; r < 4; r++)
            aL[quad * 4 + r][st * 16 + nl] = S[st][r];
    __syncthreads();
    short8 Ah[4];
#pragma unroll
    for (int ks = 0; ks < 4; ks++) {
        const float* p = &aL[nl][quad * 8 + 32 * ks];
        float4 a0 = *(const float4*)p;
        float4 a1 = *(const float4*)(p + 4);
        float hv[8] = {a0.x, a0.y, a0.z, a0.w, a1.x, a1.y, a1.z, a1.w};
        short8 ah;
#pragma unroll
        for (int j = 0; j < 8; j++) ah[j] = (short)f2us_tr(hv[j]);
        Ah[ks] = ah;
    }

    // ---- PV: out[t][d] = beta*we + alpha @ V (V via vT planes) ----
    fx4 G[4];
#pragma unroll
    for (int nt = 0; nt < 4; nt++) {
        fx4 g;
#pragma unroll
        for (int r = 0; r < 4; r++) g[r] = beta[r] * we_d[nt];
        G[nt] = g;
    }
#pragma unroll
    for (int ks = 0; ks < 4; ks++) {
#pragma unroll
        for (int nt = 0; nt < 4; nt++) {
            long dg = (long)(b * 256 + h * DHEAD + nt * 16 + nl);
            const short8 vh = *(const short8*)(vThi + dg * NN + quad * 8 + 32 * ks);
            const short8 vl = *(const short8*)(vTlo + dg * NN + quad * 8 + 32 * ks);
            G[nt] = __builtin_amdgcn_mfma_f32_16x16x32_bf16(Ah[ks], vh, G[nt], 0, 0, 0);
            G[nt] = __builtin_amdgcn_mfma_f32_16x16x32_bf16(Ah[ks], vl, G[nt], 0, 0, 0);
        }
    }

    // ---- epilogue: relu(out + skip) ----
#pragma unroll
    for (int nt = 0; nt < 4; nt++)
#pragma unroll
        for (int r = 0; r < 4; r++) {
            int gi = (b * NN + t0 + quad * 4 + r) * HD + h * DHEAD + nt * 16 + nl;
            xout[gi] = fmaxf(G[nt][r] + skip[gi], 0.f);
        }
}

// ---------------- K8: gather agent rows -> f32 out ----------------
__global__ void k_gather(const float* x2, const int* agent, float* out) {
    int b = blockIdx.x;
    int c = threadIdx.x;
    out[b * HD + c] = x2[(b * NN + agent[b]) * HD + c];
}

// ---------------- launch ----------------
extern "C" void kernel_launch(void* const* d_in, const int* in_sizes, int n_in,
                              void* d_out, int out_size, void* d_ws, size_t ws_size,
                              hipStream_t stream) {
    float* out = (float*)d_out;
    (void)hipGetLastError();

    bool ok = (n_in == 31) && in_sizes[0] == BB * NN * FF && in_sizes[2] == BB * NN * NN
              && in_sizes[5] == (FF + EE + 1) * HH && in_sizes[13] == HH * HD
              && in_sizes[22] == HD * HD && out_size == BB * HD;
    if (!ok) { k_sent<<<32, 256, 0, stream>>>(out, -30000.f); return; }

    const size_t WS_NEED = (size_t)8912896 * 4;
    if (ws_size < WS_NEED) { k_sent<<<32, 256, 0, stream>>>(out, -20000.f); return; }

    const float* nf    = (const float*)d_in[0];
    const int*   et    = (const int*)d_in[1];
    const float* adj   = (const float*)d_in[2];
    const int*   agent = (const int*)d_in[3];
    const float* emb   = (const float*)d_in[4];
    const float* W1    = (const float*)d_in[5];
    const float* b1    = (const float*)d_in[6];
    const float* g1    = (const float*)d_in[7];
    const float* be1   = (const float*)d_in[8];
    const float* Wh    = (const float*)d_in[9];
    const float* bh    = (const float*)d_in[10];
    const float* gh    = (const float*)d_in[11];
    const float* beh   = (const float*)d_in[12];
    const float* Wq1   = (const float*)d_in[13];
    const float* bq1   = (const float*)d_in[14];
    const float* Wk1   = (const float*)d_in[15];
    const float* bk1   = (const float*)d_in[16];
    const float* Wv1   = (const float*)d_in[17];
    const float* bv1   = (const float*)d_in[18];
    const float* We1   = (const float*)d_in[19];
    const float* Ws1   = (const float*)d_in[20];
    const float* bs1   = (const float*)d_in[21];
    const float* Wq2   = (const float*)d_in[22];
    const float* bq2   = (const float*)d_in[23];
    const float* Wk2   = (const float*)d_in[24];
    const float* bk2   = (const float*)d_in[25];
    const float* Wv2   = (const float*)d_in[26];
    const float* bv2   = (const float*)d_in[27];
    const float* We2   = (const float*)d_in[28];
    const float* Ws2   = (const float*)d_in[29];
    const float* bs2   = (const float*)d_in[30];

    float* ws   = (float*)d_ws;
    float* adjv = ws;                              // 524288 f
    float* base = adjv + BB * NN * NN;             // 524288 f
    float* x0   = base + BB * NN * HH;             // 524288 f
    float* q    = x0 + BB * NN * HH;               // 1048576 f
    float* kreg = q + BB * NN * HD;                // 1048576 f -> khi/klo
    float* vreg = kreg + BB * NN * HD;             // 1048576 f -> vThi/vTlo
    float* skip = vreg + BB * NN * HD;             // 1048576 f
    float* areg = skip + BB * NN * HD;             // 1048576 f -> weight planes + adjvT
    float* x1   = areg + BB * NN * HD;
    float* x2   = x1 + BB * NN * HD;

    // econv prep planes in q region (q first written AFTER econv)
    ushort_t* BhiG = (ushort_t*)q;
    ushort_t* BloG = BhiG + HH * HH;
    float*    W1sW = q + 16384;
    float*    cbW  = q + 16512;

    // K / vT planes
    ushort_t* khi  = (ushort_t*)kreg;              // 1048576 ush
    ushort_t* klo  = khi + BB * NN * HD;           // 1048576 ush
    ushort_t* vThi = (ushort_t*)vreg;
    ushort_t* vTlo = vThi + BB * NN * HD;

    // qkvs weight planes + adjvT in areg (4 MB): 1.5 MB planes + 2 MB adjvT
    ushort_t* WhA = (ushort_t*)areg;               // 4*256*128 ush
    ushort_t* WlA = WhA + 4 * 256 * HH;
    ushort_t* WhB = WlA + 4 * 256 * HH;            // 4*256*256 ush
    ushort_t* WlB = WhB + 4 * 256 * HD;
    float* adjvT  = areg + 393216;                 // 524288 f, past planes

    int fail = 0;
    hipError_t e;
#define CHK(stage) do { e = hipGetLastError(); if (e != hipSuccess && fail == 0) fail = (stage); } while (0)

    k_adjv<<<BB, 256, 0, stream>>>(adj, adjv, adjvT);                                CHK(1);
    k_base<<<BB * NN, HH, 0, stream>>>(nf, et, emb, W1, b1, base);                   CHK(2);
    k_zero<<<BB * NN * HH / 256, 256, 0, stream>>>(x0);                              CHK(3);
    k_prep<<<HH, 64, 0, stream>>>(Wh, g1, be1, bh, BhiG, BloG, W1sW, cbW);           CHK(4);
    k_prepw<<<1024, 64, 0, stream>>>(Wq1, Wk1, Wv1, Ws1, HH, WhA, WlA);              CHK(5);
    k_prepw<<<1024, 64, 0, stream>>>(Wq2, Wk2, Wv2, Ws2, HD, WhB, WlB);              CHK(6);
    k_econv_mfma<<<512, 256, 0, stream>>>(adjv, base, W1, BhiG, BloG, W1sW, cbW,
                                          gh, beh, x0);                              CHK(7);

    k_qkvs_mfma<HH><<<256, 256, 0, stream>>>(x0, WhA, WlA, bq1, bk1, bv1, bs1,
                                             q, skip, khi, klo, vThi, vTlo);         CHK(8);
    k_attn_mfma<<<1024, 64, 0, stream>>>(q, khi, klo, vThi, vTlo, adjvT, We1,
                                         skip, x1);                                  CHK(9);

    k_qkvs_mfma<HD><<<256, 256, 0, stream>>>(x1, WhB, WlB, bq2, bk2, bv2, bs2,
                                             q, skip, khi, klo, vThi, vTlo);         CHK(10);
    k_attn_mfma<<<1024, 64, 0, stream>>>(q, khi, klo, vThi, vTlo, adjvT, We2,
                                         skip, x2);                                  CHK(11);

    k_gather<<<BB, HD, 0, stream>>>(x2, agent, out);                                 CHK(12);
#undef CHK

    if (fail != 0)
        k_sent<<<32, 256, 0, stream>>>(out, -(1000.f + 500.f * (float)fail));
}

// Round 2
// 516.705 us; speedup vs baseline: 1.0962x; 1.0962x over previous
//
#include <hip/hip_runtime.h>
#include <hip/hip_bf16.h>

typedef __hip_bfloat16 bf16;
typedef unsigned short ushort_t;
typedef __attribute__((ext_vector_type(8))) short short8;
typedef __attribute__((ext_vector_type(4))) float fx4;

#define BB 32
#define NN 128
#define FF 9
#define EE 8
#define HH 128
#define HD 256
#define NHEAD 4
#define DHEAD 64

__device__ __forceinline__ float us2f(ushort_t u) {
    return __uint_as_float(((unsigned int)u) << 16);
}
// truncation split: hi = trunc16(v), lo = v - hi (lo exact in f32)
__device__ __forceinline__ ushort_t f2us_tr(float f) {
    return (ushort_t)(__float_as_uint(f) >> 16);
}

__global__ void TransformerConvNet_85315230367963_kernel() {}

__global__ void k_sent(float* out, float val) {
    out[blockIdx.x * 256 + threadIdx.x] = val;
}

__global__ void k_zero(float* p) {
    p[blockIdx.x * 256 + threadIdx.x] = 0.f;
}

// ---------------- K1: adjv + adjvT (masked) ----------------
__global__ void k_adjv(const float* adj, float* adjv, float* adjvT) {
    int b = blockIdx.x;            // 32
    const float* src = adj + b * NN * NN;
    float* d1 = adjv + b * NN * NN;
    float* d2 = adjvT + b * NN * NN;
    for (int i = threadIdx.x; i < NN * NN; i += 256) {
        float a = src[i];
        d1[i] = (a > 0.f && a < 1.0f) ? a : 0.f;
    }
    for (int i = threadIdx.x; i < NN * NN; i += 256) {
        int t = i >> 7, s = i & 127;
        float a = src[s * NN + t];
        d2[i] = (a > 0.f && a < 1.0f) ? a : 0.f;   // adjvT[t][s]
    }
}

// ---------------- K2: base[bs][c] = src(bs) @ W1[:17] + b1 ----------------
__global__ void k_base(const float* nf, const int* et, const float* emb,
                       const float* W1, const float* b1, float* base) {
    int bs = blockIdx.x;
    int c = threadIdx.x;
    int ty = et[bs];
    float acc = b1[c];
    for (int f = 0; f < FF; f++)
        acc += nf[bs * FF + f] * W1[f * HH + c];
    for (int e = 0; e < EE; e++)
        acc += emb[ty * EE + e] * W1[(FF + e) * HH + c];
    base[bs * HH + c] = acc;
}

// ---------------- K_prep: Wh' = g1*Wh split bf16 hi/lo, swizzled ----------
__global__ void k_prep(const float* Wh, const float* g1, const float* be1,
                       const float* bh, ushort_t* BhiG, ushort_t* BloG,
                       float* W1s, float* cbv) {
    int n = blockIdx.x;      // 0..127
    int t = threadIdx.x;     // 0..63
    int sw = 8 * (n & 15);
    float s1 = 0.f, s2 = 0.f;
    for (int kk = 0; kk < 2; kk++) {
        int k = t + kk * 64;
        float w = Wh[k * HH + n];
        float wp = g1[k] * w;
        ushort_t hb = f2us_tr(wp);
        float lo = wp - us2f(hb);
        BhiG[n * HH + (k ^ sw)] = hb;
        BloG[n * HH + (k ^ sw)] = f2us_tr(lo);
        s1 += wp;
        s2 += be1[k] * w;
    }
    for (int m = 1; m < 64; m <<= 1) {
        s1 += __shfl_xor(s1, m);
        s2 += __shfl_xor(s2, m);
    }
    if (t == 0) { W1s[n] = s1; cbv[n] = s2 + bh[n]; }
}

// ---------------- K_prepw: split 4 qkvs weight mats into bf16 hi/lo -------
__global__ void k_prepw(const float* W0, const float* W1p, const float* W2p,
                        const float* W3p, int IN, ushort_t* Whi, ushort_t* Wlo) {
    int blk = blockIdx.x;             // 4*256
    int mat = blk >> 8, n = blk & 255;
    const float* W = (mat == 0) ? W0 : (mat == 1) ? W1p : (mat == 2) ? W2p : W3p;
    ushort_t* hi = Whi + mat * 256 * IN;
    ushort_t* lo = Wlo + mat * 256 * IN;
    int sw = 8 * (n & 15);
    for (int k = threadIdx.x; k < IN; k += 64) {
        float w = W[k * HD + n];
        ushort_t hb = f2us_tr(w);
        float l = w - us2f(hb);
        hi[n * IN + (k ^ sw)] = hb;
        lo[n * IN + (k ^ sw)] = f2us_tr(l);
    }
}

// ---------------- K3: embed conv, MFMA, SWAPPED operands ------------------
// D[n][t] = Wh'^T (from LDS, A-operand) x  LN1(h1)^T (registers, B-operand).
// B cols = t = nl  -> LN1/LN2 stats live in the right lanes: no broadcasts,
// LN2 reduce = in-lane + 2 shuffles. LN1 folded into B pre-split; cb folded
// into G init; mask/r2/gh/beh folded into running scalars + epilogue.
// Epilogue: cross-wave LDS reduction (reusing the Phi/Plo region) then
// COALESCED global atomics (nl on the column index) -- the scattered
// per-lane row atomics were 837 MB of HBM RMW traffic.
__global__ void __launch_bounds__(256, 2) k_econv_mfma(
    const float* adjv, const float* base, const float* W1,
    const ushort_t* BhiG, const ushort_t* BloG,
    const float* W1s_unused, const float* cbv,
    const float* ghp, const float* behp, float* x0)
{
    __shared__ __align__(16) ushort_t PhiPlo[2 * HH * HH];   // 64 KB
    ushort_t* Phi = PhiPlo;
    ushort_t* Plo = PhiPlo + HH * HH;

    int blk = blockIdx.x;
    int b  = blk >> 4;
    int tt = (blk >> 1) & 7;
    int sh = blk & 1;
    int t0 = tt * 16;
    int tid = threadIdx.x;
    int wv  = tid >> 6;
    int lane = tid & 63;
    int nl = lane & 15;
    int quad = lane >> 4;

    {
        const uint4* srcH = (const uint4*)BhiG;
        const uint4* srcL = (const uint4*)BloG;
        uint4* dstH = (uint4*)Phi;
        uint4* dstL = (uint4*)Plo;
        for (int i = tid; i < HH * HH / 8; i += 256) {
            dstH[i] = srcH[i];
            dstL[i] = srcL[i];
        }
    }

    // per-lane constants: cb[n] as float4 per tile (n = tile*16 + quad*4 + r)
    float4 cb4[8];
#pragma unroll
    for (int tile = 0; tile < 8; tile++)
        cb4[tile] = *(const float4*)(cbv + tile * 16 + quad * 4);

    float w17v[4][8];
#pragma unroll
    for (int st = 0; st < 4; st++) {
        const float* p = W1 + 17 * HH + quad * 8 + 32 * st;
        float4 a = *(const float4*)p;
        float4 bq = *(const float4*)(p + 4);
        w17v[st][0] = a.x;  w17v[st][1] = a.y;  w17v[st][2] = a.z;  w17v[st][3] = a.w;
        w17v[st][4] = bq.x; w17v[st][5] = bq.y; w17v[st][6] = bq.z; w17v[st][7] = bq.w;
    }

    fx4 acc1[8];                 // sum_s mask*r2*h2   (per n, per t=nl)
#pragma unroll
    for (int tile = 0; tile < 8; tile++) acc1[tile] = (fx4){0.f, 0.f, 0.f, 0.f};
    float c0 = 0.f;              // sum_s mask
    float c1 = 0.f;              // sum_s mask*r2*mean2

    __syncthreads();

    for (int i = 0; i < 16; i++) {
        int s = sh * 64 + wv * 16 + i;
        const float* brow = base + (b * NN + s) * HH;
        float avv = adjv[(b * NN + s) * NN + t0 + nl];   // t = t0 + nl

        // h1 = relu(base + avv*w17); LN1 stats (per t = nl, reduce over k)
        float v[4][8];
        float sm = 0.f, s2 = 0.f;
#pragma unroll
        for (int st = 0; st < 4; st++) {
            const float* p = brow + quad * 8 + 32 * st;
            float4 b0 = *(const float4*)p;
            float4 b1q = *(const float4*)(p + 4);
            float h[8] = {b0.x, b0.y, b0.z, b0.w, b1q.x, b1q.y, b1q.z, b1q.w};
#pragma unroll
            for (int j = 0; j < 8; j++) {
                float vv = fmaxf(fmaf(avv, w17v[st][j], h[j]), 0.f);
                v[st][j] = vv;
                sm += vv;
                s2 = fmaf(vv, vv, s2);
            }
        }
        sm += __shfl_xor(sm, 16); sm += __shfl_xor(sm, 32);
        s2 += __shfl_xor(s2, 16); s2 += __shfl_xor(s2, 32);
        float m1 = sm * (1.f / 128.f);
        float r1 = rsqrtf(s2 * (1.f / 128.f) - m1 * m1 + 1e-5f);
        float nm = -m1 * r1;

        // B operand = (h1 - m1)*r1, split bf16 hi/lo (col = t = nl)
        short8 Hhi[4], Hlo[4];
#pragma unroll
        for (int st = 0; st < 4; st++) {
            short8 ah, al;
#pragma unroll
            for (int j = 0; j < 8; j++) {
                float vn = fmaf(v[st][j], r1, nm);
                ushort_t hb = f2us_tr(vn);
                float lo = vn - us2f(hb);
                ah[j] = (short)hb;
                al[j] = (short)f2us_tr(lo);
            }
            Hhi[st] = ah; Hlo[st] = al;
        }

        // G init = cb[n]  ->  pre-relu2 = cb + LN1(h1) @ Wh'
        fx4 G[8];
#pragma unroll
        for (int tile = 0; tile < 8; tile++)
            G[tile] = (fx4){cb4[tile].x, cb4[tile].y, cb4[tile].z, cb4[tile].w};

#pragma unroll
        for (int st = 0; st < 4; st++) {
            int koff = quad * 8 + 32 * st;
#pragma unroll
            for (int tile = 0; tile < 8; tile++) {
                int off = (tile * 16 + nl) * HH + (koff ^ (nl * 8));
                short8 ph = *(const short8*)(&Phi[off]);
                short8 pl = *(const short8*)(&Plo[off]);
                G[tile] = __builtin_amdgcn_mfma_f32_16x16x32_bf16(ph, Hhi[st], G[tile], 0, 0, 0);
                G[tile] = __builtin_amdgcn_mfma_f32_16x16x32_bf16(pl, Hhi[st], G[tile], 0, 0, 0);
                G[tile] = __builtin_amdgcn_mfma_f32_16x16x32_bf16(ph, Hlo[st], G[tile], 0, 0, 0);
            }
        }

        // h2 = relu(G); LN2 stats per t=nl (in-lane over 32 n + 2 shuffles)
        float sm2 = 0.f, ss2 = 0.f;
#pragma unroll
        for (int tile = 0; tile < 8; tile++) {
#pragma unroll
            for (int r = 0; r < 4; r++) {
                float h2 = fmaxf(G[tile][r], 0.f);
                G[tile][r] = h2;
                sm2 += h2;
                ss2 = fmaf(h2, h2, ss2);
            }
        }
        sm2 += __shfl_xor(sm2, 16); sm2 += __shfl_xor(sm2, 32);
        ss2 += __shfl_xor(ss2, 16); ss2 += __shfl_xor(ss2, 32);
        float mean2 = sm2 * (1.f / 128.f);
        float r2 = rsqrtf(ss2 * (1.f / 128.f) - mean2 * mean2 + 1e-5f);
        float msk = (avv != 0.f) ? 1.f : 0.f;
        float mr2 = msk * r2;

#pragma unroll
        for (int tile = 0; tile < 8; tile++)
#pragma unroll
            for (int r = 0; r < 4; r++)
                acc1[tile][r] = fmaf(mr2, G[tile][r], acc1[tile][r]);
        c0 += msk;
        c1 = fmaf(mr2, mean2, c1);
    }

    // ---- epilogue: xv = gh*(acc1 - c1) + beh*c0 ;  cross-wave LDS reduce,
    //      then coalesced atomics (consecutive lanes -> consecutive n) ----
    __syncthreads();                       // Phi/Plo dead; reuse as f32 slab
    float* slab = (float*)PhiPlo;          // [4 waves][16 t][stride 132]
#pragma unroll
    for (int tile = 0; tile < 8; tile++) {
        float4 g4 = *(const float4*)(ghp + tile * 16 + quad * 4);
        float4 be4 = *(const float4*)(behp + tile * 16 + quad * 4);
        float gv[4] = {g4.x, g4.y, g4.z, g4.w};
        float bv[4] = {be4.x, be4.y, be4.z, be4.w};
#pragma unroll
        for (int r = 0; r < 4; r++) {
            float xv = fmaf(gv[r], acc1[tile][r] - c1, bv[r] * c0);
            slab[(wv * 16 + nl) * 132 + tile * 16 + quad * 4 + r] = xv;
        }
    }
    __syncthreads();
    for (int e = tid; e < 16 * HH; e += 256) {
        int t = e >> 7, n = e & 127;
        float vsum = slab[t * 132 + n] + slab[(16 + t) * 132 + n]
                   + slab[(32 + t) * 132 + n] + slab[(48 + t) * 132 + n];
        atomicAdd(&x0[(b * NN + t0 + t) * HH + n], vsum);
    }
}

// ---------------- K5: qkvs via MFMA; emits q/skip f32, K planes, vT planes -
template <int IN>
__global__ void __launch_bounds__(256) k_qkvs_mfma(
    const float* x, const ushort_t* Whi, const ushort_t* Wlo,
    const float* b0, const float* b1, const float* b2, const float* b3,
    float* q, float* skipo,
    ushort_t* khi, ushort_t* klo, ushort_t* vThi, ushort_t* vTlo)
{
    const int ST = IN / 32;
    int blk = blockIdx.x;
    int m0 = (blk >> 2) * 64;
    int nsl = blk & 3;
    int tid = threadIdx.x;
    int wv = tid >> 6;
    int lane = tid & 63;
    int nl = lane & 15;
    int quad = lane >> 4;
    int row = m0 + wv * 16 + nl;

    short8 Ahi[ST], Alo[ST];
    const float* xrow = x + (long)row * IN;
#pragma unroll
    for (int st = 0; st < ST; st++) {
        const float* p = xrow + quad * 8 + 32 * st;
        float4 a = *(const float4*)p;
        float4 bq = *(const float4*)(p + 4);
        float h[8] = {a.x, a.y, a.z, a.w, bq.x, bq.y, bq.z, bq.w};
        short8 ah, al;
#pragma unroll
        for (int j = 0; j < 8; j++) {
            float v = h[j];
            ushort_t hb = f2us_tr(v);
            float lo = v - us2f(hb);
            ah[j] = (short)hb;
            al[j] = (short)f2us_tr(lo);
        }
        Ahi[st] = ah; Alo[st] = al;
    }

    const float* bs_[4] = {b0, b1, b2, b3};

#pragma unroll
    for (int mat = 0; mat < 4; mat++) {
        const ushort_t* Bh = Whi + (mat * 256 + nsl * 64) * IN;
        const ushort_t* Bl = Wlo + (mat * 256 + nsl * 64) * IN;
        fx4 G[4];
#pragma unroll
        for (int tile = 0; tile < 4; tile++) {
            float bc = bs_[mat][nsl * 64 + tile * 16 + nl];
            G[tile] = (fx4){bc, bc, bc, bc};
        }
#pragma unroll
        for (int st = 0; st < ST; st++) {
            int koff = quad * 8 + 32 * st;
#pragma unroll
            for (int tile = 0; tile < 4; tile++) {
                int off = (tile * 16 + nl) * IN + (koff ^ (nl * 8));
                short8 bh8 = *(const short8*)(Bh + off);
                short8 bl8 = *(const short8*)(Bl + off);
                G[tile] = __builtin_amdgcn_mfma_f32_16x16x32_bf16(Ahi[st], bh8, G[tile], 0, 0, 0);
                G[tile] = __builtin_amdgcn_mfma_f32_16x16x32_bf16(Alo[st], bh8, G[tile], 0, 0, 0);
                G[tile] = __builtin_amdgcn_mfma_f32_16x16x32_bf16(Ahi[st], bl8, G[tile], 0, 0, 0);
            }
        }
        int row0 = m0 + wv * 16 + quad * 4;          // rows r=0..3
        if (mat == 0 || mat == 3) {
            float* om = (mat == 0) ? q : skipo;
#pragma unroll
            for (int tile = 0; tile < 4; tile++)
#pragma unroll
                for (int r = 0; r < 4; r++)
                    om[(row0 + r) * HD + nsl * 64 + tile * 16 + nl] = G[tile][r];
        } else if (mat == 1) {
            // K planes, layout [row=b*128+s][256]
#pragma unroll
            for (int tile = 0; tile < 4; tile++) {
                int col = nsl * 64 + tile * 16 + nl;
#pragma unroll
                for (int r = 0; r < 4; r++) {
                    float gv = G[tile][r];
                    ushort_t hb = f2us_tr(gv);
                    khi[(row0 + r) * HD + col] = hb;
                    klo[(row0 + r) * HD + col] = f2us_tr(gv - us2f(hb));
                }
            }
        } else {
            // vT planes: vT[dg = b*256 + col][128 s], 4 consecutive s packed
            int bb = row0 >> 7;
            int s0 = row0 & 127;
#pragma unroll
            for (int tile = 0; tile < 4; tile++) {
                int col = nsl * 64 + tile * 16 + nl;
                int dg = bb * 256 + col;
                ushort4 h4, l4;
                float g0 = G[tile][0], g1 = G[tile][1], g2 = G[tile][2], g3 = G[tile][3];
                ushort_t h0 = f2us_tr(g0), h1 = f2us_tr(g1), h2 = f2us_tr(g2), h3 = f2us_tr(g3);
                h4.x = h0; h4.y = h1; h4.z = h2; h4.w = h3;
                l4.x = f2us_tr(g0 - us2f(h0));
                l4.y = f2us_tr(g1 - us2f(h1));
                l4.z = f2us_tr(g2 - us2f(h2));
                l4.w = f2us_tr(g3 - us2f(h3));
                *(ushort4*)&vThi[dg * NN + s0] = h4;
                *(ushort4*)&vTlo[dg * NN + s0] = l4;
            }
        }
    }
}

// ---------------- K6: attention via MFMA, 1 wave per (b,h,16-t tile) -------
__global__ void __launch_bounds__(64) k_attn_mfma(
    const float* qb, const ushort_t* khi, const ushort_t* klo,
    const ushort_t* vThi, const ushort_t* vTlo,
    const float* adjvT, const float* We, const float* skip, float* xout)
{
    __shared__ float aL[16][132];     // alpha C->A round-trip (8.4 KB)
    __shared__ float qeL[16];

    int blk = blockIdx.x;             // 1024 = 32b*4h*8tt
    int b  = blk >> 5;
    int h  = (blk >> 3) & 3;
    int tt = blk & 7;
    int t0 = tt * 16;
    int lane = threadIdx.x;
    int nl = lane & 15;
    int quad = lane >> 4;

    // ---- Q A-frags (split hi/lo) + qe partial (q . we) ----
    short8 Qhi[2], Qlo[2];
    float qe = 0.f;
#pragma unroll
    for (int ks = 0; ks < 2; ks++) {
        const float* p = qb + (b * NN + t0 + nl) * HD + h * DHEAD + quad * 8 + 32 * ks;
        const float* wp = We + h * DHEAD + quad * 8 + 32 * ks;
        float4 a0 = *(const float4*)p;
        float4 a1 = *(const float4*)(p + 4);
        float4 w0 = *(const float4*)wp;
        float4 w1 = *(const float4*)(wp + 4);
        float hv[8] = {a0.x, a0.y, a0.z, a0.w, a1.x, a1.y, a1.z, a1.w};
        float wv8[8] = {w0.x, w0.y, w0.z, w0.w, w1.x, w1.y, w1.z, w1.w};
        short8 ah, al;
#pragma unroll
        for (int j = 0; j < 8; j++) {
            float v = hv[j];
            ushort_t hb = f2us_tr(v);
            ah[j] = (short)hb;
            al[j] = (short)f2us_tr(v - us2f(hb));
            qe += v * wv8[j];
        }
        Qhi[ks] = ah; Qlo[ks] = al;
    }
    qe += __shfl_xor(qe, 16);
    qe += __shfl_xor(qe, 32);
    if (lane < 16) qeL[lane] = qe;    // qe for t = lane
    __syncthreads();
    float qe_r[4];
#pragma unroll
    for (int r = 0; r < 4; r++) qe_r[r] = qeL[quad * 4 + r];
    float we_d[4];
#pragma unroll
    for (int nt = 0; nt < 4; nt++) we_d[nt] = We[h * DHEAD + nt * 16 + nl];

    // ---- QK^T: S[t][s], 8 s-tiles ----
    fx4 S[8];
#pragma unroll
    for (int st = 0; st < 8; st++) S[st] = (fx4){0.f, 0.f, 0.f, 0.f};
#pragma unroll
    for (int ks = 0; ks < 2; ks++) {
#pragma unroll
        for (int st = 0; st < 8; st++) {
            long off = (long)(b * NN + st * 16 + nl) * HD + h * DHEAD + quad * 8 + 32 * ks;
            short8 bh8 = *(const short8*)(khi + off);
            short8 bl8 = *(const short8*)(klo + off);
            S[st] = __builtin_amdgcn_mfma_f32_16x16x32_bf16(Qhi[ks], bh8, S[st], 0, 0, 0);
            S[st] = __builtin_amdgcn_mfma_f32_16x16x32_bf16(Qlo[ks], bh8, S[st], 0, 0, 0);
            S[st] = __builtin_amdgcn_mfma_f32_16x16x32_bf16(Qhi[ks], bl8, S[st], 0, 0, 0);
        }
    }

    // ---- masked logits (D-layout: row t = quad*4+r, col s = st*16+nl) ----
    float av[8][4];
#pragma unroll
    for (int st = 0; st < 8; st++)
#pragma unroll
        for (int r = 0; r < 4; r++)
            av[st][r] = adjvT[(b * NN + t0 + quad * 4 + r) * NN + st * 16 + nl];
#pragma unroll
    for (int st = 0; st < 8; st++)
#pragma unroll
        for (int r = 0; r < 4; r++) {
            float a = av[st][r];
            S[st][r] = (a != 0.f) ? (S[st][r] + a * qe_r[r]) * 0.125f : -1e30f;
        }

    // ---- softmax per row: reduce over s = in-lane stiles + xor{1,2,4,8} ----
    float mx[4], den[4], beta[4];
#pragma unroll
    for (int r = 0; r < 4; r++) {
        float m = S[0][r];
#pragma unroll
        for (int st = 1; st < 8; st++) m = fmaxf(m, S[st][r]);
#pragma unroll
        for (int mm = 1; mm < 16; mm <<= 1) m = fmaxf(m, __shfl_xor(m, mm));
        mx[r] = m;
    }
#pragma unroll
    for (int r = 0; r < 4; r++) den[r] = 0.f;
#pragma unroll
    for (int st = 0; st < 8; st++)
#pragma unroll
        for (int r = 0; r < 4; r++) {
            float e = (av[st][r] != 0.f) ? __expf(S[st][r] - mx[r]) : 0.f;
            S[st][r] = e;
            den[r] += e;
        }
#pragma unroll
    for (int r = 0; r < 4; r++) {
#pragma unroll
        for (int mm = 1; mm < 16; mm <<= 1) den[r] += __shfl_xor(den[r], mm);
        den[r] = 1.f / fmaxf(den[r], 1e-16f);
        beta[r] = 0.f;
    }
#pragma unroll
    for (int st = 0; st < 8; st++)
#pragma unroll
        for (int r = 0; r < 4; r++) {
            float al = S[st][r] * den[r];
            S[st][r] = al;
            beta[r] += al * av[st][r];
        }
#pragma unroll
    for (int r = 0; r < 4; r++)
#pragma unroll
        for (int mm = 1; mm < 16; mm <<= 1) beta[r] += __shfl_xor(beta[r], mm);

    // ---- alpha C-layout -> LDS -> A-layout frags (hi only) ----
#pragma unroll
    for (int st = 0; st < 8; st++)
#pragma unroll
        for (int r = 0; r < 4; r++)
            aL[quad * 4 + r][st * 16 + nl] = S[st][r];
    __syncthreads();
    short8 Ah[4];
#pragma unroll
    for (int ks = 0; ks < 4; ks++) {
        const float* p = &aL[nl][quad * 8 + 32 * ks];
        float4 a0 = *(const float4*)p;
        float4 a1 = *(const float4*)(p + 4);
        float hv[8] = {a0.x, a0.y, a0.z, a0.w, a1.x, a1.y, a1.z, a1.w};
        short8 ah;
#pragma unroll
        for (int j = 0; j < 8; j++) ah[j] = (short)f2us_tr(hv[j]);
        Ah[ks] = ah;
    }

    // ---- PV: out[t][d] = beta*we + alpha @ V (V via vT planes) ----
    fx4 G[4];
#pragma unroll
    for (int nt = 0; nt < 4; nt++) {
        fx4 g;
#pragma unroll
        for (int r = 0; r < 4; r++) g[r] = beta[r] * we_d[nt];
        G[nt] = g;
    }
#pragma unroll
    for (int ks = 0; ks < 4; ks++) {
#pragma unroll
        for (int nt = 0; nt < 4; nt++) {
            long dg = (long)(b * 256 + h * DHEAD + nt * 16 + nl);
            const short8 vh = *(const short8*)(vThi + dg * NN + quad * 8 + 32 * ks);
            const short8 vl = *(const short8*)(vTlo + dg * NN + quad * 8 + 32 * ks);
            G[nt] = __builtin_amdgcn_mfma_f32_16x16x32_bf16(Ah[ks], vh, G[nt], 0, 0, 0);
            G[nt] = __builtin_amdgcn_mfma_f32_16x16x32_bf16(Ah[ks], vl, G[nt], 0, 0, 0);
        }
    }

    // ---- epilogue: relu(out + skip) ----
#pragma unroll
    for (int nt = 0; nt < 4; nt++)
#pragma unroll
        for (int r = 0; r < 4; r++) {
            int gi = (b * NN + t0 + quad * 4 + r) * HD + h * DHEAD + nt * 16 + nl;
            xout[gi] = fmaxf(G[nt][r] + skip[gi], 0.f);
        }
}

// ---------------- K8: gather agent rows -> f32 out ----------------
__global__ void k_gather(const float* x2, const int* agent, float* out) {
    int b = blockIdx.x;
    int c = threadIdx.x;
    out[b * HD + c] = x2[(b * NN + agent[b]) * HD + c];
}

// ---------------- launch ----------------
extern "C" void kernel_launch(void* const* d_in, const int* in_sizes, int n_in,
                              void* d_out, int out_size, void* d_ws, size_t ws_size,
                              hipStream_t stream) {
    float* out = (float*)d_out;
    (void)hipGetLastError();

    bool ok = (n_in == 31) && in_sizes[0] == BB * NN * FF && in_sizes[2] == BB * NN * NN
              && in_sizes[5] == (FF + EE + 1) * HH && in_sizes[13] == HH * HD
              && in_sizes[22] == HD * HD && out_size == BB * HD;
    if (!ok) { k_sent<<<32, 256, 0, stream>>>(out, -30000.f); return; }

    const size_t WS_NEED = (size_t)8912896 * 4;
    if (ws_size < WS_NEED) { k_sent<<<32, 256, 0, stream>>>(out, -20000.f); return; }

    const float* nf    = (const float*)d_in[0];
    const int*   et    = (const int*)d_in[1];
    const float* adj   = (const float*)d_in[2];
    const int*   agent = (const int*)d_in[3];
    const float* emb   = (const float*)d_in[4];
    const float* W1    = (const float*)d_in[5];
    const float* b1    = (const float*)d_in[6];
    const float* g1    = (const float*)d_in[7];
    const float* be1   = (const float*)d_in[8];
    const float* Wh    = (const float*)d_in[9];
    const float* bh    = (const float*)d_in[10];
    const float* gh    = (const float*)d_in[11];
    const float* beh   = (const float*)d_in[12];
    const float* Wq1   = (const float*)d_in[13];
    const float* bq1   = (const float*)d_in[14];
    const float* Wk1   = (const float*)d_in[15];
    const float* bk1   = (const float*)d_in[16];
    const float* Wv1   = (const float*)d_in[17];
    const float* bv1   = (const float*)d_in[18];
    const float* We1   = (const float*)d_in[19];
    const float* Ws1   = (const float*)d_in[20];
    const float* bs1   = (const float*)d_in[21];
    const float* Wq2   = (const float*)d_in[22];
    const float* bq2   = (const float*)d_in[23];
    const float* Wk2   = (const float*)d_in[24];
    const float* bk2   = (const float*)d_in[25];
    const float* Wv2   = (const float*)d_in[26];
    const float* bv2   = (const float*)d_in[27];
    const float* We2   = (const float*)d_in[28];
    const float* Ws2   = (const float*)d_in[29];
    const float* bs2   = (const float*)d_in[30];

    float* ws   = (float*)d_ws;
    float* adjv = ws;                              // 524288 f
    float* base = adjv + BB * NN * NN;             // 524288 f
    float* x0   = base + BB * NN * HH;             // 524288 f
    float* q    = x0 + BB * NN * HH;               // 1048576 f
    float* kreg = q + BB * NN * HD;                // 1048576 f -> khi/klo
    float* vreg = kreg + BB * NN * HD;             // 1048576 f -> vThi/vTlo
    float* skip = vreg + BB * NN * HD;             // 1048576 f
    float* areg = skip + BB * NN * HD;             // 1048576 f -> weight planes + adjvT
    float* x1   = areg + BB * NN * HD;
    float* x2   = x1 + BB * NN * HD;

    // econv prep planes in q region (q first written AFTER econv)
    ushort_t* BhiG = (ushort_t*)q;
    ushort_t* BloG = BhiG + HH * HH;
    float*    W1sW = q + 16384;
    float*    cbW  = q + 16512;

    // K / vT planes
    ushort_t* khi  = (ushort_t*)kreg;              // 1048576 ush
    ushort_t* klo  = khi + BB * NN * HD;           // 1048576 ush
    ushort_t* vThi = (ushort_t*)vreg;
    ushort_t* vTlo = vThi + BB * NN * HD;

    // qkvs weight planes + adjvT in areg (4 MB): 1.5 MB planes + 2 MB adjvT
    ushort_t* WhA = (ushort_t*)areg;               // 4*256*128 ush
    ushort_t* WlA = WhA + 4 * 256 * HH;
    ushort_t* WhB = WlA + 4 * 256 * HH;            // 4*256*256 ush
    ushort_t* WlB = WhB + 4 * 256 * HD;
    float* adjvT  = areg + 393216;                 // 524288 f, past planes

    int fail = 0;
    hipError_t e;
#define CHK(stage) do { e = hipGetLastError(); if (e != hipSuccess && fail == 0) fail = (stage); } while (0)

    k_adjv<<<BB, 256, 0, stream>>>(adj, adjv, adjvT);                                CHK(1);
    k_base<<<BB * NN, HH, 0, stream>>>(nf, et, emb, W1, b1, base);                   CHK(2);
    k_zero<<<BB * NN * HH / 256, 256, 0, stream>>>(x0);                              CHK(3);
    k_prep<<<HH, 64, 0, stream>>>(Wh, g1, be1, bh, BhiG, BloG, W1sW, cbW);           CHK(4);
    k_prepw<<<1024, 64, 0, stream>>>(Wq1, Wk1, Wv1, Ws1, HH, WhA, WlA);              CHK(5);
    k_prepw<<<1024, 64, 0, stream>>>(Wq2, Wk2, Wv2, Ws2, HD, WhB, WlB);              CHK(6);
    k_econv_mfma<<<512, 256, 0, stream>>>(adjv, base, W1, BhiG, BloG, W1sW, cbW,
                                          gh, beh, x0);                              CHK(7);

    k_qkvs_mfma<HH><<<256, 256, 0, stream>>>(x0, WhA, WlA, bq1, bk1, bv1, bs1,
                                             q, skip, khi, klo, vThi, vTlo);         CHK(8);
    k_attn_mfma<<<1024, 64, 0, stream>>>(q, khi, klo, vThi, vTlo, adjvT, We1,
                                         skip, x1);                                  CHK(9);

    k_qkvs_mfma<HD><<<256, 256, 0, stream>>>(x1, WhB, WlB, bq2, bk2, bv2, bs2,
                                             q, skip, khi, klo, vThi, vTlo);         CHK(10);
    k_attn_mfma<<<1024, 64, 0, stream>>>(q, khi, klo, vThi, vTlo, adjvT, We2,
                                         skip, x2);                                  CHK(11);

    k_gather<<<BB, HD, 0, stream>>>(x2, agent, out);                                 CHK(12);
#undef CHK

    if (fail != 0)
        k_sent<<<32, 256, 0, stream>>>(out, -(1000.f + 500.f * (float)fail));
}

// Round 3
// 336.201 us; speedup vs baseline: 1.6847x; 1.5369x over previous
//
#include <hip/hip_runtime.h>
#include <hip/hip_bf16.h>

typedef __hip_bfloat16 bf16;
typedef unsigned short ushort_t;
typedef __attribute__((ext_vector_type(8))) short short8;
typedef __attribute__((ext_vector_type(4))) float fx4;

#define BB 32
#define NN 128
#define FF 9
#define EE 8
#define HH 128
#define HD 256
#define NHEAD 4
#define DHEAD 64

__device__ __forceinline__ float us2f(ushort_t u) {
    return __uint_as_float(((unsigned int)u) << 16);
}
// truncation split: hi = trunc16(v), lo = v - hi (lo exact in f32)
__device__ __forceinline__ ushort_t f2us_tr(float f) {
    return (ushort_t)(__float_as_uint(f) >> 16);
}

__global__ void TransformerConvNet_85315230367963_kernel() {}

__global__ void k_sent(float* out, float val) {
    out[blockIdx.x * 256 + threadIdx.x] = val;
}

__global__ void k_zero(float* p) {
    p[blockIdx.x * 256 + threadIdx.x] = 0.f;
}

// ---------------- K1: adjv + adjvT (masked) ----------------
__global__ void k_adjv(const float* adj, float* adjv, float* adjvT) {
    int b = blockIdx.x;            // 32
    const float* src = adj + b * NN * NN;
    float* d1 = adjv + b * NN * NN;
    float* d2 = adjvT + b * NN * NN;
    for (int i = threadIdx.x; i < NN * NN; i += 256) {
        float a = src[i];
        d1[i] = (a > 0.f && a < 1.0f) ? a : 0.f;
    }
    for (int i = threadIdx.x; i < NN * NN; i += 256) {
        int t = i >> 7, s = i & 127;
        float a = src[s * NN + t];
        d2[i] = (a > 0.f && a < 1.0f) ? a : 0.f;   // adjvT[t][s]
    }
}

// ---------------- K2: base[bs][c] = src(bs) @ W1[:17] + b1 ----------------
__global__ void k_base(const float* nf, const int* et, const float* emb,
                       const float* W1, const float* b1, float* base) {
    int bs = blockIdx.x;
    int c = threadIdx.x;
    int ty = et[bs];
    float acc = b1[c];
    for (int f = 0; f < FF; f++)
        acc += nf[bs * FF + f] * W1[f * HH + c];
    for (int e = 0; e < EE; e++)
        acc += emb[ty * EE + e] * W1[(FF + e) * HH + c];
    base[bs * HH + c] = acc;
}

// ---------------- K_prep: Wh' = g1*Wh split bf16 hi/lo, swizzled ----------
__global__ void k_prep(const float* Wh, const float* g1, const float* be1,
                       const float* bh, ushort_t* BhiG, ushort_t* BloG,
                       float* W1s, float* cbv) {
    int n = blockIdx.x;      // 0..127
    int t = threadIdx.x;     // 0..63
    int sw = 8 * (n & 15);
    float s1 = 0.f, s2 = 0.f;
    for (int kk = 0; kk < 2; kk++) {
        int k = t + kk * 64;
        float w = Wh[k * HH + n];
        float wp = g1[k] * w;
        ushort_t hb = f2us_tr(wp);
        float lo = wp - us2f(hb);
        BhiG[n * HH + (k ^ sw)] = hb;
        BloG[n * HH + (k ^ sw)] = f2us_tr(lo);
        s1 += wp;
        s2 += be1[k] * w;
    }
    for (int m = 1; m < 64; m <<= 1) {
        s1 += __shfl_xor(s1, m);
        s2 += __shfl_xor(s2, m);
    }
    if (t == 0) { W1s[n] = s1; cbv[n] = s2 + bh[n]; }
}

// ---------------- K_prepw: split 4 qkvs weight mats into bf16 hi/lo -------
__global__ void k_prepw(const float* W0, const float* W1p, const float* W2p,
                        const float* W3p, int IN, ushort_t* Whi, ushort_t* Wlo) {
    int blk = blockIdx.x;             // 4*256
    int mat = blk >> 8, n = blk & 255;
    const float* W = (mat == 0) ? W0 : (mat == 1) ? W1p : (mat == 2) ? W2p : W3p;
    ushort_t* hi = Whi + mat * 256 * IN;
    ushort_t* lo = Wlo + mat * 256 * IN;
    int sw = 8 * (n & 15);
    for (int k = threadIdx.x; k < IN; k += 64) {
        float w = W[k * HD + n];
        ushort_t hb = f2us_tr(w);
        float l = w - us2f(hb);
        hi[n * IN + (k ^ sw)] = hb;
        lo[n * IN + (k ^ sw)] = f2us_tr(l);
    }
}

// ---------------- K3: embed conv, MFMA, SWAPPED operands ------------------
// D[n][t] = Wh'^T (LDS, A-op) x raw relu(h1)^T (regs, B-op).  B col = t = nl
// -> LN1/LN2 stats lane-local.  LN1 applied POST-mfma via W1s correction:
//   pre2 = r1*Graw + nm*W1s[n] + cb[n]   (nm = -m1*r1)  -- round-0 algebra.
// One-pass operand build (no v[][] array), W1s/cb reloaded per tile (L1-hot)
// => minimal register demand; plain launch_bounds so the allocator NEVER
// spills to scratch (rounds 1-2: forced (256,2) cap => 800 MB spill traffic).
__global__ void __launch_bounds__(256) k_econv_mfma(
    const float* adjv, const float* base, const float* W1,
    const ushort_t* BhiG, const ushort_t* BloG,
    const float* W1sg, const float* cbv,
    const float* ghp, const float* behp, float* x0)
{
    __shared__ __align__(16) ushort_t PhiPlo[2 * HH * HH];   // 64 KB
    ushort_t* Phi = PhiPlo;
    ushort_t* Plo = PhiPlo + HH * HH;

    int blk = blockIdx.x;
    int b  = blk >> 4;
    int tt = (blk >> 1) & 7;
    int sh = blk & 1;
    int t0 = tt * 16;
    int tid = threadIdx.x;
    int wv  = tid >> 6;
    int lane = tid & 63;
    int nl = lane & 15;
    int quad = lane >> 4;

    {
        const uint4* srcH = (const uint4*)BhiG;
        const uint4* srcL = (const uint4*)BloG;
        uint4* dstH = (uint4*)Phi;
        uint4* dstL = (uint4*)Plo;
        for (int i = tid; i < HH * HH / 8; i += 256) {
            dstH[i] = srcH[i];
            dstL[i] = srcL[i];
        }
    }

    float w17v[4][8];
#pragma unroll
    for (int st = 0; st < 4; st++) {
        const float* p = W1 + 17 * HH + quad * 8 + 32 * st;
        float4 a = *(const float4*)p;
        float4 bq = *(const float4*)(p + 4);
        w17v[st][0] = a.x;  w17v[st][1] = a.y;  w17v[st][2] = a.z;  w17v[st][3] = a.w;
        w17v[st][4] = bq.x; w17v[st][5] = bq.y; w17v[st][6] = bq.z; w17v[st][7] = bq.w;
    }

    fx4 acc1[8];                 // sum_s mask*r2*h2   (per n, per t=nl)
#pragma unroll
    for (int tile = 0; tile < 8; tile++) acc1[tile] = (fx4){0.f, 0.f, 0.f, 0.f};
    float c0 = 0.f;              // sum_s mask
    float c1 = 0.f;              // sum_s mask*r2*mean2

    __syncthreads();

    for (int i = 0; i < 16; i++) {
        int s = sh * 64 + wv * 16 + i;
        const float* brow = base + (b * NN + s) * HH;
        float avv = adjv[(b * NN + s) * NN + t0 + nl];   // t = t0 + nl

        // one pass: vv = relu(base + avv*w17); stats + raw bf16 hi/lo split
        short8 Hhi[4], Hlo[4];
        float sm = 0.f, s2 = 0.f;
#pragma unroll
        for (int st = 0; st < 4; st++) {
            const float* p = brow + quad * 8 + 32 * st;
            float4 b0 = *(const float4*)p;
            float4 b1q = *(const float4*)(p + 4);
            float h[8] = {b0.x, b0.y, b0.z, b0.w, b1q.x, b1q.y, b1q.z, b1q.w};
            short8 ah, al;
#pragma unroll
            for (int j = 0; j < 8; j++) {
                float vv = fmaxf(fmaf(avv, w17v[st][j], h[j]), 0.f);
                sm += vv;
                s2 = fmaf(vv, vv, s2);
                ushort_t hb = f2us_tr(vv);
                ah[j] = (short)hb;
                al[j] = (short)f2us_tr(vv - us2f(hb));
            }
            Hhi[st] = ah; Hlo[st] = al;
        }
        sm += __shfl_xor(sm, 16); sm += __shfl_xor(sm, 32);
        s2 += __shfl_xor(s2, 16); s2 += __shfl_xor(s2, 32);
        float m1 = sm * (1.f / 128.f);
        float r1 = rsqrtf(s2 * (1.f / 128.f) - m1 * m1 + 1e-5f);
        float nm = -m1 * r1;

        // Graw = Wh'^T @ vv
        fx4 G[8];
#pragma unroll
        for (int tile = 0; tile < 8; tile++) G[tile] = (fx4){0.f, 0.f, 0.f, 0.f};
#pragma unroll
        for (int st = 0; st < 4; st++) {
            int koff = quad * 8 + 32 * st;
#pragma unroll
            for (int tile = 0; tile < 8; tile++) {
                int off = (tile * 16 + nl) * HH + (koff ^ (nl * 8));
                short8 ph = *(const short8*)(&Phi[off]);
                short8 pl = *(const short8*)(&Plo[off]);
                G[tile] = __builtin_amdgcn_mfma_f32_16x16x32_bf16(ph, Hhi[st], G[tile], 0, 0, 0);
                G[tile] = __builtin_amdgcn_mfma_f32_16x16x32_bf16(pl, Hhi[st], G[tile], 0, 0, 0);
                G[tile] = __builtin_amdgcn_mfma_f32_16x16x32_bf16(ph, Hlo[st], G[tile], 0, 0, 0);
            }
        }

        // LN1 correction + relu; LN2 stats (in-lane over 32 n + 2 shuffles)
        float sm2 = 0.f, ss2 = 0.f;
#pragma unroll
        for (int tile = 0; tile < 8; tile++) {
            float4 w4 = *(const float4*)(W1sg + tile * 16 + quad * 4);
            float4 c4 = *(const float4*)(cbv + tile * 16 + quad * 4);
            float wa[4] = {w4.x, w4.y, w4.z, w4.w};
            float ca[4] = {c4.x, c4.y, c4.z, c4.w};
#pragma unroll
            for (int r = 0; r < 4; r++) {
                float pre = fmaf(r1, G[tile][r], fmaf(nm, wa[r], ca[r]));
                float h2 = fmaxf(pre, 0.f);
                G[tile][r] = h2;
                sm2 += h2;
                ss2 = fmaf(h2, h2, ss2);
            }
        }
        sm2 += __shfl_xor(sm2, 16); sm2 += __shfl_xor(sm2, 32);
        ss2 += __shfl_xor(ss2, 16); ss2 += __shfl_xor(ss2, 32);
        float mean2 = sm2 * (1.f / 128.f);
        float r2 = rsqrtf(ss2 * (1.f / 128.f) - mean2 * mean2 + 1e-5f);
        float msk = (avv != 0.f) ? 1.f : 0.f;
        float mr2 = msk * r2;

#pragma unroll
        for (int tile = 0; tile < 8; tile++)
#pragma unroll
            for (int r = 0; r < 4; r++)
                acc1[tile][r] = fmaf(mr2, G[tile][r], acc1[tile][r]);
        c0 += msk;
        c1 = fmaf(mr2, mean2, c1);
    }

    // ---- epilogue: xv = gh*(acc1 - c1) + beh*c0 ;  cross-wave LDS reduce,
    //      then coalesced atomics (consecutive lanes -> consecutive n) ----
    __syncthreads();                       // Phi/Plo dead; reuse as f32 slab
    float* slab = (float*)PhiPlo;          // [4 waves][16 t][stride 132]
#pragma unroll
    for (int tile = 0; tile < 8; tile++) {
        float4 g4 = *(const float4*)(ghp + tile * 16 + quad * 4);
        float4 be4 = *(const float4*)(behp + tile * 16 + quad * 4);
        float gv[4] = {g4.x, g4.y, g4.z, g4.w};
        float bv[4] = {be4.x, be4.y, be4.z, be4.w};
#pragma unroll
        for (int r = 0; r < 4; r++) {
            float xv = fmaf(gv[r], acc1[tile][r] - c1, bv[r] * c0);
            slab[(wv * 16 + nl) * 132 + tile * 16 + quad * 4 + r] = xv;
        }
    }
    __syncthreads();
    for (int e = tid; e < 16 * HH; e += 256) {
        int t = e >> 7, n = e & 127;
        float vsum = slab[t * 132 + n] + slab[(16 + t) * 132 + n]
                   + slab[(32 + t) * 132 + n] + slab[(48 + t) * 132 + n];
        atomicAdd(&x0[(b * NN + t0 + t) * HH + n], vsum);
    }
}

// ---------------- K5: qkvs via MFMA; emits q/skip f32, K planes, vT planes -
template <int IN>
__global__ void __launch_bounds__(256) k_qkvs_mfma(
    const float* x, const ushort_t* Whi, const ushort_t* Wlo,
    const float* b0, const float* b1, const float* b2, const float* b3,
    float* q, float* skipo,
    ushort_t* khi, ushort_t* klo, ushort_t* vThi, ushort_t* vTlo)
{
    const int ST = IN / 32;
    int blk = blockIdx.x;
    int m0 = (blk >> 2) * 64;
    int nsl = blk & 3;
    int tid = threadIdx.x;
    int wv = tid >> 6;
    int lane = tid & 63;
    int nl = lane & 15;
    int quad = lane >> 4;
    int row = m0 + wv * 16 + nl;

    short8 Ahi[ST], Alo[ST];
    const float* xrow = x + (long)row * IN;
#pragma unroll
    for (int st = 0; st < ST; st++) {
        const float* p = xrow + quad * 8 + 32 * st;
        float4 a = *(const float4*)p;
        float4 bq = *(const float4*)(p + 4);
        float h[8] = {a.x, a.y, a.z, a.w, bq.x, bq.y, bq.z, bq.w};
        short8 ah, al;
#pragma unroll
        for (int j = 0; j < 8; j++) {
            float v = h[j];
            ushort_t hb = f2us_tr(v);
            float lo = v - us2f(hb);
            ah[j] = (short)hb;
            al[j] = (short)f2us_tr(lo);
        }
        Ahi[st] = ah; Alo[st] = al;
    }

    const float* bs_[4] = {b0, b1, b2, b3};

#pragma unroll
    for (int mat = 0; mat < 4; mat++) {
        const ushort_t* Bh = Whi + (mat * 256 + nsl * 64) * IN;
        const ushort_t* Bl = Wlo + (mat * 256 + nsl * 64) * IN;
        fx4 G[4];
#pragma unroll
        for (int tile = 0; tile < 4; tile++) {
            float bc = bs_[mat][nsl * 64 + tile * 16 + nl];
            G[tile] = (fx4){bc, bc, bc, bc};
        }
#pragma unroll
        for (int st = 0; st < ST; st++) {
            int koff = quad * 8 + 32 * st;
#pragma unroll
            for (int tile = 0; tile < 4; tile++) {
                int off = (tile * 16 + nl) * IN + (koff ^ (nl * 8));
                short8 bh8 = *(const short8*)(Bh + off);
                short8 bl8 = *(const short8*)(Bl + off);
                G[tile] = __builtin_amdgcn_mfma_f32_16x16x32_bf16(Ahi[st], bh8, G[tile], 0, 0, 0);
                G[tile] = __builtin_amdgcn_mfma_f32_16x16x32_bf16(Alo[st], bh8, G[tile], 0, 0, 0);
                G[tile] = __builtin_amdgcn_mfma_f32_16x16x32_bf16(Ahi[st], bl8, G[tile], 0, 0, 0);
            }
        }
        int row0 = m0 + wv * 16 + quad * 4;          // rows r=0..3
        if (mat == 0 || mat == 3) {
            float* om = (mat == 0) ? q : skipo;
#pragma unroll
            for (int tile = 0; tile < 4; tile++)
#pragma unroll
                for (int r = 0; r < 4; r++)
                    om[(row0 + r) * HD + nsl * 64 + tile * 16 + nl] = G[tile][r];
        } else if (mat == 1) {
            // K planes, layout [row=b*128+s][256]
#pragma unroll
            for (int tile = 0; tile < 4; tile++) {
                int col = nsl * 64 + tile * 16 + nl;
#pragma unroll
                for (int r = 0; r < 4; r++) {
                    float gv = G[tile][r];
                    ushort_t hb = f2us_tr(gv);
                    khi[(row0 + r) * HD + col] = hb;
                    klo[(row0 + r) * HD + col] = f2us_tr(gv - us2f(hb));
                }
            }
        } else {
            // vT planes: vT[dg = b*256 + col][128 s], 4 consecutive s packed
            int bb = row0 >> 7;
            int s0 = row0 & 127;
#pragma unroll
            for (int tile = 0; tile < 4; tile++) {
                int col = nsl * 64 + tile * 16 + nl;
                int dg = bb * 256 + col;
                ushort4 h4, l4;
                float g0 = G[tile][0], g1 = G[tile][1], g2 = G[tile][2], g3 = G[tile][3];
                ushort_t h0 = f2us_tr(g0), h1 = f2us_tr(g1), h2 = f2us_tr(g2), h3 = f2us_tr(g3);
                h4.x = h0; h4.y = h1; h4.z = h2; h4.w = h3;
                l4.x = f2us_tr(g0 - us2f(h0));
                l4.y = f2us_tr(g1 - us2f(h1));
                l4.z = f2us_tr(g2 - us2f(h2));
                l4.w = f2us_tr(g3 - us2f(h3));
                *(ushort4*)&vThi[dg * NN + s0] = h4;
                *(ushort4*)&vTlo[dg * NN + s0] = l4;
            }
        }
    }
}

// ---------------- K6: attention via MFMA, 1 wave per (b,h,16-t tile) -------
__global__ void __launch_bounds__(64) k_attn_mfma(
    const float* qb, const ushort_t* khi, const ushort_t* klo,
    const ushort_t* vThi, const ushort_t* vTlo,
    const float* adjvT, const float* We, const float* skip, float* xout)
{
    __shared__ float aL[16][132];     // alpha C->A round-trip (8.4 KB)
    __shared__ float qeL[16];

    int blk = blockIdx.x;             // 1024 = 32b*4h*8tt
    int b  = blk >> 5;
    int h  = (blk >> 3) & 3;
    int tt = blk & 7;
    int t0 = tt * 16;
    int lane = threadIdx.x;
    int nl = lane & 15;
    int quad = lane >> 4;

    // ---- Q A-frags (split hi/lo) + qe partial (q . we) ----
    short8 Qhi[2], Qlo[2];
    float qe = 0.f;
#pragma unroll
    for (int ks = 0; ks < 2; ks++) {
        const float* p = qb + (b * NN + t0 + nl) * HD + h * DHEAD + quad * 8 + 32 * ks;
        const float* wp = We + h * DHEAD + quad * 8 + 32 * ks;
        float4 a0 = *(const float4*)p;
        float4 a1 = *(const float4*)(p + 4);
        float4 w0 = *(const float4*)wp;
        float4 w1 = *(const float4*)(wp + 4);
        float hv[8] = {a0.x, a0.y, a0.z, a0.w, a1.x, a1.y, a1.z, a1.w};
        float wv8[8] = {w0.x, w0.y, w0.z, w0.w, w1.x, w1.y, w1.z, w1.w};
        short8 ah, al;
#pragma unroll
        for (int j = 0; j < 8; j++) {
            float v = hv[j];
            ushort_t hb = f2us_tr(v);
            ah[j] = (short)hb;
            al[j] = (short)f2us_tr(v - us2f(hb));
            qe += v * wv8[j];
        }
        Qhi[ks] = ah; Qlo[ks] = al;
    }
    qe += __shfl_xor(qe, 16);
    qe += __shfl_xor(qe, 32);
    if (lane < 16) qeL[lane] = qe;    // qe for t = lane
    __syncthreads();
    float qe_r[4];
#pragma unroll
    for (int r = 0; r < 4; r++) qe_r[r] = qeL[quad * 4 + r];
    float we_d[4];
#pragma unroll
    for (int nt = 0; nt < 4; nt++) we_d[nt] = We[h * DHEAD + nt * 16 + nl];

    // ---- QK^T: S[t][s], 8 s-tiles ----
    fx4 S[8];
#pragma unroll
    for (int st = 0; st < 8; st++) S[st] = (fx4){0.f, 0.f, 0.f, 0.f};
#pragma unroll
    for (int ks = 0; ks < 2; ks++) {
#pragma unroll
        for (int st = 0; st < 8; st++) {
            long off = (long)(b * NN + st * 16 + nl) * HD + h * DHEAD + quad * 8 + 32 * ks;
            short8 bh8 = *(const short8*)(khi + off);
            short8 bl8 = *(const short8*)(klo + off);
            S[st] = __builtin_amdgcn_mfma_f32_16x16x32_bf16(Qhi[ks], bh8, S[st], 0, 0, 0);
            S[st] = __builtin_amdgcn_mfma_f32_16x16x32_bf16(Qlo[ks], bh8, S[st], 0, 0, 0);
            S[st] = __builtin_amdgcn_mfma_f32_16x16x32_bf16(Qhi[ks], bl8, S[st], 0, 0, 0);
        }
    }

    // ---- masked logits (D-layout: row t = quad*4+r, col s = st*16+nl) ----
    float av[8][4];
#pragma unroll
    for (int st = 0; st < 8; st++)
#pragma unroll
        for (int r = 0; r < 4; r++)
            av[st][r] = adjvT[(b * NN + t0 + quad * 4 + r) * NN + st * 16 + nl];
#pragma unroll
    for (int st = 0; st < 8; st++)
#pragma unroll
        for (int r = 0; r < 4; r++) {
            float a = av[st][r];
            S[st][r] = (a != 0.f) ? (S[st][r] + a * qe_r[r]) * 0.125f : -1e30f;
        }

    // ---- softmax per row: reduce over s = in-lane stiles + xor{1,2,4,8} ----
    float mx[4], den[4], beta[4];
#pragma unroll
    for (int r = 0; r < 4; r++) {
        float m = S[0][r];
#pragma unroll
        for (int st = 1; st < 8; st++) m = fmaxf(m, S[st][r]);
#pragma unroll
        for (int mm = 1; mm < 16; mm <<= 1) m = fmaxf(m, __shfl_xor(m, mm));
        mx[r] = m;
    }
#pragma unroll
    for (int r = 0; r < 4; r++) den[r] = 0.f;
#pragma unroll
    for (int st = 0; st < 8; st++)
#pragma unroll
        for (int r = 0; r < 4; r++) {
            float e = (av[st][r] != 0.f) ? __expf(S[st][r] - mx[r]) : 0.f;
            S[st][r] = e;
            den[r] += e;
        }
#pragma unroll
    for (int r = 0; r < 4; r++) {
#pragma unroll
        for (int mm = 1; mm < 16; mm <<= 1) den[r] += __shfl_xor(den[r], mm);
        den[r] = 1.f / fmaxf(den[r], 1e-16f);
        beta[r] = 0.f;
    }
#pragma unroll
    for (int st = 0; st < 8; st++)
#pragma unroll
        for (int r = 0; r < 4; r++) {
            float al = S[st][r] * den[r];
            S[st][r] = al;
            beta[r] += al * av[st][r];
        }
#pragma unroll
    for (int r = 0; r < 4; r++)
#pragma unroll
        for (int mm = 1; mm < 16; mm <<= 1) beta[r] += __shfl_xor(beta[r], mm);

    // ---- alpha C-layout -> LDS -> A-layout frags (hi only) ----
#pragma unroll
    for (int st = 0; st < 8; st++)
#pragma unroll
        for (int r = 0; r < 4; r++)
            aL[quad * 4 + r][st * 16 + nl] = S[st][r];
    __syncthreads();
    short8 Ah[4];
#pragma unroll
    for (int ks = 0; ks < 4; ks++) {
        const float* p = &aL[nl][quad * 8 + 32 * ks];
        float4 a0 = *(const float4*)p;
        float4 a1 = *(const float4*)(p + 4);
        float hv[8] = {a0.x, a0.y, a0.z, a0.w, a1.x, a1.y, a1.z, a1.w};
        short8 ah;
#pragma unroll
        for (int j = 0; j < 8; j++) ah[j] = (short)f2us_tr(hv[j]);
        Ah[ks] = ah;
    }

    // ---- PV: out[t][d] = beta*we + alpha @ V (V via vT planes) ----
    fx4 G[4];
#pragma unroll
    for (int nt = 0; nt < 4; nt++) {
        fx4 g;
#pragma unroll
        for (int r = 0; r < 4; r++) g[r] = beta[r] * we_d[nt];
        G[nt] = g;
    }
#pragma unroll
    for (int ks = 0; ks < 4; ks++) {
#pragma unroll
        for (int nt = 0; nt < 4; nt++) {
            long dg = (long)(b * 256 + h * DHEAD + nt * 16 + nl);
            const short8 vh = *(const short8*)(vThi + dg * NN + quad * 8 + 32 * ks);
            const short8 vl = *(const short8*)(vTlo + dg * NN + quad * 8 + 32 * ks);
            G[nt] = __builtin_amdgcn_mfma_f32_16x16x32_bf16(Ah[ks], vh, G[nt], 0, 0, 0);
            G[nt] = __builtin_amdgcn_mfma_f32_16x16x32_bf16(Ah[ks], vl, G[nt], 0, 0, 0);
        }
    }

    // ---- epilogue: relu(out + skip) ----
#pragma unroll
    for (int nt = 0; nt < 4; nt++)
#pragma unroll
        for (int r = 0; r < 4; r++) {
            int gi = (b * NN + t0 + quad * 4 + r) * HD + h * DHEAD + nt * 16 + nl;
            xout[gi] = fmaxf(G[nt][r] + skip[gi], 0.f);
        }
}

// ---------------- K8: gather agent rows -> f32 out ----------------
__global__ void k_gather(const float* x2, const int* agent, float* out) {
    int b = blockIdx.x;
    int c = threadIdx.x;
    out[b * HD + c] = x2[(b * NN + agent[b]) * HD + c];
}

// ---------------- launch ----------------
extern "C" void kernel_launch(void* const* d_in, const int* in_sizes, int n_in,
                              void* d_out, int out_size, void* d_ws, size_t ws_size,
                              hipStream_t stream) {
    float* out = (float*)d_out;
    (void)hipGetLastError();

    bool ok = (n_in == 31) && in_sizes[0] == BB * NN * FF && in_sizes[2] == BB * NN * NN
              && in_sizes[5] == (FF + EE + 1) * HH && in_sizes[13] == HH * HD
              && in_sizes[22] == HD * HD && out_size == BB * HD;
    if (!ok) { k_sent<<<32, 256, 0, stream>>>(out, -30000.f); return; }

    const size_t WS_NEED = (size_t)8912896 * 4;
    if (ws_size < WS_NEED) { k_sent<<<32, 256, 0, stream>>>(out, -20000.f); return; }

    const float* nf    = (const float*)d_in[0];
    const int*   et    = (const int*)d_in[1];
    const float* adj   = (const float*)d_in[2];
    const int*   agent = (const int*)d_in[3];
    const float* emb   = (const float*)d_in[4];
    const float* W1    = (const float*)d_in[5];
    const float* b1    = (const float*)d_in[6];
    const float* g1    = (const float*)d_in[7];
    const float* be1   = (const float*)d_in[8];
    const float* Wh    = (const float*)d_in[9];
    const float* bh    = (const float*)d_in[10];
    const float* gh    = (const float*)d_in[11];
    const float* beh   = (const float*)d_in[12];
    const float* Wq1   = (const float*)d_in[13];
    const float* bq1   = (const float*)d_in[14];
    const float* Wk1   = (const float*)d_in[15];
    const float* bk1   = (const float*)d_in[16];
    const float* Wv1   = (const float*)d_in[17];
    const float* bv1   = (const float*)d_in[18];
    const float* We1   = (const float*)d_in[19];
    const float* Ws1   = (const float*)d_in[20];
    const float* bs1   = (const float*)d_in[21];
    const float* Wq2   = (const float*)d_in[22];
    const float* bq2   = (const float*)d_in[23];
    const float* Wk2   = (const float*)d_in[24];
    const float* bk2   = (const float*)d_in[25];
    const float* Wv2   = (const float*)d_in[26];
    const float* bv2   = (const float*)d_in[27];
    const float* We2   = (const float*)d_in[28];
    const float* Ws2   = (const float*)d_in[29];
    const float* bs2   = (const float*)d_in[30];

    float* ws   = (float*)d_ws;
    float* adjv = ws;                              // 524288 f
    float* base = adjv + BB * NN * NN;             // 524288 f
    float* x0   = base + BB * NN * HH;             // 524288 f
    float* q    = x0 + BB * NN * HH;               // 1048576 f
    float* kreg = q + BB * NN * HD;                // 1048576 f -> khi/klo
    float* vreg = kreg + BB * NN * HD;             // 1048576 f -> vThi/vTlo
    float* skip = vreg + BB * NN * HD;             // 1048576 f
    float* areg = skip + BB * NN * HD;             // 1048576 f -> weight planes + adjvT
    float* x1   = areg + BB * NN * HD;
    float* x2   = x1 + BB * NN * HD;

    // econv prep planes in q region (q first written AFTER econv)
    ushort_t* BhiG = (ushort_t*)q;
    ushort_t* BloG = BhiG + HH * HH;
    float*    W1sW = q + 16384;
    float*    cbW  = q + 16512;

    // K / vT planes
    ushort_t* khi  = (ushort_t*)kreg;              // 1048576 ush
    ushort_t* klo  = khi + BB * NN * HD;           // 1048576 ush
    ushort_t* vThi = (ushort_t*)vreg;
    ushort_t* vTlo = vThi + BB * NN * HD;

    // qkvs weight planes + adjvT in areg (4 MB): 1.5 MB planes + 2 MB adjvT
    ushort_t* WhA = (ushort_t*)areg;               // 4*256*128 ush
    ushort_t* WlA = WhA + 4 * 256 * HH;
    ushort_t* WhB = WlA + 4 * 256 * HH;            // 4*256*256 ush
    ushort_t* WlB = WhB + 4 * 256 * HD;
    float* adjvT  = areg + 393216;                 // 524288 f, past planes

    int fail = 0;
    hipError_t e;
#define CHK(stage) do { e = hipGetLastError(); if (e != hipSuccess && fail == 0) fail = (stage); } while (0)

    k_adjv<<<BB, 256, 0, stream>>>(adj, adjv, adjvT);                                CHK(1);
    k_base<<<BB * NN, HH, 0, stream>>>(nf, et, emb, W1, b1, base);                   CHK(2);
    k_zero<<<BB * NN * HH / 256, 256, 0, stream>>>(x0);                              CHK(3);
    k_prep<<<HH, 64, 0, stream>>>(Wh, g1, be1, bh, BhiG, BloG, W1sW, cbW);           CHK(4);
    k_prepw<<<1024, 64, 0, stream>>>(Wq1, Wk1, Wv1, Ws1, HH, WhA, WlA);              CHK(5);
    k_prepw<<<1024, 64, 0, stream>>>(Wq2, Wk2, Wv2, Ws2, HD, WhB, WlB);              CHK(6);
    k_econv_mfma<<<512, 256, 0, stream>>>(adjv, base, W1, BhiG, BloG, W1sW, cbW,
                                          gh, beh, x0);                              CHK(7);

    k_qkvs_mfma<HH><<<256, 256, 0, stream>>>(x0, WhA, WlA, bq1, bk1, bv1, bs1,
                                             q, skip, khi, klo, vThi, vTlo);         CHK(8);
    k_attn_mfma<<<1024, 64, 0, stream>>>(q, khi, klo, vThi, vTlo, adjvT, We1,
                                         skip, x1);                                  CHK(9);

    k_qkvs_mfma<HD><<<256, 256, 0, stream>>>(x1, WhB, WlB, bq2, bk2, bv2, bs2,
                                             q, skip, khi, klo, vThi, vTlo);         CHK(10);
    k_attn_mfma<<<1024, 64, 0, stream>>>(q, khi, klo, vThi, vTlo, adjvT, We2,
                                         skip, x2);                                  CHK(11);

    k_gather<<<BB, HD, 0, stream>>>(x2, agent, out);                                 CHK(12);
#undef CHK

    if (fail != 0)
        k_sent<<<32, 256, 0, stream>>>(out, -(1000.f + 500.f * (float)fail));
}

// Round 4
// 306.964 us; speedup vs baseline: 1.8452x; 1.0952x over previous
//
#include <hip/hip_runtime.h>
#include <hip/hip_bf16.h>

typedef __hip_bfloat16 bf16;
typedef unsigned short ushort_t;
typedef unsigned int uint_t;
typedef __attribute__((ext_vector_type(8))) short short8;
typedef __attribute__((ext_vector_type(4))) float fx4;
typedef __attribute__((ext_vector_type(4))) unsigned int uintx4;

#define BB 32
#define NN 128
#define FF 9
#define EE 8
#define HH 128
#define HD 256
#define NHEAD 4
#define DHEAD 64

__device__ __forceinline__ float us2f(ushort_t u) {
    return __uint_as_float(((unsigned int)u) << 16);
}
// truncation split: hi = trunc16(v), lo = v - hi (lo exact in f32)
__device__ __forceinline__ ushort_t f2us_tr(float f) {
    return (ushort_t)(__float_as_uint(f) >> 16);
}
__device__ __forceinline__ short8 pack4(uint_t w0, uint_t w1, uint_t w2, uint_t w3) {
    uintx4 u = (uintx4){w0, w1, w2, w3};
    return __builtin_bit_cast(short8, u);
}
// pair split: a -> low short of word, c -> high short (bit-identical to
// per-element f2us_tr path: keep = bits & 0xffff0000 == us2f(f2us_tr(x)))
__device__ __forceinline__ void pair_split(float a, float c, uint_t& hw, uint_t& lw) {
    uint_t ua = __float_as_uint(a), uc = __float_as_uint(c);
    uint_t ka = ua & 0xffff0000u, kc = uc & 0xffff0000u;
    float la = a - __uint_as_float(ka);
    float lc = c - __uint_as_float(kc);
    hw = (ua >> 16) | kc;
    lw = (__float_as_uint(la) >> 16) | (__float_as_uint(lc) & 0xffff0000u);
}
__device__ __forceinline__ uint_t pair_hi(float a, float c) {
    return (__float_as_uint(a) >> 16) | (__float_as_uint(c) & 0xffff0000u);
}

__global__ void TransformerConvNet_85315230367963_kernel() {}

__global__ void k_sent(float* out, float val) {
    out[blockIdx.x * 256 + threadIdx.x] = val;
}

__global__ void k_zero(float* p) {
    p[blockIdx.x * 256 + threadIdx.x] = 0.f;
}

// ---------------- K1: adjv + adjvT (masked), 256 blocks ----------------
__global__ void k_adjv(const float* adj, float* adjv, float* adjvT) {
    int blk = blockIdx.x;          // 256 = 32 b * 8 slices
    int b = blk >> 3, sl = blk & 7;
    const float* src = adj + b * NN * NN;
    float* d1 = adjv + b * NN * NN;
    float* d2 = adjvT + b * NN * NN;
    int i0 = sl * 2048;
    for (int ii = threadIdx.x; ii < 2048; ii += 256) {
        int i = i0 + ii;
        float a = src[i];
        d1[i] = (a > 0.f && a < 1.0f) ? a : 0.f;
        int t = i >> 7, s = i & 127;
        float a2 = src[s * NN + t];
        d2[i] = (a2 > 0.f && a2 < 1.0f) ? a2 : 0.f;   // adjvT[t][s]
    }
}

// ---------------- K2: base[bs][c] = src(bs) @ W1[:17] + b1 ----------------
__global__ void k_base(const float* nf, const int* et, const float* emb,
                       const float* W1, const float* b1, float* base) {
    int bs = blockIdx.x;
    int c = threadIdx.x;
    int ty = et[bs];
    float acc = b1[c];
    for (int f = 0; f < FF; f++)
        acc += nf[bs * FF + f] * W1[f * HH + c];
    for (int e = 0; e < EE; e++)
        acc += emb[ty * EE + e] * W1[(FF + e) * HH + c];
    base[bs * HH + c] = acc;
}

// ---------------- K_prep: Wh' = g1*Wh split bf16 hi/lo, swizzled ----------
__global__ void k_prep(const float* Wh, const float* g1, const float* be1,
                       const float* bh, ushort_t* BhiG, ushort_t* BloG,
                       float* W1s, float* cbv) {
    int n = blockIdx.x;      // 0..127
    int t = threadIdx.x;     // 0..63
    int sw = 8 * (n & 15);
    float s1 = 0.f, s2 = 0.f;
    for (int kk = 0; kk < 2; kk++) {
        int k = t + kk * 64;
        float w = Wh[k * HH + n];
        float wp = g1[k] * w;
        ushort_t hb = f2us_tr(wp);
        float lo = wp - us2f(hb);
        BhiG[n * HH + (k ^ sw)] = hb;
        BloG[n * HH + (k ^ sw)] = f2us_tr(lo);
        s1 += wp;
        s2 += be1[k] * w;
    }
    for (int m = 1; m < 64; m <<= 1) {
        s1 += __shfl_xor(s1, m);
        s2 += __shfl_xor(s2, m);
    }
    if (t == 0) { W1s[n] = s1; cbv[n] = s2 + bh[n]; }
}

// ---------------- K_prepw: split 4 qkvs weight mats into bf16 hi/lo -------
__global__ void k_prepw(const float* W0, const float* W1p, const float* W2p,
                        const float* W3p, int IN, ushort_t* Whi, ushort_t* Wlo) {
    int blk = blockIdx.x;             // 4*256
    int mat = blk >> 8, n = blk & 255;
    const float* W = (mat == 0) ? W0 : (mat == 1) ? W1p : (mat == 2) ? W2p : W3p;
    ushort_t* hi = Whi + mat * 256 * IN;
    ushort_t* lo = Wlo + mat * 256 * IN;
    int sw = 8 * (n & 15);
    for (int k = threadIdx.x; k < IN; k += 64) {
        float w = W[k * HD + n];
        ushort_t hb = f2us_tr(w);
        float l = w - us2f(hb);
        hi[n * IN + (k ^ sw)] = hb;
        lo[n * IN + (k ^ sw)] = f2us_tr(l);
    }
}

// ---------------- K3: embed conv, MFMA, SWAPPED operands ------------------
// D[n][t] = Wh'^T (LDS, A-op) x raw relu(h1)^T (regs, B-op).  B col = t = nl
// -> LN1/LN2 stats lane-local.  LN1 applied POST-mfma via W1s correction:
//   pre2 = r1*Graw + nm*W1s[n] + cb[n]   (nm = -m1*r1).
// Pair-packed bf16 split (32-bit ops only, bit-identical).  Plain
// launch_bounds: a forced (256,2) cap previously spilled 800 MB to scratch.
__global__ void __launch_bounds__(256) k_econv_mfma(
    const float* adjv, const float* base, const float* W1,
    const ushort_t* BhiG, const ushort_t* BloG,
    const float* W1sg, const float* cbv,
    const float* ghp, const float* behp, float* x0)
{
    __shared__ __align__(16) ushort_t PhiPlo[2 * HH * HH];   // 64 KB
    ushort_t* Phi = PhiPlo;
    ushort_t* Plo = PhiPlo + HH * HH;

    int blk = blockIdx.x;
    int b  = blk >> 4;
    int tt = (blk >> 1) & 7;
    int sh = blk & 1;
    int t0 = tt * 16;
    int tid = threadIdx.x;
    int wv  = tid >> 6;
    int lane = tid & 63;
    int nl = lane & 15;
    int quad = lane >> 4;

    {
        const uint4* srcH = (const uint4*)BhiG;
        const uint4* srcL = (const uint4*)BloG;
        uint4* dstH = (uint4*)Phi;
        uint4* dstL = (uint4*)Plo;
        for (int i = tid; i < HH * HH / 8; i += 256) {
            dstH[i] = srcH[i];
            dstL[i] = srcL[i];
        }
    }

    float w17v[4][8];
#pragma unroll
    for (int st = 0; st < 4; st++) {
        const float* p = W1 + 17 * HH + quad * 8 + 32 * st;
        float4 a = *(const float4*)p;
        float4 bq = *(const float4*)(p + 4);
        w17v[st][0] = a.x;  w17v[st][1] = a.y;  w17v[st][2] = a.z;  w17v[st][3] = a.w;
        w17v[st][4] = bq.x; w17v[st][5] = bq.y; w17v[st][6] = bq.z; w17v[st][7] = bq.w;
    }

    fx4 acc1[8];                 // sum_s mask*r2*h2   (per n, per t=nl)
#pragma unroll
    for (int tile = 0; tile < 8; tile++) acc1[tile] = (fx4){0.f, 0.f, 0.f, 0.f};
    float c0 = 0.f;              // sum_s mask
    float c1 = 0.f;              // sum_s mask*r2*mean2

    __syncthreads();

    for (int i = 0; i < 16; i++) {
        int s = sh * 64 + wv * 16 + i;
        const float* brow = base + (b * NN + s) * HH;
        float avv = adjv[(b * NN + s) * NN + t0 + nl];   // t = t0 + nl

        // one pass: vv = relu(base + avv*w17); stats + pair-packed hi/lo
        short8 Hhi[4], Hlo[4];
        float sm = 0.f, s2 = 0.f;
#pragma unroll
        for (int st = 0; st < 4; st++) {
            const float* p = brow + quad * 8 + 32 * st;
            float4 b0 = *(const float4*)p;
            float4 b1q = *(const float4*)(p + 4);
            float h[8] = {b0.x, b0.y, b0.z, b0.w, b1q.x, b1q.y, b1q.z, b1q.w};
            uint_t hw[4], lw[4];
#pragma unroll
            for (int pr = 0; pr < 4; pr++) {
                float a = fmaxf(fmaf(avv, w17v[st][2 * pr], h[2 * pr]), 0.f);
                float c = fmaxf(fmaf(avv, w17v[st][2 * pr + 1], h[2 * pr + 1]), 0.f);
                sm += a; sm += c;
                s2 = fmaf(a, a, s2);
                s2 = fmaf(c, c, s2);
                pair_split(a, c, hw[pr], lw[pr]);
            }
            Hhi[st] = pack4(hw[0], hw[1], hw[2], hw[3]);
            Hlo[st] = pack4(lw[0], lw[1], lw[2], lw[3]);
        }
        sm += __shfl_xor(sm, 16); sm += __shfl_xor(sm, 32);
        s2 += __shfl_xor(s2, 16); s2 += __shfl_xor(s2, 32);
        float m1 = sm * (1.f / 128.f);
        float r1 = rsqrtf(s2 * (1.f / 128.f) - m1 * m1 + 1e-5f);
        float nm = -m1 * r1;

        // Graw = Wh'^T @ vv
        fx4 G[8];
#pragma unroll
        for (int tile = 0; tile < 8; tile++) G[tile] = (fx4){0.f, 0.f, 0.f, 0.f};
#pragma unroll
        for (int st = 0; st < 4; st++) {
            int koff = quad * 8 + 32 * st;
#pragma unroll
            for (int tile = 0; tile < 8; tile++) {
                int off = (tile * 16 + nl) * HH + (koff ^ (nl * 8));
                short8 ph = *(const short8*)(&Phi[off]);
                short8 pl = *(const short8*)(&Plo[off]);
                G[tile] = __builtin_amdgcn_mfma_f32_16x16x32_bf16(ph, Hhi[st], G[tile], 0, 0, 0);
                G[tile] = __builtin_amdgcn_mfma_f32_16x16x32_bf16(pl, Hhi[st], G[tile], 0, 0, 0);
                G[tile] = __builtin_amdgcn_mfma_f32_16x16x32_bf16(ph, Hlo[st], G[tile], 0, 0, 0);
            }
        }

        // LN1 correction + relu; LN2 stats (in-lane over 32 n + 2 shuffles)
        float sm2 = 0.f, ss2 = 0.f;
#pragma unroll
        for (int tile = 0; tile < 8; tile++) {
            float4 w4 = *(const float4*)(W1sg + tile * 16 + quad * 4);
            float4 c4 = *(const float4*)(cbv + tile * 16 + quad * 4);
            float wa[4] = {w4.x, w4.y, w4.z, w4.w};
            float ca[4] = {c4.x, c4.y, c4.z, c4.w};
#pragma unroll
            for (int r = 0; r < 4; r++) {
                float pre = fmaf(r1, G[tile][r], fmaf(nm, wa[r], ca[r]));
                float h2 = fmaxf(pre, 0.f);
                G[tile][r] = h2;
                sm2 += h2;
                ss2 = fmaf(h2, h2, ss2);
            }
        }
        sm2 += __shfl_xor(sm2, 16); sm2 += __shfl_xor(sm2, 32);
        ss2 += __shfl_xor(ss2, 16); ss2 += __shfl_xor(ss2, 32);
        float mean2 = sm2 * (1.f / 128.f);
        float r2 = rsqrtf(ss2 * (1.f / 128.f) - mean2 * mean2 + 1e-5f);
        float msk = (avv != 0.f) ? 1.f : 0.f;
        float mr2 = msk * r2;

#pragma unroll
        for (int tile = 0; tile < 8; tile++)
#pragma unroll
            for (int r = 0; r < 4; r++)
                acc1[tile][r] = fmaf(mr2, G[tile][r], acc1[tile][r]);
        c0 += msk;
        c1 = fmaf(mr2, mean2, c1);
    }

    // ---- epilogue: xv = gh*(acc1 - c1) + beh*c0 ;  cross-wave LDS reduce,
    //      then coalesced atomics (consecutive lanes -> consecutive n) ----
    __syncthreads();                       // Phi/Plo dead; reuse as f32 slab
    float* slab = (float*)PhiPlo;          // [4 waves][16 t][stride 132]
#pragma unroll
    for (int tile = 0; tile < 8; tile++) {
        float4 g4 = *(const float4*)(ghp + tile * 16 + quad * 4);
        float4 be4 = *(const float4*)(behp + tile * 16 + quad * 4);
        float gv[4] = {g4.x, g4.y, g4.z, g4.w};
        float bv[4] = {be4.x, be4.y, be4.z, be4.w};
#pragma unroll
        for (int r = 0; r < 4; r++) {
            float xv = fmaf(gv[r], acc1[tile][r] - c1, bv[r] * c0);
            slab[(wv * 16 + nl) * 132 + tile * 16 + quad * 4 + r] = xv;
        }
    }
    __syncthreads();
    for (int e = tid; e < 16 * HH; e += 256) {
        int t = e >> 7, n = e & 127;
        float vsum = slab[t * 132 + n] + slab[(16 + t) * 132 + n]
                   + slab[(32 + t) * 132 + n] + slab[(48 + t) * 132 + n];
        atomicAdd(&x0[(b * NN + t0 + t) * HH + n], vsum);
    }
}

// ---------------- K5: qkvs via MFMA, 512 blocks (32-col n slices) ---------
template <int IN>
__global__ void __launch_bounds__(256) k_qkvs_mfma(
    const float* x, const ushort_t* Whi, const ushort_t* Wlo,
    const float* b0, const float* b1, const float* b2, const float* b3,
    float* q, float* skipo,
    ushort_t* khi, ushort_t* klo, ushort_t* vThi, ushort_t* vTlo)
{
    const int ST = IN / 32;
    int blk = blockIdx.x;             // 512 = 64 m-blocks * 8 col slices
    int m0 = (blk >> 3) * 64;
    int nsl = blk & 7;                // 32-col slice
    int tid = threadIdx.x;
    int wv = tid >> 6;
    int lane = tid & 63;
    int nl = lane & 15;
    int quad = lane >> 4;
    int row = m0 + wv * 16 + nl;

    short8 Ahi[ST], Alo[ST];
    const float* xrow = x + (long)row * IN;
#pragma unroll
    for (int st = 0; st < ST; st++) {
        const float* p = xrow + quad * 8 + 32 * st;
        float4 a4 = *(const float4*)p;
        float4 b4 = *(const float4*)(p + 4);
        float h[8] = {a4.x, a4.y, a4.z, a4.w, b4.x, b4.y, b4.z, b4.w};
        uint_t hw[4], lw[4];
#pragma unroll
        for (int pr = 0; pr < 4; pr++)
            pair_split(h[2 * pr], h[2 * pr + 1], hw[pr], lw[pr]);
        Ahi[st] = pack4(hw[0], hw[1], hw[2], hw[3]);
        Alo[st] = pack4(lw[0], lw[1], lw[2], lw[3]);
    }

    const float* bs_[4] = {b0, b1, b2, b3};

#pragma unroll
    for (int mat = 0; mat < 4; mat++) {
        const ushort_t* Bh = Whi + (mat * 256 + nsl * 32) * IN;
        const ushort_t* Bl = Wlo + (mat * 256 + nsl * 32) * IN;
        fx4 G[2];
#pragma unroll
        for (int tile = 0; tile < 2; tile++) {
            float bc = bs_[mat][nsl * 32 + tile * 16 + nl];
            G[tile] = (fx4){bc, bc, bc, bc};
        }
#pragma unroll
        for (int st = 0; st < ST; st++) {
            int koff = quad * 8 + 32 * st;
#pragma unroll
            for (int tile = 0; tile < 2; tile++) {
                int off = (tile * 16 + nl) * IN + (koff ^ (nl * 8));
                short8 bh8 = *(const short8*)(Bh + off);
                short8 bl8 = *(const short8*)(Bl + off);
                G[tile] = __builtin_amdgcn_mfma_f32_16x16x32_bf16(Ahi[st], bh8, G[tile], 0, 0, 0);
                G[tile] = __builtin_amdgcn_mfma_f32_16x16x32_bf16(Alo[st], bh8, G[tile], 0, 0, 0);
                G[tile] = __builtin_amdgcn_mfma_f32_16x16x32_bf16(Ahi[st], bl8, G[tile], 0, 0, 0);
            }
        }
        int row0 = m0 + wv * 16 + quad * 4;          // rows r=0..3
        if (mat == 0 || mat == 3) {
            float* om = (mat == 0) ? q : skipo;
#pragma unroll
            for (int tile = 0; tile < 2; tile++)
#pragma unroll
                for (int r = 0; r < 4; r++)
                    om[(row0 + r) * HD + nsl * 32 + tile * 16 + nl] = G[tile][r];
        } else if (mat == 1) {
            // K planes, layout [row=b*128+s][256]
#pragma unroll
            for (int tile = 0; tile < 2; tile++) {
                int col = nsl * 32 + tile * 16 + nl;
#pragma unroll
                for (int r = 0; r < 4; r++) {
                    float gv = G[tile][r];
                    ushort_t hb = f2us_tr(gv);
                    khi[(row0 + r) * HD + col] = hb;
                    klo[(row0 + r) * HD + col] = f2us_tr(gv - us2f(hb));
                }
            }
        } else {
            // vT planes: vT[dg = b*256 + col][128 s], 4 consecutive s packed
            int bb = row0 >> 7;
            int s0 = row0 & 127;
#pragma unroll
            for (int tile = 0; tile < 2; tile++) {
                int col = nsl * 32 + tile * 16 + nl;
                int dg = bb * 256 + col;
                ushort4 h4, l4;
                float g0 = G[tile][0], g1 = G[tile][1], g2 = G[tile][2], g3 = G[tile][3];
                ushort_t h0 = f2us_tr(g0), h1 = f2us_tr(g1), h2 = f2us_tr(g2), h3 = f2us_tr(g3);
                h4.x = h0; h4.y = h1; h4.z = h2; h4.w = h3;
                l4.x = f2us_tr(g0 - us2f(h0));
                l4.y = f2us_tr(g1 - us2f(h1));
                l4.z = f2us_tr(g2 - us2f(h2));
                l4.w = f2us_tr(g3 - us2f(h3));
                *(ushort4*)&vThi[dg * NN + s0] = h4;
                *(ushort4*)&vTlo[dg * NN + s0] = l4;
            }
        }
    }
}

// ---------------- K6: attention via MFMA, 1 wave per (b,h,16-t tile) -------
__global__ void __launch_bounds__(64) k_attn_mfma(
    const float* qb, const ushort_t* khi, const ushort_t* klo,
    const ushort_t* vThi, const ushort_t* vTlo,
    const float* adjvT, const float* We, const float* skip, float* xout)
{
    __shared__ float aL[16][132];     // alpha C->A round-trip (8.4 KB)
    __shared__ float qeL[16];

    int blk = blockIdx.x;             // 1024 = 32b*4h*8tt
    int b  = blk >> 5;
    int h  = (blk >> 3) & 3;
    int tt = blk & 7;
    int t0 = tt * 16;
    int lane = threadIdx.x;
    int nl = lane & 15;
    int quad = lane >> 4;

    // ---- Q A-frags (split hi/lo) + qe partial (q . we) ----
    short8 Qhi[2], Qlo[2];
    float qe = 0.f;
#pragma unroll
    for (int ks = 0; ks < 2; ks++) {
        const float* p = qb + (b * NN + t0 + nl) * HD + h * DHEAD + quad * 8 + 32 * ks;
        const float* wp = We + h * DHEAD + quad * 8 + 32 * ks;
        float4 a0 = *(const float4*)p;
        float4 a1 = *(const float4*)(p + 4);
        float4 w0 = *(const float4*)wp;
        float4 w1 = *(const float4*)(wp + 4);
        float hv[8] = {a0.x, a0.y, a0.z, a0.w, a1.x, a1.y, a1.z, a1.w};
        float wv8[8] = {w0.x, w0.y, w0.z, w0.w, w1.x, w1.y, w1.z, w1.w};
        uint_t hw[4], lw[4];
#pragma unroll
        for (int pr = 0; pr < 4; pr++) {
            float a = hv[2 * pr], c = hv[2 * pr + 1];
            qe = fmaf(a, wv8[2 * pr], qe);
            qe = fmaf(c, wv8[2 * pr + 1], qe);
            pair_split(a, c, hw[pr], lw[pr]);
        }
        Qhi[ks] = pack4(hw[0], hw[1], hw[2], hw[3]);
        Qlo[ks] = pack4(lw[0], lw[1], lw[2], lw[3]);
    }
    qe += __shfl_xor(qe, 16);
    qe += __shfl_xor(qe, 32);
    if (lane < 16) qeL[lane] = qe;    // qe for t = lane
    __syncthreads();
    float qe_r[4];
#pragma unroll
    for (int r = 0; r < 4; r++) qe_r[r] = qeL[quad * 4 + r];
    float we_d[4];
#pragma unroll
    for (int nt = 0; nt < 4; nt++) we_d[nt] = We[h * DHEAD + nt * 16 + nl];

    // ---- QK^T: S[t][s], 8 s-tiles ----
    fx4 S[8];
#pragma unroll
    for (int st = 0; st < 8; st++) S[st] = (fx4){0.f, 0.f, 0.f, 0.f};
#pragma unroll
    for (int ks = 0; ks < 2; ks++) {
#pragma unroll
        for (int st = 0; st < 8; st++) {
            long off = (long)(b * NN + st * 16 + nl) * HD + h * DHEAD + quad * 8 + 32 * ks;
            short8 bh8 = *(const short8*)(khi + off);
            short8 bl8 = *(const short8*)(klo + off);
            S[st] = __builtin_amdgcn_mfma_f32_16x16x32_bf16(Qhi[ks], bh8, S[st], 0, 0, 0);
            S[st] = __builtin_amdgcn_mfma_f32_16x16x32_bf16(Qlo[ks], bh8, S[st], 0, 0, 0);
            S[st] = __builtin_amdgcn_mfma_f32_16x16x32_bf16(Qhi[ks], bl8, S[st], 0, 0, 0);
        }
    }

    // ---- masked logits (D-layout: row t = quad*4+r, col s = st*16+nl) ----
    float av[8][4];
#pragma unroll
    for (int st = 0; st < 8; st++)
#pragma unroll
        for (int r = 0; r < 4; r++)
            av[st][r] = adjvT[(b * NN + t0 + quad * 4 + r) * NN + st * 16 + nl];
#pragma unroll
    for (int st = 0; st < 8; st++)
#pragma unroll
        for (int r = 0; r < 4; r++) {
            float a = av[st][r];
            S[st][r] = (a != 0.f) ? (S[st][r] + a * qe_r[r]) * 0.125f : -1e30f;
        }

    // ---- softmax per row: reduce over s = in-lane stiles + xor{1,2,4,8} ----
    float mx[4], den[4], beta[4];
#pragma unroll
    for (int r = 0; r < 4; r++) {
        float m = S[0][r];
#pragma unroll
        for (int st = 1; st < 8; st++) m = fmaxf(m, S[st][r]);
#pragma unroll
        for (int mm = 1; mm < 16; mm <<= 1) m = fmaxf(m, __shfl_xor(m, mm));
        mx[r] = m;
    }
#pragma unroll
    for (int r = 0; r < 4; r++) den[r] = 0.f;
#pragma unroll
    for (int st = 0; st < 8; st++)
#pragma unroll
        for (int r = 0; r < 4; r++) {
            float e = (av[st][r] != 0.f) ? __expf(S[st][r] - mx[r]) : 0.f;
            S[st][r] = e;
            den[r] += e;
        }
#pragma unroll
    for (int r = 0; r < 4; r++) {
#pragma unroll
        for (int mm = 1; mm < 16; mm <<= 1) den[r] += __shfl_xor(den[r], mm);
        den[r] = 1.f / fmaxf(den[r], 1e-16f);
        beta[r] = 0.f;
    }
#pragma unroll
    for (int st = 0; st < 8; st++)
#pragma unroll
        for (int r = 0; r < 4; r++) {
            float al = S[st][r] * den[r];
            S[st][r] = al;
            beta[r] += al * av[st][r];
        }
#pragma unroll
    for (int r = 0; r < 4; r++)
#pragma unroll
        for (int mm = 1; mm < 16; mm <<= 1) beta[r] += __shfl_xor(beta[r], mm);

    // ---- alpha C-layout -> LDS -> A-layout frags (hi only) ----
#pragma unroll
    for (int st = 0; st < 8; st++)
#pragma unroll
        for (int r = 0; r < 4; r++)
            aL[quad * 4 + r][st * 16 + nl] = S[st][r];
    __syncthreads();
    short8 Ah[4];
#pragma unroll
    for (int ks = 0; ks < 4; ks++) {
        const float* p = &aL[nl][quad * 8 + 32 * ks];
        float4 a0 = *(const float4*)p;
        float4 a1 = *(const float4*)(p + 4);
        float hv[8] = {a0.x, a0.y, a0.z, a0.w, a1.x, a1.y, a1.z, a1.w};
        uint_t w[4];
#pragma unroll
        for (int pr = 0; pr < 4; pr++) w[pr] = pair_hi(hv[2 * pr], hv[2 * pr + 1]);
        Ah[ks] = pack4(w[0], w[1], w[2], w[3]);
    }

    // ---- PV: out[t][d] = beta*we + alpha @ V (V via vT planes) ----
    fx4 G[4];
#pragma unroll
    for (int nt = 0; nt < 4; nt++) {
        fx4 g;
#pragma unroll
        for (int r = 0; r < 4; r++) g[r] = beta[r] * we_d[nt];
        G[nt] = g;
    }
#pragma unroll
    for (int ks = 0; ks < 4; ks++) {
#pragma unroll
        for (int nt = 0; nt < 4; nt++) {
            long dg = (long)(b * 256 + h * DHEAD + nt * 16 + nl);
            const short8 vh = *(const short8*)(vThi + dg * NN + quad * 8 + 32 * ks);
            const short8 vl = *(const short8*)(vTlo + dg * NN + quad * 8 + 32 * ks);
            G[nt] = __builtin_amdgcn_mfma_f32_16x16x32_bf16(Ah[ks], vh, G[nt], 0, 0, 0);
            G[nt] = __builtin_amdgcn_mfma_f32_16x16x32_bf16(Ah[ks], vl, G[nt], 0, 0, 0);
        }
    }

    // ---- epilogue: relu(out + skip) ----
#pragma unroll
    for (int nt = 0; nt < 4; nt++)
#pragma unroll
        for (int r = 0; r < 4; r++) {
            int gi = (b * NN + t0 + quad * 4 + r) * HD + h * DHEAD + nt * 16 + nl;
            xout[gi] = fmaxf(G[nt][r] + skip[gi], 0.f);
        }
}

// ---------------- K8: gather agent rows -> f32 out ----------------
__global__ void k_gather(const float* x2, const int* agent, float* out) {
    int b = blockIdx.x;
    int c = threadIdx.x;
    out[b * HD + c] = x2[(b * NN + agent[b]) * HD + c];
}

// ---------------- launch ----------------
extern "C" void kernel_launch(void* const* d_in, const int* in_sizes, int n_in,
                              void* d_out, int out_size, void* d_ws, size_t ws_size,
                              hipStream_t stream) {
    float* out = (float*)d_out;
    (void)hipGetLastError();

    bool ok = (n_in == 31) && in_sizes[0] == BB * NN * FF && in_sizes[2] == BB * NN * NN
              && in_sizes[5] == (FF + EE + 1) * HH && in_sizes[13] == HH * HD
              && in_sizes[22] == HD * HD && out_size == BB * HD;
    if (!ok) { k_sent<<<32, 256, 0, stream>>>(out, -30000.f); return; }

    const size_t WS_NEED = (size_t)8912896 * 4;
    if (ws_size < WS_NEED) { k_sent<<<32, 256, 0, stream>>>(out, -20000.f); return; }

    const float* nf    = (const float*)d_in[0];
    const int*   et    = (const int*)d_in[1];
    const float* adj   = (const float*)d_in[2];
    const int*   agent = (const int*)d_in[3];
    const float* emb   = (const float*)d_in[4];
    const float* W1    = (const float*)d_in[5];
    const float* b1    = (const float*)d_in[6];
    const float* g1    = (const float*)d_in[7];
    const float* be1   = (const float*)d_in[8];
    const float* Wh    = (const float*)d_in[9];
    const float* bh    = (const float*)d_in[10];
    const float* gh    = (const float*)d_in[11];
    const float* beh   = (const float*)d_in[12];
    const float* Wq1   = (const float*)d_in[13];
    const float* bq1   = (const float*)d_in[14];
    const float* Wk1   = (const float*)d_in[15];
    const float* bk1   = (const float*)d_in[16];
    const float* Wv1   = (const float*)d_in[17];
    const float* bv1   = (const float*)d_in[18];
    const float* We1   = (const float*)d_in[19];
    const float* Ws1   = (const float*)d_in[20];
    const float* bs1   = (const float*)d_in[21];
    const float* Wq2   = (const float*)d_in[22];
    const float* bq2   = (const float*)d_in[23];
    const float* Wk2   = (const float*)d_in[24];
    const float* bk2   = (const float*)d_in[25];
    const float* Wv2   = (const float*)d_in[26];
    const float* bv2   = (const float*)d_in[27];
    const float* We2   = (const float*)d_in[28];
    const float* Ws2   = (const float*)d_in[29];
    const float* bs2   = (const float*)d_in[30];

    float* ws   = (float*)d_ws;
    float* adjv = ws;                              // 524288 f
    float* base = adjv + BB * NN * NN;             // 524288 f
    float* x0   = base + BB * NN * HH;             // 524288 f
    float* q    = x0 + BB * NN * HH;               // 1048576 f
    float* kreg = q + BB * NN * HD;                // 1048576 f -> khi/klo
    float* vreg = kreg + BB * NN * HD;             // 1048576 f -> vThi/vTlo
    float* skip = vreg + BB * NN * HD;             // 1048576 f
    float* areg = skip + BB * NN * HD;             // 1048576 f -> weight planes + adjvT
    float* x1   = areg + BB * NN * HD;
    float* x2   = x1 + BB * NN * HD;

    // econv prep planes in q region (q first written AFTER econv)
    ushort_t* BhiG = (ushort_t*)q;
    ushort_t* BloG = BhiG + HH * HH;
    float*    W1sW = q + 16384;
    float*    cbW  = q + 16512;

    // K / vT planes
    ushort_t* khi  = (ushort_t*)kreg;              // 1048576 ush
    ushort_t* klo  = khi + BB * NN * HD;           // 1048576 ush
    ushort_t* vThi = (ushort_t*)vreg;
    ushort_t* vTlo = vThi + BB * NN * HD;

    // qkvs weight planes + adjvT in areg (4 MB): 1.5 MB planes + 2 MB adjvT
    ushort_t* WhA = (ushort_t*)areg;               // 4*256*128 ush
    ushort_t* WlA = WhA + 4 * 256 * HH;
    ushort_t* WhB = WlA + 4 * 256 * HH;            // 4*256*256 ush
    ushort_t* WlB = WhB + 4 * 256 * HD;
    float* adjvT  = areg + 393216;                 // 524288 f, past planes

    int fail = 0;
    hipError_t e;
#define CHK(stage) do { e = hipGetLastError(); if (e != hipSuccess && fail == 0) fail = (stage); } while (0)

    k_adjv<<<256, 256, 0, stream>>>(adj, adjv, adjvT);                               CHK(1);
    k_base<<<BB * NN, HH, 0, stream>>>(nf, et, emb, W1, b1, base);                   CHK(2);
    k_zero<<<BB * NN * HH / 256, 256, 0, stream>>>(x0);                              CHK(3);
    k_prep<<<HH, 64, 0, stream>>>(Wh, g1, be1, bh, BhiG, BloG, W1sW, cbW);           CHK(4);
    k_prepw<<<1024, 64, 0, stream>>>(Wq1, Wk1, Wv1, Ws1, HH, WhA, WlA);              CHK(5);
    k_prepw<<<1024, 64, 0, stream>>>(Wq2, Wk2, Wv2, Ws2, HD, WhB, WlB);              CHK(6);
    k_econv_mfma<<<512, 256, 0, stream>>>(adjv, base, W1, BhiG, BloG, W1sW, cbW,
                                          gh, beh, x0);                              CHK(7);

    k_qkvs_mfma<HH><<<512, 256, 0, stream>>>(x0, WhA, WlA, bq1, bk1, bv1, bs1,
                                             q, skip, khi, klo, vThi, vTlo);         CHK(8);
    k_attn_mfma<<<1024, 64, 0, stream>>>(q, khi, klo, vThi, vTlo, adjvT, We1,
                                         skip, x1);                                  CHK(9);

    k_qkvs_mfma<HD><<<512, 256, 0, stream>>>(x1, WhB, WlB, bq2, bk2, bv2, bs2,
                                             q, skip, khi, klo, vThi, vTlo);         CHK(10);
    k_attn_mfma<<<1024, 64, 0, stream>>>(q, khi, klo, vThi, vTlo, adjvT, We2,
                                         skip, x2);                                  CHK(11);

    k_gather<<<BB, HD, 0, stream>>>(x2, agent, out);                                 CHK(12);
#undef CHK

    if (fail != 0)
        k_sent<<<32, 256, 0, stream>>>(out, -(1000.f + 500.f * (float)fail));
}

// Round 5
// 293.213 us; speedup vs baseline: 1.9317x; 1.0469x over previous
//
#include <hip/hip_runtime.h>
#include <hip/hip_bf16.h>

typedef __hip_bfloat16 bf16;
typedef unsigned short ushort_t;
typedef unsigned char uchar_t;
typedef unsigned int uint_t;
typedef __attribute__((ext_vector_type(8))) short short8;
typedef __attribute__((ext_vector_type(4))) float fx4;
typedef __attribute__((ext_vector_type(4))) unsigned int uintx4;

#define BB 32
#define NN 128
#define FF 9
#define EE 8
#define HH 128
#define HD 256
#define NHEAD 4
#define DHEAD 64

__device__ __forceinline__ float us2f(ushort_t u) {
    return __uint_as_float(((unsigned int)u) << 16);
}
// truncation split: hi = trunc16(v), lo = v - hi (lo exact in f32)
__device__ __forceinline__ ushort_t f2us_tr(float f) {
    return (ushort_t)(__float_as_uint(f) >> 16);
}
__device__ __forceinline__ short8 pack4(uint_t w0, uint_t w1, uint_t w2, uint_t w3) {
    uintx4 u = (uintx4){w0, w1, w2, w3};
    return __builtin_bit_cast(short8, u);
}
// pair split: a -> low short of word, c -> high short (bit-identical to
// per-element f2us_tr path: keep = bits & 0xffff0000 == us2f(f2us_tr(x)))
__device__ __forceinline__ void pair_split(float a, float c, uint_t& hw, uint_t& lw) {
    uint_t ua = __float_as_uint(a), uc = __float_as_uint(c);
    uint_t ka = ua & 0xffff0000u, kc = uc & 0xffff0000u;
    float la = a - __uint_as_float(ka);
    float lc = c - __uint_as_float(kc);
    hw = (ua >> 16) | kc;
    lw = (__float_as_uint(la) >> 16) | (__float_as_uint(lc) & 0xffff0000u);
}
__device__ __forceinline__ uint_t pair_hi(float a, float c) {
    return (__float_as_uint(a) >> 16) | (__float_as_uint(c) & 0xffff0000u);
}

__global__ void TransformerConvNet_85315230367963_kernel() {}

__global__ void k_sent(float* out, float val) {
    out[blockIdx.x * 256 + threadIdx.x] = val;
}

__global__ void k_zero(float* p) {
    p[blockIdx.x * 256 + threadIdx.x] = 0.f;
}

// ---------------- K1: adjvT (masked transpose), 256 blocks ----------------
__global__ void k_adjv(const float* adj, float* adjvT) {
    int blk = blockIdx.x;          // 256 = 32 b * 8 slices
    int b = blk >> 3, sl = blk & 7;
    const float* src = adj + b * NN * NN;
    float* d2 = adjvT + b * NN * NN;
    int i0 = sl * 2048;
    for (int ii = threadIdx.x; ii < 2048; ii += 256) {
        int i = i0 + ii;
        int t = i >> 7, s = i & 127;
        float a2 = src[s * NN + t];
        d2[i] = (a2 > 0.f && a2 < 1.0f) ? a2 : 0.f;   // adjvT[t][s]
    }
}

// ---------------- K1b: per-(b,t,sh) compacted unmasked-s lists ------------
// key = (b*128+t)*2 + sh; list covers s in [sh*64, sh*64+64).
__global__ void k_slist(const float* adjvT, uchar_t* sl_s, float* sl_av, int* cnts) {
    int key = blockIdx.x * 256 + threadIdx.x;     // 8192 keys
    int bt = key >> 1, sh = key & 1;
    const float* row = adjvT + bt * NN + sh * 64;
    uchar_t* os = sl_s + key * 64;
    float* oa = sl_av + key * 64;
    int c = 0;
    for (int s = 0; s < 64; s++) {
        float a = row[s];
        if (a != 0.f) { os[c] = (uchar_t)(sh * 64 + s); oa[c] = a; c++; }
    }
    if (c == 0) { os[0] = 0; oa[0] = 0.f; }
    cnts[key] = c;
}

// ---------------- K2: base[bs][c] = src(bs) @ W1[:17] + b1 ----------------
__global__ void k_base(const float* nf, const int* et, const float* emb,
                       const float* W1, const float* b1, float* base) {
    int bs = blockIdx.x;
    int c = threadIdx.x;
    int ty = et[bs];
    float acc = b1[c];
    for (int f = 0; f < FF; f++)
        acc += nf[bs * FF + f] * W1[f * HH + c];
    for (int e = 0; e < EE; e++)
        acc += emb[ty * EE + e] * W1[(FF + e) * HH + c];
    base[bs * HH + c] = acc;
}

// ---------------- K_prep: Wh' = g1*Wh split bf16 hi/lo, swizzled ----------
__global__ void k_prep(const float* Wh, const float* g1, const float* be1,
                       const float* bh, ushort_t* BhiG, ushort_t* BloG,
                       float* W1s, float* cbv) {
    int n = blockIdx.x;      // 0..127
    int t = threadIdx.x;     // 0..63
    int sw = 8 * (n & 15);
    float s1 = 0.f, s2 = 0.f;
    for (int kk = 0; kk < 2; kk++) {
        int k = t + kk * 64;
        float w = Wh[k * HH + n];
        float wp = g1[k] * w;
        ushort_t hb = f2us_tr(wp);
        float lo = wp - us2f(hb);
        BhiG[n * HH + (k ^ sw)] = hb;
        BloG[n * HH + (k ^ sw)] = f2us_tr(lo);
        s1 += wp;
        s2 += be1[k] * w;
    }
    for (int m = 1; m < 64; m <<= 1) {
        s1 += __shfl_xor(s1, m);
        s2 += __shfl_xor(s2, m);
    }
    if (t == 0) { W1s[n] = s1; cbv[n] = s2 + bh[n]; }
}

// ---------------- K_prepw: split 4 qkvs weight mats into bf16 hi/lo -------
__global__ void k_prepw(const float* W0, const float* W1p, const float* W2p,
                        const float* W3p, int IN, ushort_t* Whi, ushort_t* Wlo) {
    int blk = blockIdx.x;             // 4*256
    int mat = blk >> 8, n = blk & 255;
    const float* W = (mat == 0) ? W0 : (mat == 1) ? W1p : (mat == 2) ? W2p : W3p;
    ushort_t* hi = Whi + mat * 256 * IN;
    ushort_t* lo = Wlo + mat * 256 * IN;
    int sw = 8 * (n & 15);
    for (int k = threadIdx.x; k < IN; k += 64) {
        float w = W[k * HD + n];
        ushort_t hb = f2us_tr(w);
        float l = w - us2f(hb);
        hi[n * IN + (k ^ sw)] = hb;
        lo[n * IN + (k ^ sw)] = f2us_tr(l);
    }
}

// ---------------- K3: embed conv, MFMA, compacted s-lists ------------------
// D[n][t] = Wh'^T (LDS, A-op) x raw relu(h1)^T (regs, B-op).  B col = t = nl.
// Per column t, only UNMASKED s are processed (p(mask)=0.5): lane walks its
// own compacted list; wave wv takes contiguous quarter (bit-identical order;
// skipped entries contributed exactly 0 via fmaf(0,h2,acc)).
// LN1 applied POST-mfma: pre2 = r1*Graw + nm*W1s[n] + cb[n]  (nm = -m1*r1).
__global__ void __launch_bounds__(256) k_econv_mfma(
    const uchar_t* sl_s, const float* sl_av, const int* cnts,
    const float* base, const float* W1,
    const ushort_t* BhiG, const ushort_t* BloG,
    const float* W1sg, const float* cbv,
    const float* ghp, const float* behp, float* x0)
{
    __shared__ __align__(16) ushort_t PhiPlo[2 * HH * HH];   // 64 KB
    ushort_t* Phi = PhiPlo;
    ushort_t* Plo = PhiPlo + HH * HH;

    int blk = blockIdx.x;
    int b  = blk >> 4;
    int tt = (blk >> 1) & 7;
    int sh = blk & 1;
    int t0 = tt * 16;
    int tid = threadIdx.x;
    int wv  = tid >> 6;
    int lane = tid & 63;
    int nl = lane & 15;
    int quad = lane >> 4;

    {
        const uint4* srcH = (const uint4*)BhiG;
        const uint4* srcL = (const uint4*)BloG;
        uint4* dstH = (uint4*)Phi;
        uint4* dstL = (uint4*)Plo;
        for (int i = tid; i < HH * HH / 8; i += 256) {
            dstH[i] = srcH[i];
            dstL[i] = srcL[i];
        }
    }

    float w17v[4][8];
#pragma unroll
    for (int st = 0; st < 4; st++) {
        const float* p = W1 + 17 * HH + quad * 8 + 32 * st;
        float4 a = *(const float4*)p;
        float4 bq = *(const float4*)(p + 4);
        w17v[st][0] = a.x;  w17v[st][1] = a.y;  w17v[st][2] = a.z;  w17v[st][3] = a.w;
        w17v[st][4] = bq.x; w17v[st][5] = bq.y; w17v[st][6] = bq.z; w17v[st][7] = bq.w;
    }

    // per-lane (col t) compacted list
    int key = ((b * NN) + t0 + nl) * 2 + sh;
    int cnt = cnts[key];
    int q = (cnt + 3) >> 2;              // per-wave chunk
    int mq = q;
#pragma unroll
    for (int m = 1; m < 16; m <<= 1) mq = max(mq, __shfl_xor(mq, m));
    const uchar_t* lst_s = sl_s + key * 64;
    const float*   lst_a = sl_av + key * 64;
    int i0 = wv * q;

    fx4 acc1[8];                 // sum_s mask*r2*h2   (per n, per t=nl)
#pragma unroll
    for (int tile = 0; tile < 8; tile++) acc1[tile] = (fx4){0.f, 0.f, 0.f, 0.f};
    float c0 = 0.f;              // sum_s mask
    float c1 = 0.f;              // sum_s mask*r2*mean2

    __syncthreads();

    for (int i = 0; i < mq; i++) {
        int idx = i0 + i;
        bool val = (i < q) && (idx < cnt);
        int ridx = (idx < cnt) ? idx : (cnt > 0 ? cnt - 1 : 0);
        int s = lst_s[ridx];
        float avv = val ? lst_a[ridx] : 0.f;
        const float* brow = base + (b * NN + s) * HH;

        // one pass: vv = relu(base + avv*w17); stats + pair-packed hi/lo
        short8 Hhi[4], Hlo[4];
        float sm = 0.f, s2 = 0.f;
#pragma unroll
        for (int st = 0; st < 4; st++) {
            const float* p = brow + quad * 8 + 32 * st;
            float4 b0 = *(const float4*)p;
            float4 b1q = *(const float4*)(p + 4);
            float h[8] = {b0.x, b0.y, b0.z, b0.w, b1q.x, b1q.y, b1q.z, b1q.w};
            uint_t hw[4], lw[4];
#pragma unroll
            for (int pr = 0; pr < 4; pr++) {
                float a = fmaxf(fmaf(avv, w17v[st][2 * pr], h[2 * pr]), 0.f);
                float c = fmaxf(fmaf(avv, w17v[st][2 * pr + 1], h[2 * pr + 1]), 0.f);
                sm += a; sm += c;
                s2 = fmaf(a, a, s2);
                s2 = fmaf(c, c, s2);
                pair_split(a, c, hw[pr], lw[pr]);
            }
            Hhi[st] = pack4(hw[0], hw[1], hw[2], hw[3]);
            Hlo[st] = pack4(lw[0], lw[1], lw[2], lw[3]);
        }
        sm += __shfl_xor(sm, 16); sm += __shfl_xor(sm, 32);
        s2 += __shfl_xor(s2, 16); s2 += __shfl_xor(s2, 32);
        float m1 = sm * (1.f / 128.f);
        float r1 = rsqrtf(s2 * (1.f / 128.f) - m1 * m1 + 1e-5f);
        float nm = -m1 * r1;

        // Graw = Wh'^T @ vv
        fx4 G[8];
#pragma unroll
        for (int tile = 0; tile < 8; tile++) G[tile] = (fx4){0.f, 0.f, 0.f, 0.f};
#pragma unroll
        for (int st = 0; st < 4; st++) {
            int koff = quad * 8 + 32 * st;
#pragma unroll
            for (int tile = 0; tile < 8; tile++) {
                int off = (tile * 16 + nl) * HH + (koff ^ (nl * 8));
                short8 ph = *(const short8*)(&Phi[off]);
                short8 pl = *(const short8*)(&Plo[off]);
                G[tile] = __builtin_amdgcn_mfma_f32_16x16x32_bf16(ph, Hhi[st], G[tile], 0, 0, 0);
                G[tile] = __builtin_amdgcn_mfma_f32_16x16x32_bf16(pl, Hhi[st], G[tile], 0, 0, 0);
                G[tile] = __builtin_amdgcn_mfma_f32_16x16x32_bf16(ph, Hlo[st], G[tile], 0, 0, 0);
            }
        }

        // LN1 correction + relu; LN2 stats (in-lane over 32 n + 2 shuffles)
        float sm2 = 0.f, ss2 = 0.f;
#pragma unroll
        for (int tile = 0; tile < 8; tile++) {
            float4 w4 = *(const float4*)(W1sg + tile * 16 + quad * 4);
            float4 c4 = *(const float4*)(cbv + tile * 16 + quad * 4);
            float wa[4] = {w4.x, w4.y, w4.z, w4.w};
            float ca[4] = {c4.x, c4.y, c4.z, c4.w};
#pragma unroll
            for (int r = 0; r < 4; r++) {
                float pre = fmaf(r1, G[tile][r], fmaf(nm, wa[r], ca[r]));
                float h2 = fmaxf(pre, 0.f);
                G[tile][r] = h2;
                sm2 += h2;
                ss2 = fmaf(h2, h2, ss2);
            }
        }
        sm2 += __shfl_xor(sm2, 16); sm2 += __shfl_xor(sm2, 32);
        ss2 += __shfl_xor(ss2, 16); ss2 += __shfl_xor(ss2, 32);
        float mean2 = sm2 * (1.f / 128.f);
        float r2 = rsqrtf(ss2 * (1.f / 128.f) - mean2 * mean2 + 1e-5f);
        float msk = val ? 1.f : 0.f;
        float mr2 = msk * r2;

#pragma unroll
        for (int tile = 0; tile < 8; tile++)
#pragma unroll
            for (int r = 0; r < 4; r++)
                acc1[tile][r] = fmaf(mr2, G[tile][r], acc1[tile][r]);
        c0 += msk;
        c1 = fmaf(mr2, mean2, c1);
    }

    // ---- epilogue: xv = gh*(acc1 - c1) + beh*c0 ;  cross-wave LDS reduce,
    //      then coalesced atomics (consecutive lanes -> consecutive n) ----
    __syncthreads();                       // Phi/Plo dead; reuse as f32 slab
    float* slab = (float*)PhiPlo;          // [4 waves][16 t][stride 132]
#pragma unroll
    for (int tile = 0; tile < 8; tile++) {
        float4 g4 = *(const float4*)(ghp + tile * 16 + quad * 4);
        float4 be4 = *(const float4*)(behp + tile * 16 + quad * 4);
        float gv[4] = {g4.x, g4.y, g4.z, g4.w};
        float bv[4] = {be4.x, be4.y, be4.z, be4.w};
#pragma unroll
        for (int r = 0; r < 4; r++) {
            float xv = fmaf(gv[r], acc1[tile][r] - c1, bv[r] * c0);
            slab[(wv * 16 + nl) * 132 + tile * 16 + quad * 4 + r] = xv;
        }
    }
    __syncthreads();
    for (int e = tid; e < 16 * HH; e += 256) {
        int t = e >> 7, n = e & 127;
        float vsum = slab[t * 132 + n] + slab[(16 + t) * 132 + n]
                   + slab[(32 + t) * 132 + n] + slab[(48 + t) * 132 + n];
        atomicAdd(&x0[(b * NN + t0 + t) * HH + n], vsum);
    }
}

// ---------------- K5: qkvs via MFMA, 512 blocks (32-col n slices) ---------
template <int IN>
__global__ void __launch_bounds__(256) k_qkvs_mfma(
    const float* x, const ushort_t* Whi, const ushort_t* Wlo,
    const float* b0, const float* b1, const float* b2, const float* b3,
    float* q, float* skipo,
    ushort_t* khi, ushort_t* klo, ushort_t* vThi, ushort_t* vTlo)
{
    const int ST = IN / 32;
    int blk = blockIdx.x;             // 512 = 64 m-blocks * 8 col slices
    int m0 = (blk >> 3) * 64;
    int nsl = blk & 7;                // 32-col slice
    int tid = threadIdx.x;
    int wv = tid >> 6;
    int lane = tid & 63;
    int nl = lane & 15;
    int quad = lane >> 4;
    int row = m0 + wv * 16 + nl;

    short8 Ahi[ST], Alo[ST];
    const float* xrow = x + (long)row * IN;
#pragma unroll
    for (int st = 0; st < ST; st++) {
        const float* p = xrow + quad * 8 + 32 * st;
        float4 a4 = *(const float4*)p;
        float4 b4 = *(const float4*)(p + 4);
        float h[8] = {a4.x, a4.y, a4.z, a4.w, b4.x, b4.y, b4.z, b4.w};
        uint_t hw[4], lw[4];
#pragma unroll
        for (int pr = 0; pr < 4; pr++)
            pair_split(h[2 * pr], h[2 * pr + 1], hw[pr], lw[pr]);
        Ahi[st] = pack4(hw[0], hw[1], hw[2], hw[3]);
        Alo[st] = pack4(lw[0], lw[1], lw[2], lw[3]);
    }

    const float* bs_[4] = {b0, b1, b2, b3};

#pragma unroll
    for (int mat = 0; mat < 4; mat++) {
        const ushort_t* Bh = Whi + (mat * 256 + nsl * 32) * IN;
        const ushort_t* Bl = Wlo + (mat * 256 + nsl * 32) * IN;
        fx4 G[2];
#pragma unroll
        for (int tile = 0; tile < 2; tile++) {
            float bc = bs_[mat][nsl * 32 + tile * 16 + nl];
            G[tile] = (fx4){bc, bc, bc, bc};
        }
#pragma unroll
        for (int st = 0; st < ST; st++) {
            int koff = quad * 8 + 32 * st;
#pragma unroll
            for (int tile = 0; tile < 2; tile++) {
                int off = (tile * 16 + nl) * IN + (koff ^ (nl * 8));
                short8 bh8 = *(const short8*)(Bh + off);
                short8 bl8 = *(const short8*)(Bl + off);
                G[tile] = __builtin_amdgcn_mfma_f32_16x16x32_bf16(Ahi[st], bh8, G[tile], 0, 0, 0);
                G[tile] = __builtin_amdgcn_mfma_f32_16x16x32_bf16(Alo[st], bh8, G[tile], 0, 0, 0);
                G[tile] = __builtin_amdgcn_mfma_f32_16x16x32_bf16(Ahi[st], bl8, G[tile], 0, 0, 0);
            }
        }
        int row0 = m0 + wv * 16 + quad * 4;          // rows r=0..3
        if (mat == 0 || mat == 3) {
            float* om = (mat == 0) ? q : skipo;
#pragma unroll
            for (int tile = 0; tile < 2; tile++)
#pragma unroll
                for (int r = 0; r < 4; r++)
                    om[(row0 + r) * HD + nsl * 32 + tile * 16 + nl] = G[tile][r];
        } else if (mat == 1) {
            // K planes, layout [row=b*128+s][256]
#pragma unroll
            for (int tile = 0; tile < 2; tile++) {
                int col = nsl * 32 + tile * 16 + nl;
#pragma unroll
                for (int r = 0; r < 4; r++) {
                    float gv = G[tile][r];
                    ushort_t hb = f2us_tr(gv);
                    khi[(row0 + r) * HD + col] = hb;
                    klo[(row0 + r) * HD + col] = f2us_tr(gv - us2f(hb));
                }
            }
        } else {
            // vT planes: vT[dg = b*256 + col][128 s], 4 consecutive s packed
            int bb = row0 >> 7;
            int s0 = row0 & 127;
#pragma unroll
            for (int tile = 0; tile < 2; tile++) {
                int col = nsl * 32 + tile * 16 + nl;
                int dg = bb * 256 + col;
                ushort4 h4, l4;
                float g0 = G[tile][0], g1 = G[tile][1], g2 = G[tile][2], g3 = G[tile][3];
                ushort_t h0 = f2us_tr(g0), h1 = f2us_tr(g1), h2 = f2us_tr(g2), h3 = f2us_tr(g3);
                h4.x = h0; h4.y = h1; h4.z = h2; h4.w = h3;
                l4.x = f2us_tr(g0 - us2f(h0));
                l4.y = f2us_tr(g1 - us2f(h1));
                l4.z = f2us_tr(g2 - us2f(h2));
                l4.w = f2us_tr(g3 - us2f(h3));
                *(ushort4*)&vThi[dg * NN + s0] = h4;
                *(ushort4*)&vTlo[dg * NN + s0] = l4;
            }
        }
    }
}

// ---------------- K6: attention via MFMA, 1 wave per (b,h,16-t tile) -------
__global__ void __launch_bounds__(64) k_attn_mfma(
    const float* qb, const ushort_t* khi, const ushort_t* klo,
    const ushort_t* vThi, const ushort_t* vTlo,
    const float* adjvT, const float* We, const float* skip, float* xout)
{
    __shared__ float aL[16][132];     // alpha C->A round-trip (8.4 KB)
    __shared__ float qeL[16];

    int blk = blockIdx.x;             // 1024 = 32b*4h*8tt
    int b  = blk >> 5;
    int h  = (blk >> 3) & 3;
    int tt = blk & 7;
    int t0 = tt * 16;
    int lane = threadIdx.x;
    int nl = lane & 15;
    int quad = lane >> 4;

    // ---- Q A-frags (split hi/lo) + qe partial (q . we) ----
    short8 Qhi[2], Qlo[2];
    float qe = 0.f;
#pragma unroll
    for (int ks = 0; ks < 2; ks++) {
        const float* p = qb + (b * NN + t0 + nl) * HD + h * DHEAD + quad * 8 + 32 * ks;
        const float* wp = We + h * DHEAD + quad * 8 + 32 * ks;
        float4 a0 = *(const float4*)p;
        float4 a1 = *(const float4*)(p + 4);
        float4 w0 = *(const float4*)wp;
        float4 w1 = *(const float4*)(wp + 4);
        float hv[8] = {a0.x, a0.y, a0.z, a0.w, a1.x, a1.y, a1.z, a1.w};
        float wv8[8] = {w0.x, w0.y, w0.z, w0.w, w1.x, w1.y, w1.z, w1.w};
        uint_t hw[4], lw[4];
#pragma unroll
        for (int pr = 0; pr < 4; pr++) {
            float a = hv[2 * pr], c = hv[2 * pr + 1];
            qe = fmaf(a, wv8[2 * pr], qe);
            qe = fmaf(c, wv8[2 * pr + 1], qe);
            pair_split(a, c, hw[pr], lw[pr]);
        }
        Qhi[ks] = pack4(hw[0], hw[1], hw[2], hw[3]);
        Qlo[ks] = pack4(lw[0], lw[1], lw[2], lw[3]);
    }
    qe += __shfl_xor(qe, 16);
    qe += __shfl_xor(qe, 32);
    if (lane < 16) qeL[lane] = qe;    // qe for t = lane
    __syncthreads();
    float qe_r[4];
#pragma unroll
    for (int r = 0; r < 4; r++) qe_r[r] = qeL[quad * 4 + r];
    float we_d[4];
#pragma unroll
    for (int nt = 0; nt < 4; nt++) we_d[nt] = We[h * DHEAD + nt * 16 + nl];

    // ---- QK^T: S[t][s], 8 s-tiles ----
    fx4 S[8];
#pragma unroll
    for (int st = 0; st < 8; st++) S[st] = (fx4){0.f, 0.f, 0.f, 0.f};
#pragma unroll
    for (int ks = 0; ks < 2; ks++) {
#pragma unroll
        for (int st = 0; st < 8; st++) {
            long off = (long)(b * NN + st * 16 + nl) * HD + h * DHEAD + quad * 8 + 32 * ks;
            short8 bh8 = *(const short8*)(khi + off);
            short8 bl8 = *(const short8*)(klo + off);
            S[st] = __builtin_amdgcn_mfma_f32_16x16x32_bf16(Qhi[ks], bh8, S[st], 0, 0, 0);
            S[st] = __builtin_amdgcn_mfma_f32_16x16x32_bf16(Qlo[ks], bh8, S[st], 0, 0, 0);
            S[st] = __builtin_amdgcn_mfma_f32_16x16x32_bf16(Qhi[ks], bl8, S[st], 0, 0, 0);
        }
    }

    // ---- masked logits (D-layout: row t = quad*4+r, col s = st*16+nl) ----
    float av[8][4];
#pragma unroll
    for (int st = 0; st < 8; st++)
#pragma unroll
        for (int r = 0; r < 4; r++)
            av[st][r] = adjvT[(b * NN + t0 + quad * 4 + r) * NN + st * 16 + nl];
#pragma unroll
    for (int st = 0; st < 8; st++)
#pragma unroll
        for (int r = 0; r < 4; r++) {
            float a = av[st][r];
            S[st][r] = (a != 0.f) ? (S[st][r] + a * qe_r[r]) * 0.125f : -1e30f;
        }

    // ---- softmax per row: reduce over s = in-lane stiles + xor{1,2,4,8} ----
    float mx[4], den[4], beta[4];
#pragma unroll
    for (int r = 0; r < 4; r++) {
        float m = S[0][r];
#pragma unroll
        for (int st = 1; st < 8; st++) m = fmaxf(m, S[st][r]);
#pragma unroll
        for (int mm = 1; mm < 16; mm <<= 1) m = fmaxf(m, __shfl_xor(m, mm));
        mx[r] = m;
    }
#pragma unroll
    for (int r = 0; r < 4; r++) den[r] = 0.f;
#pragma unroll
    for (int st = 0; st < 8; st++)
#pragma unroll
        for (int r = 0; r < 4; r++) {
            float e = (av[st][r] != 0.f) ? __expf(S[st][r] - mx[r]) : 0.f;
            S[st][r] = e;
            den[r] += e;
        }
#pragma unroll
    for (int r = 0; r < 4; r++) {
#pragma unroll
        for (int mm = 1; mm < 16; mm <<= 1) den[r] += __shfl_xor(den[r], mm);
        den[r] = 1.f / fmaxf(den[r], 1e-16f);
        beta[r] = 0.f;
    }
#pragma unroll
    for (int st = 0; st < 8; st++)
#pragma unroll
        for (int r = 0; r < 4; r++) {
            float al = S[st][r] * den[r];
            S[st][r] = al;
            beta[r] += al * av[st][r];
        }
#pragma unroll
    for (int r = 0; r < 4; r++)
#pragma unroll
        for (int mm = 1; mm < 16; mm <<= 1) beta[r] += __shfl_xor(beta[r], mm);

    // ---- alpha C-layout -> LDS -> A-layout frags (hi only) ----
#pragma unroll
    for (int st = 0; st < 8; st++)
#pragma unroll
        for (int r = 0; r < 4; r++)
            aL[quad * 4 + r][st * 16 + nl] = S[st][r];
    __syncthreads();
    short8 Ah[4];
#pragma unroll
    for (int ks = 0; ks < 4; ks++) {
        const float* p = &aL[nl][quad * 8 + 32 * ks];
        float4 a0 = *(const float4*)p;
        float4 a1 = *(const float4*)(p + 4);
        float hv[8] = {a0.x, a0.y, a0.z, a0.w, a1.x, a1.y, a1.z, a1.w};
        uint_t w[4];
#pragma unroll
        for (int pr = 0; pr < 4; pr++) w[pr] = pair_hi(hv[2 * pr], hv[2 * pr + 1]);
        Ah[ks] = pack4(w[0], w[1], w[2], w[3]);
    }

    // ---- PV: out[t][d] = beta*we + alpha @ V (V via vT planes) ----
    fx4 G[4];
#pragma unroll
    for (int nt = 0; nt < 4; nt++) {
        fx4 g;
#pragma unroll
        for (int r = 0; r < 4; r++) g[r] = beta[r] * we_d[nt];
        G[nt] = g;
    }
#pragma unroll
    for (int ks = 0; ks < 4; ks++) {
#pragma unroll
        for (int nt = 0; nt < 4; nt++) {
            long dg = (long)(b * 256 + h * DHEAD + nt * 16 + nl);
            const short8 vh = *(const short8*)(vThi + dg * NN + quad * 8 + 32 * ks);
            const short8 vl = *(const short8*)(vTlo + dg * NN + quad * 8 + 32 * ks);
            G[nt] = __builtin_amdgcn_mfma_f32_16x16x32_bf16(Ah[ks], vh, G[nt], 0, 0, 0);
            G[nt] = __builtin_amdgcn_mfma_f32_16x16x32_bf16(Ah[ks], vl, G[nt], 0, 0, 0);
        }
    }

    // ---- epilogue: relu(out + skip) ----
#pragma unroll
    for (int nt = 0; nt < 4; nt++)
#pragma unroll
        for (int r = 0; r < 4; r++) {
            int gi = (b * NN + t0 + quad * 4 + r) * HD + h * DHEAD + nt * 16 + nl;
            xout[gi] = fmaxf(G[nt][r] + skip[gi], 0.f);
        }
}

// ---------------- K8: gather agent rows -> f32 out ----------------
__global__ void k_gather(const float* x2, const int* agent, float* out) {
    int b = blockIdx.x;
    int c = threadIdx.x;
    out[b * HD + c] = x2[(b * NN + agent[b]) * HD + c];
}

// ---------------- launch ----------------
extern "C" void kernel_launch(void* const* d_in, const int* in_sizes, int n_in,
                              void* d_out, int out_size, void* d_ws, size_t ws_size,
                              hipStream_t stream) {
    float* out = (float*)d_out;
    (void)hipGetLastError();

    bool ok = (n_in == 31) && in_sizes[0] == BB * NN * FF && in_sizes[2] == BB * NN * NN
              && in_sizes[5] == (FF + EE + 1) * HH && in_sizes[13] == HH * HD
              && in_sizes[22] == HD * HD && out_size == BB * HD;
    if (!ok) { k_sent<<<32, 256, 0, stream>>>(out, -30000.f); return; }

    const size_t WS_NEED = (size_t)8912896 * 4;
    if (ws_size < WS_NEED) { k_sent<<<32, 256, 0, stream>>>(out, -20000.f); return; }

    const float* nf    = (const float*)d_in[0];
    const int*   et    = (const int*)d_in[1];
    const float* adj   = (const float*)d_in[2];
    const int*   agent = (const int*)d_in[3];
    const float* emb   = (const float*)d_in[4];
    const float* W1    = (const float*)d_in[5];
    const float* b1    = (const float*)d_in[6];
    const float* g1    = (const float*)d_in[7];
    const float* be1   = (const float*)d_in[8];
    const float* Wh    = (const float*)d_in[9];
    const float* bh    = (const float*)d_in[10];
    const float* gh    = (const float*)d_in[11];
    const float* beh   = (const float*)d_in[12];
    const float* Wq1   = (const float*)d_in[13];
    const float* bq1   = (const float*)d_in[14];
    const float* Wk1   = (const float*)d_in[15];
    const float* bk1   = (const float*)d_in[16];
    const float* Wv1   = (const float*)d_in[17];
    const float* bv1   = (const float*)d_in[18];
    const float* We1   = (const float*)d_in[19];
    const float* Ws1   = (const float*)d_in[20];
    const float* bs1   = (const float*)d_in[21];
    const float* Wq2   = (const float*)d_in[22];
    const float* bq2   = (const float*)d_in[23];
    const float* Wk2   = (const float*)d_in[24];
    const float* bk2   = (const float*)d_in[25];
    const float* Wv2   = (const float*)d_in[26];
    const float* bv2   = (const float*)d_in[27];
    const float* We2   = (const float*)d_in[28];
    const float* Ws2   = (const float*)d_in[29];
    const float* bs2   = (const float*)d_in[30];

    float* ws   = (float*)d_ws;
    float* slav = ws;                              // 524288 f (was adjv; now sl_av)
    float* base = slav + BB * NN * NN / 32;        // + 524288/... see below
    // NOTE: keep the original region sizes: slav region is 524288 floats.
    base = ws + 524288;                            // 524288 f
    float* x0   = base + BB * NN * HH;             // 524288 f
    float* q    = x0 + BB * NN * HH;               // 1048576 f
    float* kreg = q + BB * NN * HD;                // 1048576 f -> khi/klo
    float* vreg = kreg + BB * NN * HD;             // 1048576 f -> vThi/vTlo
    float* skip = vreg + BB * NN * HD;             // 1048576 f
    float* areg = skip + BB * NN * HD;             // 1048576 f -> planes + adjvT + sl_s
    float* x1   = areg + BB * NN * HD;
    float* x2   = x1 + BB * NN * HD;

    // econv prep planes in q region (q first written AFTER econv)
    ushort_t* BhiG = (ushort_t*)q;
    ushort_t* BloG = BhiG + HH * HH;
    float*    W1sW = q + 16384;
    float*    cbW  = q + 16512;
    int*      cnts = (int*)(q + 17024);            // 8192 ints, free q space

    // K / vT planes
    ushort_t* khi  = (ushort_t*)kreg;              // 1048576 ush
    ushort_t* klo  = khi + BB * NN * HD;           // 1048576 ush
    ushort_t* vThi = (ushort_t*)vreg;
    ushort_t* vTlo = vThi + BB * NN * HD;

    // qkvs weight planes + adjvT + sl_s in areg (4 MB):
    // planes 1.5 MB + adjvT 2 MB + sl_s 0.5 MB = 4 MB exactly
    ushort_t* WhA = (ushort_t*)areg;               // 4*256*128 ush
    ushort_t* WlA = WhA + 4 * 256 * HH;
    ushort_t* WhB = WlA + 4 * 256 * HH;            // 4*256*256 ush
    ushort_t* WlB = WhB + 4 * 256 * HD;
    float* adjvT  = areg + 393216;                 // 524288 f, past planes
    uchar_t* sl_s = (uchar_t*)(areg + 917504);     // 524288 uchars, tail

    int fail = 0;
    hipError_t e;
#define CHK(stage) do { e = hipGetLastError(); if (e != hipSuccess && fail == 0) fail = (stage); } while (0)

    k_adjv<<<256, 256, 0, stream>>>(adj, adjvT);                                     CHK(1);
    k_slist<<<32, 256, 0, stream>>>(adjvT, sl_s, slav, cnts);                        CHK(2);
    k_base<<<BB * NN, HH, 0, stream>>>(nf, et, emb, W1, b1, base);                   CHK(3);
    k_zero<<<BB * NN * HH / 256, 256, 0, stream>>>(x0);                              CHK(4);
    k_prep<<<HH, 64, 0, stream>>>(Wh, g1, be1, bh, BhiG, BloG, W1sW, cbW);           CHK(5);
    k_prepw<<<1024, 64, 0, stream>>>(Wq1, Wk1, Wv1, Ws1, HH, WhA, WlA);              CHK(6);
    k_prepw<<<1024, 64, 0, stream>>>(Wq2, Wk2, Wv2, Ws2, HD, WhB, WlB);              CHK(7);
    k_econv_mfma<<<512, 256, 0, stream>>>(sl_s, slav, cnts, base, W1,
                                          BhiG, BloG, W1sW, cbW, gh, beh, x0);       CHK(8);

    k_qkvs_mfma<HH><<<512, 256, 0, stream>>>(x0, WhA, WlA, bq1, bk1, bv1, bs1,
                                             q, skip, khi, klo, vThi, vTlo);         CHK(9);
    k_attn_mfma<<<1024, 64, 0, stream>>>(q, khi, klo, vThi, vTlo, adjvT, We1,
                                         skip, x1);                                  CHK(10);

    k_qkvs_mfma<HD><<<512, 256, 0, stream>>>(x1, WhB, WlB, bq2, bk2, bv2, bs2,
                                             q, skip, khi, klo, vThi, vTlo);         CHK(11);
    k_attn_mfma<<<1024, 64, 0, stream>>>(q, khi, klo, vThi, vTlo, adjvT, We2,
                                         skip, x2);                                  CHK(12);

    k_gather<<<BB, HD, 0, stream>>>(x2, agent, out);                                 CHK(13);
#undef CHK

    if (fail != 0)
        k_sent<<<32, 256, 0, stream>>>(out, -(1000.f + 500.f * (float)fail));
}

// Round 6
// 260.583 us; speedup vs baseline: 2.1736x; 1.1252x over previous
//
#include <hip/hip_runtime.h>
#include <hip/hip_bf16.h>

typedef __hip_bfloat16 bf16;
typedef unsigned short ushort_t;
typedef unsigned char uchar_t;
typedef unsigned int uint_t;
typedef __attribute__((ext_vector_type(8))) short short8;
typedef __attribute__((ext_vector_type(4))) float fx4;
typedef __attribute__((ext_vector_type(4))) unsigned int uintx4;

#define BB 32
#define NN 128
#define FF 9
#define EE 8
#define HH 128
#define HD 256
#define NHEAD 4
#define DHEAD 64

__device__ __forceinline__ float us2f(ushort_t u) {
    return __uint_as_float(((unsigned int)u) << 16);
}
// truncation split: hi = trunc16(v), lo = v - hi (lo exact in f32)
__device__ __forceinline__ ushort_t f2us_tr(float f) {
    return (ushort_t)(__float_as_uint(f) >> 16);
}
__device__ __forceinline__ short8 pack4(uint_t w0, uint_t w1, uint_t w2, uint_t w3) {
    uintx4 u = (uintx4){w0, w1, w2, w3};
    return __builtin_bit_cast(short8, u);
}
// pair split: a -> low short of word, c -> high short (bit-identical to
// per-element f2us_tr path: keep = bits & 0xffff0000 == us2f(f2us_tr(x)))
__device__ __forceinline__ void pair_split(float a, float c, uint_t& hw, uint_t& lw) {
    uint_t ua = __float_as_uint(a), uc = __float_as_uint(c);
    uint_t ka = ua & 0xffff0000u, kc = uc & 0xffff0000u;
    float la = a - __uint_as_float(ka);
    float lc = c - __uint_as_float(kc);
    hw = (ua >> 16) | kc;
    lw = (__float_as_uint(la) >> 16) | (__float_as_uint(lc) & 0xffff0000u);
}
__device__ __forceinline__ uint_t pair_hi(float a, float c) {
    return (__float_as_uint(a) >> 16) | (__float_as_uint(c) & 0xffff0000u);
}

__global__ void TransformerConvNet_85315230367963_kernel() {}

__global__ void k_sent(float* out, float val) {
    out[blockIdx.x * 256 + threadIdx.x] = val;
}

// ---------------- K_prep_all: all independent prep work, ONE launch -------
// blocks [0,256):      adjvT (masked transpose) + ballot-compacted s-lists
// blocks [256,1280):   base = src @ W1[:17] + b1          (1024 blocks)
// blocks [1280,1536):  zero x0                            (256 blocks)
// blocks [1536,1568):  Wh' split hi/lo + W1s/cb           (32 blocks, 4 n/blk)
// blocks [1568,1824):  prepw layer1 (IN=128)              (256 blocks, 4 keys/blk)
// blocks [1824,2080):  prepw layer2 (IN=256)              (256 blocks, 4 keys/blk)
__global__ void __launch_bounds__(256) k_prep_all(
    const float* adj, float* adjvT, uchar_t* sl_s, float* sl_av, int* cnts,
    const float* nf, const int* et, const float* emb, const float* W1,
    const float* b1, float* base, float* x0,
    const float* Wh, const float* g1, const float* be1, const float* bh,
    ushort_t* BhiG, ushort_t* BloG, float* W1s, float* cbv,
    const float* Wq1, const float* Wk1, const float* Wv1, const float* Ws1,
    ushort_t* WhA, ushort_t* WlA,
    const float* Wq2, const float* Wk2, const float* Wv2, const float* Ws2,
    ushort_t* WhB, ushort_t* WlB)
{
    int blk = blockIdx.x;
    int tid = threadIdx.x;

    if (blk < 256) {
        // ---- adjvT + slist (ballot compaction, ascending-s == serial order)
        int b = blk >> 3, sl = blk & 7;
        int wv = tid >> 6, lane = tid & 63;
#pragma unroll
        for (int j = 0; j < 8; j++) {
            int u = wv * 8 + j;               // 32 (t,sh) units per block
            int t = sl * 16 + (u >> 1);
            int sh = u & 1;
            int s = sh * 64 + lane;
            float a = adj[(b * NN + s) * NN + t];
            float av = (a > 0.f && a < 1.0f) ? a : 0.f;
            adjvT[(b * NN + t) * NN + s] = av;
            unsigned long long mask = __ballot(av != 0.f);
            int key = (b * NN + t) * 2 + sh;
            if (av != 0.f) {
                int pos = __popcll(mask & ((1ull << lane) - 1ull));
                sl_s[key * 64 + pos] = (uchar_t)s;
                sl_av[key * 64 + pos] = av;
            }
            if (lane == 0) {
                cnts[key] = (int)__popcll(mask);
                if (mask == 0ull) { sl_s[key * 64] = 0; sl_av[key * 64] = 0.f; }
            }
        }
    } else if (blk < 1280) {
        // ---- base rows (4 per block)
        int bblk = blk - 256;
        int c = tid & 127;
#pragma unroll
        for (int rr = 0; rr < 2; rr++) {
            int bs = bblk * 4 + rr * 2 + (tid >> 7);
            int ty = et[bs];
            float acc = b1[c];
            for (int f = 0; f < FF; f++)
                acc += nf[bs * FF + f] * W1[f * HH + c];
            for (int e2 = 0; e2 < EE; e2++)
                acc += emb[ty * EE + e2] * W1[(FF + e2) * HH + c];
            base[bs * HH + c] = acc;
        }
    } else if (blk < 1536) {
        // ---- zero x0 (524288 floats = 131072 float4)
        int zblk = blk - 1280;
        float4* p = (float4*)x0 + zblk * 512 + tid * 2;
        p[0] = (float4){0.f, 0.f, 0.f, 0.f};
        p[1] = (float4){0.f, 0.f, 0.f, 0.f};
    } else if (blk < 1568) {
        // ---- Wh' = g1*Wh split bf16 hi/lo, swizzled; W1s/cb (wave per n)
        int n = (blk - 1536) * 4 + (tid >> 6);
        int t = tid & 63;
        int sw = 8 * (n & 15);
        float s1 = 0.f, s2 = 0.f;
#pragma unroll
        for (int kk = 0; kk < 2; kk++) {
            int k = t + kk * 64;
            float w = Wh[k * HH + n];
            float wp = g1[k] * w;
            ushort_t hb = f2us_tr(wp);
            float lo = wp - us2f(hb);
            BhiG[n * HH + (k ^ sw)] = hb;
            BloG[n * HH + (k ^ sw)] = f2us_tr(lo);
            s1 += wp;
            s2 += be1[k] * w;
        }
        for (int m = 1; m < 64; m <<= 1) {
            s1 += __shfl_xor(s1, m);
            s2 += __shfl_xor(s2, m);
        }
        if (t == 0) { W1s[n] = s1; cbv[n] = s2 + bh[n]; }
    } else if (blk < 1824) {
        // ---- prepw layer 1 (IN = HH), key = (mat,n), wave per key
        int key = (blk - 1568) * 4 + (tid >> 6);
        int lane = tid & 63;
        int mat = key >> 8, n = key & 255;
        const float* W = (mat == 0) ? Wq1 : (mat == 1) ? Wk1 : (mat == 2) ? Wv1 : Ws1;
        ushort_t* hi = WhA + mat * 256 * HH;
        ushort_t* lo = WlA + mat * 256 * HH;
        int sw = 8 * (n & 15);
        for (int k = lane; k < HH; k += 64) {
            float w = W[k * HD + n];
            ushort_t hb = f2us_tr(w);
            float l = w - us2f(hb);
            hi[n * HH + (k ^ sw)] = hb;
            lo[n * HH + (k ^ sw)] = f2us_tr(l);
        }
    } else {
        // ---- prepw layer 2 (IN = HD)
        int key = (blk - 1824) * 4 + (tid >> 6);
        int lane = tid & 63;
        int mat = key >> 8, n = key & 255;
        const float* W = (mat == 0) ? Wq2 : (mat == 1) ? Wk2 : (mat == 2) ? Wv2 : Ws2;
        ushort_t* hi = WhB + mat * 256 * HD;
        ushort_t* lo = WlB + mat * 256 * HD;
        int sw = 8 * (n & 15);
        for (int k = lane; k < HD; k += 64) {
            float w = W[k * HD + n];
            ushort_t hb = f2us_tr(w);
            float l = w - us2f(hb);
            hi[n * HD + (k ^ sw)] = hb;
            lo[n * HD + (k ^ sw)] = f2us_tr(l);
        }
    }
}

// ---------------- K3: embed conv, MFMA, compacted s-lists ------------------
// D[n][t] = Wh'^T (LDS, A-op) x raw relu(h1)^T (regs, B-op).  B col = t = nl.
// Per column t, only UNMASKED s are processed (p(mask)=0.5): lane walks its
// own compacted list; wave wv takes contiguous quarter (bit-identical order;
// skipped entries contributed exactly 0 via fmaf(0,h2,acc)).
// LN1 applied POST-mfma: pre2 = r1*Graw + nm*W1s[n] + cb[n]  (nm = -m1*r1).
__global__ void __launch_bounds__(256) k_econv_mfma(
    const uchar_t* sl_s, const float* sl_av, const int* cnts,
    const float* base, const float* W1,
    const ushort_t* BhiG, const ushort_t* BloG,
    const float* W1sg, const float* cbv,
    const float* ghp, const float* behp, float* x0)
{
    __shared__ __align__(16) ushort_t PhiPlo[2 * HH * HH];   // 64 KB
    ushort_t* Phi = PhiPlo;
    ushort_t* Plo = PhiPlo + HH * HH;

    int blk = blockIdx.x;
    int b  = blk >> 4;
    int tt = (blk >> 1) & 7;
    int sh = blk & 1;
    int t0 = tt * 16;
    int tid = threadIdx.x;
    int wv  = tid >> 6;
    int lane = tid & 63;
    int nl = lane & 15;
    int quad = lane >> 4;

    {
        const uint4* srcH = (const uint4*)BhiG;
        const uint4* srcL = (const uint4*)BloG;
        uint4* dstH = (uint4*)Phi;
        uint4* dstL = (uint4*)Plo;
        for (int i = tid; i < HH * HH / 8; i += 256) {
            dstH[i] = srcH[i];
            dstL[i] = srcL[i];
        }
    }

    float w17v[4][8];
#pragma unroll
    for (int st = 0; st < 4; st++) {
        const float* p = W1 + 17 * HH + quad * 8 + 32 * st;
        float4 a = *(const float4*)p;
        float4 bq = *(const float4*)(p + 4);
        w17v[st][0] = a.x;  w17v[st][1] = a.y;  w17v[st][2] = a.z;  w17v[st][3] = a.w;
        w17v[st][4] = bq.x; w17v[st][5] = bq.y; w17v[st][6] = bq.z; w17v[st][7] = bq.w;
    }

    // per-lane (col t) compacted list
    int key = ((b * NN) + t0 + nl) * 2 + sh;
    int cnt = cnts[key];
    int q = (cnt + 3) >> 2;              // per-wave chunk
    int mq = q;
#pragma unroll
    for (int m = 1; m < 16; m <<= 1) mq = max(mq, __shfl_xor(mq, m));
    const uchar_t* lst_s = sl_s + key * 64;
    const float*   lst_a = sl_av + key * 64;
    int i0 = wv * q;

    fx4 acc1[8];                 // sum_s mask*r2*h2   (per n, per t=nl)
#pragma unroll
    for (int tile = 0; tile < 8; tile++) acc1[tile] = (fx4){0.f, 0.f, 0.f, 0.f};
    float c0 = 0.f;              // sum_s mask
    float c1 = 0.f;              // sum_s mask*r2*mean2

    __syncthreads();

    for (int i = 0; i < mq; i++) {
        int idx = i0 + i;
        bool val = (i < q) && (idx < cnt);
        int ridx = (idx < cnt) ? idx : (cnt > 0 ? cnt - 1 : 0);
        int s = lst_s[ridx];
        float avv = val ? lst_a[ridx] : 0.f;
        const float* brow = base + (b * NN + s) * HH;

        // one pass: vv = relu(base + avv*w17); stats + pair-packed hi/lo
        short8 Hhi[4], Hlo[4];
        float sm = 0.f, s2 = 0.f;
#pragma unroll
        for (int st = 0; st < 4; st++) {
            const float* p = brow + quad * 8 + 32 * st;
            float4 b0 = *(const float4*)p;
            float4 b1q = *(const float4*)(p + 4);
            float h[8] = {b0.x, b0.y, b0.z, b0.w, b1q.x, b1q.y, b1q.z, b1q.w};
            uint_t hw[4], lw[4];
#pragma unroll
            for (int pr = 0; pr < 4; pr++) {
                float a = fmaxf(fmaf(avv, w17v[st][2 * pr], h[2 * pr]), 0.f);
                float c = fmaxf(fmaf(avv, w17v[st][2 * pr + 1], h[2 * pr + 1]), 0.f);
                sm += a; sm += c;
                s2 = fmaf(a, a, s2);
                s2 = fmaf(c, c, s2);
                pair_split(a, c, hw[pr], lw[pr]);
            }
            Hhi[st] = pack4(hw[0], hw[1], hw[2], hw[3]);
            Hlo[st] = pack4(lw[0], lw[1], lw[2], lw[3]);
        }
        sm += __shfl_xor(sm, 16); sm += __shfl_xor(sm, 32);
        s2 += __shfl_xor(s2, 16); s2 += __shfl_xor(s2, 32);
        float m1 = sm * (1.f / 128.f);
        float r1 = rsqrtf(s2 * (1.f / 128.f) - m1 * m1 + 1e-5f);
        float nm = -m1 * r1;

        // Graw = Wh'^T @ vv
        fx4 G[8];
#pragma unroll
        for (int tile = 0; tile < 8; tile++) G[tile] = (fx4){0.f, 0.f, 0.f, 0.f};
#pragma unroll
        for (int st = 0; st < 4; st++) {
            int koff = quad * 8 + 32 * st;
#pragma unroll
            for (int tile = 0; tile < 8; tile++) {
                int off = (tile * 16 + nl) * HH + (koff ^ (nl * 8));
                short8 ph = *(const short8*)(&Phi[off]);
                short8 pl = *(const short8*)(&Plo[off]);
                G[tile] = __builtin_amdgcn_mfma_f32_16x16x32_bf16(ph, Hhi[st], G[tile], 0, 0, 0);
                G[tile] = __builtin_amdgcn_mfma_f32_16x16x32_bf16(pl, Hhi[st], G[tile], 0, 0, 0);
                G[tile] = __builtin_amdgcn_mfma_f32_16x16x32_bf16(ph, Hlo[st], G[tile], 0, 0, 0);
            }
        }

        // LN1 correction + relu; LN2 stats (in-lane over 32 n + 2 shuffles)
        float sm2 = 0.f, ss2 = 0.f;
#pragma unroll
        for (int tile = 0; tile < 8; tile++) {
            float4 w4 = *(const float4*)(W1sg + tile * 16 + quad * 4);
            float4 c4 = *(const float4*)(cbv + tile * 16 + quad * 4);
            float wa[4] = {w4.x, w4.y, w4.z, w4.w};
            float ca[4] = {c4.x, c4.y, c4.z, c4.w};
#pragma unroll
            for (int r = 0; r < 4; r++) {
                float pre = fmaf(r1, G[tile][r], fmaf(nm, wa[r], ca[r]));
                float h2 = fmaxf(pre, 0.f);
                G[tile][r] = h2;
                sm2 += h2;
                ss2 = fmaf(h2, h2, ss2);
            }
        }
        sm2 += __shfl_xor(sm2, 16); sm2 += __shfl_xor(sm2, 32);
        ss2 += __shfl_xor(ss2, 16); ss2 += __shfl_xor(ss2, 32);
        float mean2 = sm2 * (1.f / 128.f);
        float r2 = rsqrtf(ss2 * (1.f / 128.f) - mean2 * mean2 + 1e-5f);
        float msk = val ? 1.f : 0.f;
        float mr2 = msk * r2;

#pragma unroll
        for (int tile = 0; tile < 8; tile++)
#pragma unroll
            for (int r = 0; r < 4; r++)
                acc1[tile][r] = fmaf(mr2, G[tile][r], acc1[tile][r]);
        c0 += msk;
        c1 = fmaf(mr2, mean2, c1);
    }

    // ---- epilogue: xv = gh*(acc1 - c1) + beh*c0 ;  cross-wave LDS reduce,
    //      then coalesced atomics (consecutive lanes -> consecutive n) ----
    __syncthreads();                       // Phi/Plo dead; reuse as f32 slab
    float* slab = (float*)PhiPlo;          // [4 waves][16 t][stride 132]
#pragma unroll
    for (int tile = 0; tile < 8; tile++) {
        float4 g4 = *(const float4*)(ghp + tile * 16 + quad * 4);
        float4 be4 = *(const float4*)(behp + tile * 16 + quad * 4);
        float gv[4] = {g4.x, g4.y, g4.z, g4.w};
        float bv[4] = {be4.x, be4.y, be4.z, be4.w};
#pragma unroll
        for (int r = 0; r < 4; r++) {
            float xv = fmaf(gv[r], acc1[tile][r] - c1, bv[r] * c0);
            slab[(wv * 16 + nl) * 132 + tile * 16 + quad * 4 + r] = xv;
        }
    }
    __syncthreads();
    for (int e = tid; e < 16 * HH; e += 256) {
        int t = e >> 7, n = e & 127;
        float vsum = slab[t * 132 + n] + slab[(16 + t) * 132 + n]
                   + slab[(32 + t) * 132 + n] + slab[(48 + t) * 132 + n];
        atomicAdd(&x0[(b * NN + t0 + t) * HH + n], vsum);
    }
}

// ---------------- K5: qkvs via MFMA, 512 blocks (32-col n slices) ---------
template <int IN>
__global__ void __launch_bounds__(256) k_qkvs_mfma(
    const float* x, const ushort_t* Whi, const ushort_t* Wlo,
    const float* b0, const float* b1, const float* b2, const float* b3,
    float* q, float* skipo,
    ushort_t* khi, ushort_t* klo, ushort_t* vThi, ushort_t* vTlo)
{
    const int ST = IN / 32;
    int blk = blockIdx.x;             // 512 = 64 m-blocks * 8 col slices
    int m0 = (blk >> 3) * 64;
    int nsl = blk & 7;                // 32-col slice
    int tid = threadIdx.x;
    int wv = tid >> 6;
    int lane = tid & 63;
    int nl = lane & 15;
    int quad = lane >> 4;
    int row = m0 + wv * 16 + nl;

    short8 Ahi[ST], Alo[ST];
    const float* xrow = x + (long)row * IN;
#pragma unroll
    for (int st = 0; st < ST; st++) {
        const float* p = xrow + quad * 8 + 32 * st;
        float4 a4 = *(const float4*)p;
        float4 b4 = *(const float4*)(p + 4);
        float h[8] = {a4.x, a4.y, a4.z, a4.w, b4.x, b4.y, b4.z, b4.w};
        uint_t hw[4], lw[4];
#pragma unroll
        for (int pr = 0; pr < 4; pr++)
            pair_split(h[2 * pr], h[2 * pr + 1], hw[pr], lw[pr]);
        Ahi[st] = pack4(hw[0], hw[1], hw[2], hw[3]);
        Alo[st] = pack4(lw[0], lw[1], lw[2], lw[3]);
    }

    const float* bs_[4] = {b0, b1, b2, b3};

#pragma unroll
    for (int mat = 0; mat < 4; mat++) {
        const ushort_t* Bh = Whi + (mat * 256 + nsl * 32) * IN;
        const ushort_t* Bl = Wlo + (mat * 256 + nsl * 32) * IN;
        fx4 G[2];
#pragma unroll
        for (int tile = 0; tile < 2; tile++) {
            float bc = bs_[mat][nsl * 32 + tile * 16 + nl];
            G[tile] = (fx4){bc, bc, bc, bc};
        }
#pragma unroll
        for (int st = 0; st < ST; st++) {
            int koff = quad * 8 + 32 * st;
#pragma unroll
            for (int tile = 0; tile < 2; tile++) {
                int off = (tile * 16 + nl) * IN + (koff ^ (nl * 8));
                short8 bh8 = *(const short8*)(Bh + off);
                short8 bl8 = *(const short8*)(Bl + off);
                G[tile] = __builtin_amdgcn_mfma_f32_16x16x32_bf16(Ahi[st], bh8, G[tile], 0, 0, 0);
                G[tile] = __builtin_amdgcn_mfma_f32_16x16x32_bf16(Alo[st], bh8, G[tile], 0, 0, 0);
                G[tile] = __builtin_amdgcn_mfma_f32_16x16x32_bf16(Ahi[st], bl8, G[tile], 0, 0, 0);
            }
        }
        int row0 = m0 + wv * 16 + quad * 4;          // rows r=0..3
        if (mat == 0 || mat == 3) {
            float* om = (mat == 0) ? q : skipo;
#pragma unroll
            for (int tile = 0; tile < 2; tile++)
#pragma unroll
                for (int r = 0; r < 4; r++)
                    om[(row0 + r) * HD + nsl * 32 + tile * 16 + nl] = G[tile][r];
        } else if (mat == 1) {
            // K planes, layout [row=b*128+s][256]
#pragma unroll
            for (int tile = 0; tile < 2; tile++) {
                int col = nsl * 32 + tile * 16 + nl;
#pragma unroll
                for (int r = 0; r < 4; r++) {
                    float gv = G[tile][r];
                    ushort_t hb = f2us_tr(gv);
                    khi[(row0 + r) * HD + col] = hb;
                    klo[(row0 + r) * HD + col] = f2us_tr(gv - us2f(hb));
                }
            }
        } else {
            // vT planes: vT[dg = b*256 + col][128 s], 4 consecutive s packed
            int bb = row0 >> 7;
            int s0 = row0 & 127;
#pragma unroll
            for (int tile = 0; tile < 2; tile++) {
                int col = nsl * 32 + tile * 16 + nl;
                int dg = bb * 256 + col;
                ushort4 h4, l4;
                float g0 = G[tile][0], g1 = G[tile][1], g2 = G[tile][2], g3 = G[tile][3];
                ushort_t h0 = f2us_tr(g0), h1 = f2us_tr(g1), h2 = f2us_tr(g2), h3 = f2us_tr(g3);
                h4.x = h0; h4.y = h1; h4.z = h2; h4.w = h3;
                l4.x = f2us_tr(g0 - us2f(h0));
                l4.y = f2us_tr(g1 - us2f(h1));
                l4.z = f2us_tr(g2 - us2f(h2));
                l4.w = f2us_tr(g3 - us2f(h3));
                *(ushort4*)&vThi[dg * NN + s0] = h4;
                *(ushort4*)&vTlo[dg * NN + s0] = l4;
            }
        }
    }
}

// ---------------- K6: attention via MFMA, 1 wave per (b,h,16-t tile) -------
// agentp==nullptr: layer-1 mode, write full xout.
// agentp!=nullptr: layer-2 mode, write ONLY the agent row directly to outp
//                  (fused gather; x2 store dropped, no other consumer).
__global__ void __launch_bounds__(64) k_attn_mfma(
    const float* qb, const ushort_t* khi, const ushort_t* klo,
    const ushort_t* vThi, const ushort_t* vTlo,
    const float* adjvT, const float* We, const float* skip, float* xout,
    const int* agentp, float* outp)
{
    __shared__ float aL[16][132];     // alpha C->A round-trip (8.4 KB)
    __shared__ float qeL[16];

    int blk = blockIdx.x;             // 1024 = 32b*4h*8tt
    int b  = blk >> 5;
    int h  = (blk >> 3) & 3;
    int tt = blk & 7;
    int t0 = tt * 16;
    int lane = threadIdx.x;
    int nl = lane & 15;
    int quad = lane >> 4;

    // ---- Q A-frags (split hi/lo) + qe partial (q . we) ----
    short8 Qhi[2], Qlo[2];
    float qe = 0.f;
#pragma unroll
    for (int ks = 0; ks < 2; ks++) {
        const float* p = qb + (b * NN + t0 + nl) * HD + h * DHEAD + quad * 8 + 32 * ks;
        const float* wp = We + h * DHEAD + quad * 8 + 32 * ks;
        float4 a0 = *(const float4*)p;
        float4 a1 = *(const float4*)(p + 4);
        float4 w0 = *(const float4*)wp;
        float4 w1 = *(const float4*)(wp + 4);
        float hv[8] = {a0.x, a0.y, a0.z, a0.w, a1.x, a1.y, a1.z, a1.w};
        float wv8[8] = {w0.x, w0.y, w0.z, w0.w, w1.x, w1.y, w1.z, w1.w};
        uint_t hw[4], lw[4];
#pragma unroll
        for (int pr = 0; pr < 4; pr++) {
            float a = hv[2 * pr], c = hv[2 * pr + 1];
            qe = fmaf(a, wv8[2 * pr], qe);
            qe = fmaf(c, wv8[2 * pr + 1], qe);
            pair_split(a, c, hw[pr], lw[pr]);
        }
        Qhi[ks] = pack4(hw[0], hw[1], hw[2], hw[3]);
        Qlo[ks] = pack4(lw[0], lw[1], lw[2], lw[3]);
    }
    qe += __shfl_xor(qe, 16);
    qe += __shfl_xor(qe, 32);
    if (lane < 16) qeL[lane] = qe;    // qe for t = lane
    __syncthreads();
    float qe_r[4];
#pragma unroll
    for (int r = 0; r < 4; r++) qe_r[r] = qeL[quad * 4 + r];
    float we_d[4];
#pragma unroll
    for (int nt = 0; nt < 4; nt++) we_d[nt] = We[h * DHEAD + nt * 16 + nl];

    // ---- QK^T: S[t][s], 8 s-tiles ----
    fx4 S[8];
#pragma unroll
    for (int st = 0; st < 8; st++) S[st] = (fx4){0.f, 0.f, 0.f, 0.f};
#pragma unroll
    for (int ks = 0; ks < 2; ks++) {
#pragma unroll
        for (int st = 0; st < 8; st++) {
            long off = (long)(b * NN + st * 16 + nl) * HD + h * DHEAD + quad * 8 + 32 * ks;
            short8 bh8 = *(const short8*)(khi + off);
            short8 bl8 = *(const short8*)(klo + off);
            S[st] = __builtin_amdgcn_mfma_f32_16x16x32_bf16(Qhi[ks], bh8, S[st], 0, 0, 0);
            S[st] = __builtin_amdgcn_mfma_f32_16x16x32_bf16(Qlo[ks], bh8, S[st], 0, 0, 0);
            S[st] = __builtin_amdgcn_mfma_f32_16x16x32_bf16(Qhi[ks], bl8, S[st], 0, 0, 0);
        }
    }

    // ---- masked logits (D-layout: row t = quad*4+r, col s = st*16+nl) ----
    float av[8][4];
#pragma unroll
    for (int st = 0; st < 8; st++)
#pragma unroll
        for (int r = 0; r < 4; r++)
            av[st][r] = adjvT[(b * NN + t0 + quad * 4 + r) * NN + st * 16 + nl];
#pragma unroll
    for (int st = 0; st < 8; st++)
#pragma unroll
        for (int r = 0; r < 4; r++) {
            float a = av[st][r];
            S[st][r] = (a != 0.f) ? (S[st][r] + a * qe_r[r]) * 0.125f : -1e30f;
        }

    // ---- softmax per row: reduce over s = in-lane stiles + xor{1,2,4,8} ----
    float mx[4], den[4], beta[4];
#pragma unroll
    for (int r = 0; r < 4; r++) {
        float m = S[0][r];
#pragma unroll
        for (int st = 1; st < 8; st++) m = fmaxf(m, S[st][r]);
#pragma unroll
        for (int mm = 1; mm < 16; mm <<= 1) m = fmaxf(m, __shfl_xor(m, mm));
        mx[r] = m;
    }
#pragma unroll
    for (int r = 0; r < 4; r++) den[r] = 0.f;
#pragma unroll
    for (int st = 0; st < 8; st++)
#pragma unroll
        for (int r = 0; r < 4; r++) {
            float e = (av[st][r] != 0.f) ? __expf(S[st][r] - mx[r]) : 0.f;
            S[st][r] = e;
            den[r] += e;
        }
#pragma unroll
    for (int r = 0; r < 4; r++) {
#pragma unroll
        for (int mm = 1; mm < 16; mm <<= 1) den[r] += __shfl_xor(den[r], mm);
        den[r] = 1.f / fmaxf(den[r], 1e-16f);
        beta[r] = 0.f;
    }
#pragma unroll
    for (int st = 0; st < 8; st++)
#pragma unroll
        for (int r = 0; r < 4; r++) {
            float al = S[st][r] * den[r];
            S[st][r] = al;
            beta[r] += al * av[st][r];
        }
#pragma unroll
    for (int r = 0; r < 4; r++)
#pragma unroll
        for (int mm = 1; mm < 16; mm <<= 1) beta[r] += __shfl_xor(beta[r], mm);

    // ---- alpha C-layout -> LDS -> A-layout frags (hi only) ----
#pragma unroll
    for (int st = 0; st < 8; st++)
#pragma unroll
        for (int r = 0; r < 4; r++)
            aL[quad * 4 + r][st * 16 + nl] = S[st][r];
    __syncthreads();
    short8 Ah[4];
#pragma unroll
    for (int ks = 0; ks < 4; ks++) {
        const float* p = &aL[nl][quad * 8 + 32 * ks];
        float4 a0 = *(const float4*)p;
        float4 a1 = *(const float4*)(p + 4);
        float hv[8] = {a0.x, a0.y, a0.z, a0.w, a1.x, a1.y, a1.z, a1.w};
        uint_t w[4];
#pragma unroll
        for (int pr = 0; pr < 4; pr++) w[pr] = pair_hi(hv[2 * pr], hv[2 * pr + 1]);
        Ah[ks] = pack4(w[0], w[1], w[2], w[3]);
    }

    // ---- PV: out[t][d] = beta*we + alpha @ V (V via vT planes) ----
    fx4 G[4];
#pragma unroll
    for (int nt = 0; nt < 4; nt++) {
        fx4 g;
#pragma unroll
        for (int r = 0; r < 4; r++) g[r] = beta[r] * we_d[nt];
        G[nt] = g;
    }
#pragma unroll
    for (int ks = 0; ks < 4; ks++) {
#pragma unroll
        for (int nt = 0; nt < 4; nt++) {
            long dg = (long)(b * 256 + h * DHEAD + nt * 16 + nl);
            const short8 vh = *(const short8*)(vThi + dg * NN + quad * 8 + 32 * ks);
            const short8 vl = *(const short8*)(vTlo + dg * NN + quad * 8 + 32 * ks);
            G[nt] = __builtin_amdgcn_mfma_f32_16x16x32_bf16(Ah[ks], vh, G[nt], 0, 0, 0);
            G[nt] = __builtin_amdgcn_mfma_f32_16x16x32_bf16(Ah[ks], vl, G[nt], 0, 0, 0);
        }
    }

    // ---- epilogue ----
    if (agentp == nullptr) {
        // layer 1: full relu(out + skip) -> xout
#pragma unroll
        for (int nt = 0; nt < 4; nt++)
#pragma unroll
            for (int r = 0; r < 4; r++) {
                int gi = (b * NN + t0 + quad * 4 + r) * HD + h * DHEAD + nt * 16 + nl;
                xout[gi] = fmaxf(G[nt][r] + skip[gi], 0.f);
            }
    } else {
        // layer 2 + fused gather: only the agent row reaches the output
        int ag = agentp[b];
#pragma unroll
        for (int nt = 0; nt < 4; nt++)
#pragma unroll
            for (int r = 0; r < 4; r++) {
                int t = t0 + quad * 4 + r;
                if (t == ag) {
                    int gi = (b * NN + t) * HD + h * DHEAD + nt * 16 + nl;
                    outp[b * HD + h * DHEAD + nt * 16 + nl] = fmaxf(G[nt][r] + skip[gi], 0.f);
                }
            }
    }
}

// ---------------- launch ----------------
extern "C" void kernel_launch(void* const* d_in, const int* in_sizes, int n_in,
                              void* d_out, int out_size, void* d_ws, size_t ws_size,
                              hipStream_t stream) {
    float* out = (float*)d_out;
    (void)hipGetLastError();

    bool ok = (n_in == 31) && in_sizes[0] == BB * NN * FF && in_sizes[2] == BB * NN * NN
              && in_sizes[5] == (FF + EE + 1) * HH && in_sizes[13] == HH * HD
              && in_sizes[22] == HD * HD && out_size == BB * HD;
    if (!ok) { k_sent<<<32, 256, 0, stream>>>(out, -30000.f); return; }

    const size_t WS_NEED = (size_t)8912896 * 4;
    if (ws_size < WS_NEED) { k_sent<<<32, 256, 0, stream>>>(out, -20000.f); return; }

    const float* nf    = (const float*)d_in[0];
    const int*   et    = (const int*)d_in[1];
    const float* adj   = (const float*)d_in[2];
    const int*   agent = (const int*)d_in[3];
    const float* emb   = (const float*)d_in[4];
    const float* W1    = (const float*)d_in[5];
    const float* b1    = (const float*)d_in[6];
    const float* g1    = (const float*)d_in[7];
    const float* be1   = (const float*)d_in[8];
    const float* Wh    = (const float*)d_in[9];
    const float* bh    = (const float*)d_in[10];
    const float* gh    = (const float*)d_in[11];
    const float* beh   = (const float*)d_in[12];
    const float* Wq1   = (const float*)d_in[13];
    const float* bq1   = (const float*)d_in[14];
    const float* Wk1   = (const float*)d_in[15];
    const float* bk1   = (const float*)d_in[16];
    const float* Wv1   = (const float*)d_in[17];
    const float* bv1   = (const float*)d_in[18];
    const float* We1   = (const float*)d_in[19];
    const float* Ws1   = (const float*)d_in[20];
    const float* bs1   = (const float*)d_in[21];
    const float* Wq2   = (const float*)d_in[22];
    const float* bq2   = (const float*)d_in[23];
    const float* Wk2   = (const float*)d_in[24];
    const float* bk2   = (const float*)d_in[25];
    const float* Wv2   = (const float*)d_in[26];
    const float* bv2   = (const float*)d_in[27];
    const float* We2   = (const float*)d_in[28];
    const float* Ws2   = (const float*)d_in[29];
    const float* bs2   = (const float*)d_in[30];

    float* ws   = (float*)d_ws;
    float* slav = ws;                              // 524288 f region (sl_av)
    float* base = ws + 524288;                     // 524288 f
    float* x0   = base + BB * NN * HH;             // 524288 f
    float* q    = x0 + BB * NN * HH;               // 1048576 f
    float* kreg = q + BB * NN * HD;                // 1048576 f -> khi/klo
    float* vreg = kreg + BB * NN * HD;             // 1048576 f -> vThi/vTlo
    float* skip = vreg + BB * NN * HD;             // 1048576 f
    float* areg = skip + BB * NN * HD;             // 1048576 f -> planes + adjvT + sl_s
    float* x1   = areg + BB * NN * HD;
    float* x2   = x1 + BB * NN * HD;

    // econv prep planes in q region (q first written AFTER econv)
    ushort_t* BhiG = (ushort_t*)q;
    ushort_t* BloG = BhiG + HH * HH;
    float*    W1sW = q + 16384;
    float*    cbW  = q + 16512;
    int*      cnts = (int*)(q + 17024);            // 8192 ints, free q space

    // K / vT planes
    ushort_t* khi  = (ushort_t*)kreg;              // 1048576 ush
    ushort_t* klo  = khi + BB * NN * HD;           // 1048576 ush
    ushort_t* vThi = (ushort_t*)vreg;
    ushort_t* vTlo = vThi + BB * NN * HD;

    // qkvs weight planes + adjvT + sl_s in areg (4 MB):
    // planes 1.5 MB + adjvT 2 MB + sl_s 0.5 MB = 4 MB exactly
    ushort_t* WhA = (ushort_t*)areg;               // 4*256*128 ush
    ushort_t* WlA = WhA + 4 * 256 * HH;
    ushort_t* WhB = WlA + 4 * 256 * HH;            // 4*256*256 ush
    ushort_t* WlB = WhB + 4 * 256 * HD;
    float* adjvT  = areg + 393216;                 // 524288 f, past planes
    uchar_t* sl_s = (uchar_t*)(areg + 917504);     // 524288 uchars, tail

    int fail = 0;
    hipError_t e;
#define CHK(stage) do { e = hipGetLastError(); if (e != hipSuccess && fail == 0) fail = (stage); } while (0)

    k_prep_all<<<2080, 256, 0, stream>>>(
        adj, adjvT, sl_s, slav, cnts,
        nf, et, emb, W1, b1, base, x0,
        Wh, g1, be1, bh, BhiG, BloG, W1sW, cbW,
        Wq1, Wk1, Wv1, Ws1, WhA, WlA,
        Wq2, Wk2, Wv2, Ws2, WhB, WlB);                                               CHK(1);

    k_econv_mfma<<<512, 256, 0, stream>>>(sl_s, slav, cnts, base, W1,
                                          BhiG, BloG, W1sW, cbW, gh, beh, x0);       CHK(2);

    k_qkvs_mfma<HH><<<512, 256, 0, stream>>>(x0, WhA, WlA, bq1, bk1, bv1, bs1,
                                             q, skip, khi, klo, vThi, vTlo);         CHK(3);
    k_attn_mfma<<<1024, 64, 0, stream>>>(q, khi, klo, vThi, vTlo, adjvT, We1,
                                         skip, x1, nullptr, nullptr);                CHK(4);

    k_qkvs_mfma<HD><<<512, 256, 0, stream>>>(x1, WhB, WlB, bq2, bk2, bv2, bs2,
                                             q, skip, khi, klo, vThi, vTlo);         CHK(5);
    k_attn_mfma<<<1024, 64, 0, stream>>>(q, khi, klo, vThi, vTlo, adjvT, We2,
                                         skip, x2, agent, out);                      CHK(6);
#undef CHK

    if (fail != 0)
        k_sent<<<32, 256, 0, stream>>>(out, -(1000.f + 500.f * (float)fail));
}

// Round 7
// 250.902 us; speedup vs baseline: 2.2574x; 1.0386x over previous
//
#include <hip/hip_runtime.h>
#include <hip/hip_bf16.h>

typedef __hip_bfloat16 bf16;
typedef unsigned short ushort_t;
typedef unsigned char uchar_t;
typedef unsigned int uint_t;
typedef __attribute__((ext_vector_type(8))) short short8;
typedef __attribute__((ext_vector_type(4))) float fx4;
typedef __attribute__((ext_vector_type(4))) unsigned int uintx4;

#define BB 32
#define NN 128
#define FF 9
#define EE 8
#define HH 128
#define HD 256
#define NHEAD 4
#define DHEAD 64

__device__ __forceinline__ float us2f(ushort_t u) {
    return __uint_as_float(((unsigned int)u) << 16);
}
// truncation split: hi = trunc16(v), lo = v - hi (lo exact in f32)
__device__ __forceinline__ ushort_t f2us_tr(float f) {
    return (ushort_t)(__float_as_uint(f) >> 16);
}
__device__ __forceinline__ short8 pack4(uint_t w0, uint_t w1, uint_t w2, uint_t w3) {
    uintx4 u = (uintx4){w0, w1, w2, w3};
    return __builtin_bit_cast(short8, u);
}
// pair split: a -> low short of word, c -> high short (bit-identical to
// per-element f2us_tr path: keep = bits & 0xffff0000 == us2f(f2us_tr(x)))
__device__ __forceinline__ void pair_split(float a, float c, uint_t& hw, uint_t& lw) {
    uint_t ua = __float_as_uint(a), uc = __float_as_uint(c);
    uint_t ka = ua & 0xffff0000u, kc = uc & 0xffff0000u;
    float la = a - __uint_as_float(ka);
    float lc = c - __uint_as_float(kc);
    hw = (ua >> 16) | kc;
    lw = (__float_as_uint(la) >> 16) | (__float_as_uint(lc) & 0xffff0000u);
}
__device__ __forceinline__ uint_t pair_hi(float a, float c) {
    return (__float_as_uint(a) >> 16) | (__float_as_uint(c) & 0xffff0000u);
}

__global__ void TransformerConvNet_85315230367963_kernel() {}

__global__ void k_sent(float* out, float val) {
    out[blockIdx.x * 256 + threadIdx.x] = val;
}

// ---------------- K_prep_all: all independent prep work, ONE launch -------
// blocks [0,256):      adjvT (masked transpose) + ballot-compacted s-lists
// blocks [256,1280):   base = src @ W1[:17] + b1          (1024 blocks)
// blocks [1280,1536):  zero x0                            (256 blocks)
// blocks [1536,1568):  Wh' split hi/lo + W1s/cb           (32 blocks, 4 n/blk)
// blocks [1568,1824):  prepw layer1 (IN=128)              (256 blocks, 4 keys/blk)
// blocks [1824,2080):  prepw layer2 (IN=256)              (256 blocks, 4 keys/blk)
__global__ void __launch_bounds__(256) k_prep_all(
    const float* adj, float* adjvT, uchar_t* sl_s, float* sl_av, int* cnts,
    const float* nf, const int* et, const float* emb, const float* W1,
    const float* b1, float* base, float* x0,
    const float* Wh, const float* g1, const float* be1, const float* bh,
    ushort_t* BhiG, ushort_t* BloG, float* W1s, float* cbv,
    const float* Wq1, const float* Wk1, const float* Wv1, const float* Ws1,
    ushort_t* WhA, ushort_t* WlA,
    const float* Wq2, const float* Wk2, const float* Wv2, const float* Ws2,
    ushort_t* WhB, ushort_t* WlB)
{
    int blk = blockIdx.x;
    int tid = threadIdx.x;

    if (blk < 256) {
        // ---- adjvT + slist (ballot compaction, ascending-s == serial order)
        int b = blk >> 3, sl = blk & 7;
        int wv = tid >> 6, lane = tid & 63;
#pragma unroll
        for (int j = 0; j < 8; j++) {
            int u = wv * 8 + j;               // 32 (t,sh) units per block
            int t = sl * 16 + (u >> 1);
            int sh = u & 1;
            int s = sh * 64 + lane;
            float a = adj[(b * NN + s) * NN + t];
            float av = (a > 0.f && a < 1.0f) ? a : 0.f;
            adjvT[(b * NN + t) * NN + s] = av;
            unsigned long long mask = __ballot(av != 0.f);
            int key = (b * NN + t) * 2 + sh;
            if (av != 0.f) {
                int pos = __popcll(mask & ((1ull << lane) - 1ull));
                sl_s[key * 64 + pos] = (uchar_t)s;
                sl_av[key * 64 + pos] = av;
            }
            if (lane == 0) {
                cnts[key] = (int)__popcll(mask);
                if (mask == 0ull) { sl_s[key * 64] = 0; sl_av[key * 64] = 0.f; }
            }
        }
    } else if (blk < 1280) {
        // ---- base rows (4 per block)
        int bblk = blk - 256;
        int c = tid & 127;
#pragma unroll
        for (int rr = 0; rr < 2; rr++) {
            int bs = bblk * 4 + rr * 2 + (tid >> 7);
            int ty = et[bs];
            float acc = b1[c];
            for (int f = 0; f < FF; f++)
                acc += nf[bs * FF + f] * W1[f * HH + c];
            for (int e2 = 0; e2 < EE; e2++)
                acc += emb[ty * EE + e2] * W1[(FF + e2) * HH + c];
            base[bs * HH + c] = acc;
        }
    } else if (blk < 1536) {
        // ---- zero x0 (524288 floats = 131072 float4)
        int zblk = blk - 1280;
        float4* p = (float4*)x0 + zblk * 512 + tid * 2;
        p[0] = (float4){0.f, 0.f, 0.f, 0.f};
        p[1] = (float4){0.f, 0.f, 0.f, 0.f};
    } else if (blk < 1568) {
        // ---- Wh' = g1*Wh split bf16 hi/lo, swizzled; W1s/cb (wave per n)
        int n = (blk - 1536) * 4 + (tid >> 6);
        int t = tid & 63;
        int sw = 8 * (n & 15);
        float s1 = 0.f, s2 = 0.f;
#pragma unroll
        for (int kk = 0; kk < 2; kk++) {
            int k = t + kk * 64;
            float w = Wh[k * HH + n];
            float wp = g1[k] * w;
            ushort_t hb = f2us_tr(wp);
            float lo = wp - us2f(hb);
            BhiG[n * HH + (k ^ sw)] = hb;
            BloG[n * HH + (k ^ sw)] = f2us_tr(lo);
            s1 += wp;
            s2 += be1[k] * w;
        }
        for (int m = 1; m < 64; m <<= 1) {
            s1 += __shfl_xor(s1, m);
            s2 += __shfl_xor(s2, m);
        }
        if (t == 0) { W1s[n] = s1; cbv[n] = s2 + bh[n]; }
    } else if (blk < 1824) {
        // ---- prepw layer 1 (IN = HH), key = (mat,n), wave per key
        int key = (blk - 1568) * 4 + (tid >> 6);
        int lane = tid & 63;
        int mat = key >> 8, n = key & 255;
        const float* W = (mat == 0) ? Wq1 : (mat == 1) ? Wk1 : (mat == 2) ? Wv1 : Ws1;
        ushort_t* hi = WhA + mat * 256 * HH;
        ushort_t* lo = WlA + mat * 256 * HH;
        int sw = 8 * (n & 15);
        for (int k = lane; k < HH; k += 64) {
            float w = W[k * HD + n];
            ushort_t hb = f2us_tr(w);
            float l = w - us2f(hb);
            hi[n * HH + (k ^ sw)] = hb;
            lo[n * HH + (k ^ sw)] = f2us_tr(l);
        }
    } else {
        // ---- prepw layer 2 (IN = HD)
        int key = (blk - 1824) * 4 + (tid >> 6);
        int lane = tid & 63;
        int mat = key >> 8, n = key & 255;
        const float* W = (mat == 0) ? Wq2 : (mat == 1) ? Wk2 : (mat == 2) ? Wv2 : Ws2;
        ushort_t* hi = WhB + mat * 256 * HD;
        ushort_t* lo = WlB + mat * 256 * HD;
        int sw = 8 * (n & 15);
        for (int k = lane; k < HD; k += 64) {
            float w = W[k * HD + n];
            ushort_t hb = f2us_tr(w);
            float l = w - us2f(hb);
            hi[n * HD + (k ^ sw)] = hb;
            lo[n * HD + (k ^ sw)] = f2us_tr(l);
        }
    }
}

// ---------------- K3: embed conv, MFMA, compacted s-lists ------------------
// D[n][t] = Wh'^T (LDS, A-op) x raw relu(h1)^T (regs, B-op).  B col = t = nl.
// Per column t, only UNMASKED s are processed (p(mask)=0.5): lane walks its
// own compacted list; wave wv takes contiguous quarter (bit-identical order;
// skipped entries contributed exactly 0 via fmaf(0,h2,acc)).
// LN1 applied POST-mfma: pre2 = r1*Graw + nm*W1s[n] + cb[n]  (nm = -m1*r1).
__global__ void __launch_bounds__(256) k_econv_mfma(
    const uchar_t* sl_s, const float* sl_av, const int* cnts,
    const float* base, const float* W1,
    const ushort_t* BhiG, const ushort_t* BloG,
    const float* W1sg, const float* cbv,
    const float* ghp, const float* behp, float* x0)
{
    __shared__ __align__(16) ushort_t PhiPlo[2 * HH * HH];   // 64 KB
    ushort_t* Phi = PhiPlo;
    ushort_t* Plo = PhiPlo + HH * HH;

    int blk = blockIdx.x;
    int b  = blk >> 4;
    int tt = (blk >> 1) & 7;
    int sh = blk & 1;
    int t0 = tt * 16;
    int tid = threadIdx.x;
    int wv  = tid >> 6;
    int lane = tid & 63;
    int nl = lane & 15;
    int quad = lane >> 4;

    {
        const uint4* srcH = (const uint4*)BhiG;
        const uint4* srcL = (const uint4*)BloG;
        uint4* dstH = (uint4*)Phi;
        uint4* dstL = (uint4*)Plo;
        for (int i = tid; i < HH * HH / 8; i += 256) {
            dstH[i] = srcH[i];
            dstL[i] = srcL[i];
        }
    }

    float w17v[4][8];
#pragma unroll
    for (int st = 0; st < 4; st++) {
        const float* p = W1 + 17 * HH + quad * 8 + 32 * st;
        float4 a = *(const float4*)p;
        float4 bq = *(const float4*)(p + 4);
        w17v[st][0] = a.x;  w17v[st][1] = a.y;  w17v[st][2] = a.z;  w17v[st][3] = a.w;
        w17v[st][4] = bq.x; w17v[st][5] = bq.y; w17v[st][6] = bq.z; w17v[st][7] = bq.w;
    }

    // per-lane (col t) compacted list
    int key = ((b * NN) + t0 + nl) * 2 + sh;
    int cnt = cnts[key];
    int q = (cnt + 3) >> 2;              // per-wave chunk
    int mq = q;
#pragma unroll
    for (int m = 1; m < 16; m <<= 1) mq = max(mq, __shfl_xor(mq, m));
    const uchar_t* lst_s = sl_s + key * 64;
    const float*   lst_a = sl_av + key * 64;
    int i0 = wv * q;

    fx4 acc1[8];                 // sum_s mask*r2*h2   (per n, per t=nl)
#pragma unroll
    for (int tile = 0; tile < 8; tile++) acc1[tile] = (fx4){0.f, 0.f, 0.f, 0.f};
    float c0 = 0.f;              // sum_s mask
    float c1 = 0.f;              // sum_s mask*r2*mean2

    __syncthreads();

    for (int i = 0; i < mq; i++) {
        int idx = i0 + i;
        bool val = (i < q) && (idx < cnt);
        int ridx = (idx < cnt) ? idx : (cnt > 0 ? cnt - 1 : 0);
        int s = lst_s[ridx];
        float avv = val ? lst_a[ridx] : 0.f;
        const float* brow = base + (b * NN + s) * HH;

        // one pass: vv = relu(base + avv*w17); stats + pair-packed hi/lo
        short8 Hhi[4], Hlo[4];
        float sm = 0.f, s2 = 0.f;
#pragma unroll
        for (int st = 0; st < 4; st++) {
            const float* p = brow + quad * 8 + 32 * st;
            float4 b0 = *(const float4*)p;
            float4 b1q = *(const float4*)(p + 4);
            float h[8] = {b0.x, b0.y, b0.z, b0.w, b1q.x, b1q.y, b1q.z, b1q.w};
            uint_t hw[4], lw[4];
#pragma unroll
            for (int pr = 0; pr < 4; pr++) {
                float a = fmaxf(fmaf(avv, w17v[st][2 * pr], h[2 * pr]), 0.f);
                float c = fmaxf(fmaf(avv, w17v[st][2 * pr + 1], h[2 * pr + 1]), 0.f);
                sm += a; sm += c;
                s2 = fmaf(a, a, s2);
                s2 = fmaf(c, c, s2);
                pair_split(a, c, hw[pr], lw[pr]);
            }
            Hhi[st] = pack4(hw[0], hw[1], hw[2], hw[3]);
            Hlo[st] = pack4(lw[0], lw[1], lw[2], lw[3]);
        }
        sm += __shfl_xor(sm, 16); sm += __shfl_xor(sm, 32);
        s2 += __shfl_xor(s2, 16); s2 += __shfl_xor(s2, 32);
        float m1 = sm * (1.f / 128.f);
        float r1 = rsqrtf(s2 * (1.f / 128.f) - m1 * m1 + 1e-5f);
        float nm = -m1 * r1;

        // Graw = Wh'^T @ vv
        fx4 G[8];
#pragma unroll
        for (int tile = 0; tile < 8; tile++) G[tile] = (fx4){0.f, 0.f, 0.f, 0.f};
#pragma unroll
        for (int st = 0; st < 4; st++) {
            int koff = quad * 8 + 32 * st;
#pragma unroll
            for (int tile = 0; tile < 8; tile++) {
                int off = (tile * 16 + nl) * HH + (koff ^ (nl * 8));
                short8 ph = *(const short8*)(&Phi[off]);
                short8 pl = *(const short8*)(&Plo[off]);
                G[tile] = __builtin_amdgcn_mfma_f32_16x16x32_bf16(ph, Hhi[st], G[tile], 0, 0, 0);
                G[tile] = __builtin_amdgcn_mfma_f32_16x16x32_bf16(pl, Hhi[st], G[tile], 0, 0, 0);
                G[tile] = __builtin_amdgcn_mfma_f32_16x16x32_bf16(ph, Hlo[st], G[tile], 0, 0, 0);
            }
        }

        // LN1 correction + relu; LN2 stats (in-lane over 32 n + 2 shuffles)
        float sm2 = 0.f, ss2 = 0.f;
#pragma unroll
        for (int tile = 0; tile < 8; tile++) {
            float4 w4 = *(const float4*)(W1sg + tile * 16 + quad * 4);
            float4 c4 = *(const float4*)(cbv + tile * 16 + quad * 4);
            float wa[4] = {w4.x, w4.y, w4.z, w4.w};
            float ca[4] = {c4.x, c4.y, c4.z, c4.w};
#pragma unroll
            for (int r = 0; r < 4; r++) {
                float pre = fmaf(r1, G[tile][r], fmaf(nm, wa[r], ca[r]));
                float h2 = fmaxf(pre, 0.f);
                G[tile][r] = h2;
                sm2 += h2;
                ss2 = fmaf(h2, h2, ss2);
            }
        }
        sm2 += __shfl_xor(sm2, 16); sm2 += __shfl_xor(sm2, 32);
        ss2 += __shfl_xor(ss2, 16); ss2 += __shfl_xor(ss2, 32);
        float mean2 = sm2 * (1.f / 128.f);
        float r2 = rsqrtf(ss2 * (1.f / 128.f) - mean2 * mean2 + 1e-5f);
        float msk = val ? 1.f : 0.f;
        float mr2 = msk * r2;

#pragma unroll
        for (int tile = 0; tile < 8; tile++)
#pragma unroll
            for (int r = 0; r < 4; r++)
                acc1[tile][r] = fmaf(mr2, G[tile][r], acc1[tile][r]);
        c0 += msk;
        c1 = fmaf(mr2, mean2, c1);
    }

    // ---- epilogue: xv = gh*(acc1 - c1) + beh*c0 ;  cross-wave LDS reduce,
    //      then coalesced atomics (consecutive lanes -> consecutive n) ----
    __syncthreads();                       // Phi/Plo dead; reuse as f32 slab
    float* slab = (float*)PhiPlo;          // [4 waves][16 t][stride 132]
#pragma unroll
    for (int tile = 0; tile < 8; tile++) {
        float4 g4 = *(const float4*)(ghp + tile * 16 + quad * 4);
        float4 be4 = *(const float4*)(behp + tile * 16 + quad * 4);
        float gv[4] = {g4.x, g4.y, g4.z, g4.w};
        float bv[4] = {be4.x, be4.y, be4.z, be4.w};
#pragma unroll
        for (int r = 0; r < 4; r++) {
            float xv = fmaf(gv[r], acc1[tile][r] - c1, bv[r] * c0);
            slab[(wv * 16 + nl) * 132 + tile * 16 + quad * 4 + r] = xv;
        }
    }
    __syncthreads();
    for (int e = tid; e < 16 * HH; e += 256) {
        int t = e >> 7, n = e & 127;
        float vsum = slab[t * 132 + n] + slab[(16 + t) * 132 + n]
                   + slab[(32 + t) * 132 + n] + slab[(48 + t) * 132 + n];
        atomicAdd(&x0[(b * NN + t0 + t) * HH + n], vsum);
    }
}

// ---------------- K5: qkvs via MFMA, 512 blocks (32-col n slices) ---------
template <int IN>
__global__ void __launch_bounds__(256) k_qkvs_mfma(
    const float* x, const ushort_t* Whi, const ushort_t* Wlo,
    const float* b0, const float* b1, const float* b2, const float* b3,
    float* q, float* skipo,
    ushort_t* khi, ushort_t* klo, ushort_t* vThi, ushort_t* vTlo)
{
    const int ST = IN / 32;
    int blk = blockIdx.x;             // 512 = 64 m-blocks * 8 col slices
    int m0 = (blk >> 3) * 64;
    int nsl = blk & 7;                // 32-col slice
    int tid = threadIdx.x;
    int wv = tid >> 6;
    int lane = tid & 63;
    int nl = lane & 15;
    int quad = lane >> 4;
    int row = m0 + wv * 16 + nl;

    short8 Ahi[ST], Alo[ST];
    const float* xrow = x + (long)row * IN;
#pragma unroll
    for (int st = 0; st < ST; st++) {
        const float* p = xrow + quad * 8 + 32 * st;
        float4 a4 = *(const float4*)p;
        float4 b4 = *(const float4*)(p + 4);
        float h[8] = {a4.x, a4.y, a4.z, a4.w, b4.x, b4.y, b4.z, b4.w};
        uint_t hw[4], lw[4];
#pragma unroll
        for (int pr = 0; pr < 4; pr++)
            pair_split(h[2 * pr], h[2 * pr + 1], hw[pr], lw[pr]);
        Ahi[st] = pack4(hw[0], hw[1], hw[2], hw[3]);
        Alo[st] = pack4(lw[0], lw[1], lw[2], lw[3]);
    }

    const float* bs_[4] = {b0, b1, b2, b3};

#pragma unroll
    for (int mat = 0; mat < 4; mat++) {
        const ushort_t* Bh = Whi + (mat * 256 + nsl * 32) * IN;
        const ushort_t* Bl = Wlo + (mat * 256 + nsl * 32) * IN;
        fx4 G[2];
#pragma unroll
        for (int tile = 0; tile < 2; tile++) {
            float bc = bs_[mat][nsl * 32 + tile * 16 + nl];
            G[tile] = (fx4){bc, bc, bc, bc};
        }
#pragma unroll
        for (int st = 0; st < ST; st++) {
            int koff = quad * 8 + 32 * st;
#pragma unroll
            for (int tile = 0; tile < 2; tile++) {
                int off = (tile * 16 + nl) * IN + (koff ^ (nl * 8));
                short8 bh8 = *(const short8*)(Bh + off);
                short8 bl8 = *(const short8*)(Bl + off);
                G[tile] = __builtin_amdgcn_mfma_f32_16x16x32_bf16(Ahi[st], bh8, G[tile], 0, 0, 0);
                G[tile] = __builtin_amdgcn_mfma_f32_16x16x32_bf16(Alo[st], bh8, G[tile], 0, 0, 0);
                G[tile] = __builtin_amdgcn_mfma_f32_16x16x32_bf16(Ahi[st], bl8, G[tile], 0, 0, 0);
            }
        }
        int row0 = m0 + wv * 16 + quad * 4;          // rows r=0..3
        if (mat == 0 || mat == 3) {
            float* om = (mat == 0) ? q : skipo;
#pragma unroll
            for (int tile = 0; tile < 2; tile++)
#pragma unroll
                for (int r = 0; r < 4; r++)
                    om[(row0 + r) * HD + nsl * 32 + tile * 16 + nl] = G[tile][r];
        } else if (mat == 1) {
            // K planes, layout [row=b*128+s][256]
#pragma unroll
            for (int tile = 0; tile < 2; tile++) {
                int col = nsl * 32 + tile * 16 + nl;
#pragma unroll
                for (int r = 0; r < 4; r++) {
                    float gv = G[tile][r];
                    ushort_t hb = f2us_tr(gv);
                    khi[(row0 + r) * HD + col] = hb;
                    klo[(row0 + r) * HD + col] = f2us_tr(gv - us2f(hb));
                }
            }
        } else {
            // vT planes: vT[dg = b*256 + col][128 s], 4 consecutive s packed
            int bb = row0 >> 7;
            int s0 = row0 & 127;
#pragma unroll
            for (int tile = 0; tile < 2; tile++) {
                int col = nsl * 32 + tile * 16 + nl;
                int dg = bb * 256 + col;
                ushort4 h4, l4;
                float g0 = G[tile][0], g1 = G[tile][1], g2 = G[tile][2], g3 = G[tile][3];
                ushort_t h0 = f2us_tr(g0), h1 = f2us_tr(g1), h2 = f2us_tr(g2), h3 = f2us_tr(g3);
                h4.x = h0; h4.y = h1; h4.z = h2; h4.w = h3;
                l4.x = f2us_tr(g0 - us2f(h0));
                l4.y = f2us_tr(g1 - us2f(h1));
                l4.z = f2us_tr(g2 - us2f(h2));
                l4.w = f2us_tr(g3 - us2f(h3));
                *(ushort4*)&vThi[dg * NN + s0] = h4;
                *(ushort4*)&vTlo[dg * NN + s0] = l4;
            }
        }
    }
}

// ---------------- K6: attention via MFMA, 2 waves per (b,h,16-t tile) ------
// wave w: QK^T s-tiles {4w..4w+3}; softmax stats combined via LDS (max is
// exact under any order; den/beta reassociation ~1ulp); PV output-d half.
// agentp==nullptr: layer-1, full xout.  agentp!=nullptr: layer-2, agent row
// only, written directly to outp (fused gather).
__global__ void __launch_bounds__(128) k_attn_mfma(
    const float* qb, const ushort_t* khi, const ushort_t* klo,
    const ushort_t* vThi, const ushort_t* vTlo,
    const float* adjvT, const float* We, const float* skip, float* xout,
    const int* agentp, float* outp)
{
    __shared__ float aL[16][132];     // alpha C->A round-trip (8.4 KB)
    __shared__ float qeL[16];
    __shared__ float mxL[2][16];
    __shared__ float dnL[2][16];
    __shared__ float ebL[2][16];

    int blk = blockIdx.x;             // 1024 = 32b*4h*8tt
    int b  = blk >> 5;
    int h  = (blk >> 3) & 3;
    int tt = blk & 7;
    int t0 = tt * 16;
    int tid = threadIdx.x;
    int w   = tid >> 6;               // wave 0/1
    int lane = tid & 63;
    int nl = lane & 15;
    int quad = lane >> 4;

    // ---- Q A-frags (split hi/lo) + qe partial (q . we) ----
    short8 Qhi[2], Qlo[2];
    float qe = 0.f;
#pragma unroll
    for (int ks = 0; ks < 2; ks++) {
        const float* p = qb + (b * NN + t0 + nl) * HD + h * DHEAD + quad * 8 + 32 * ks;
        const float* wp = We + h * DHEAD + quad * 8 + 32 * ks;
        float4 a0 = *(const float4*)p;
        float4 a1 = *(const float4*)(p + 4);
        float4 w0 = *(const float4*)wp;
        float4 w1 = *(const float4*)(wp + 4);
        float hv[8] = {a0.x, a0.y, a0.z, a0.w, a1.x, a1.y, a1.z, a1.w};
        float wv8[8] = {w0.x, w0.y, w0.z, w0.w, w1.x, w1.y, w1.z, w1.w};
        uint_t hw[4], lw[4];
#pragma unroll
        for (int pr = 0; pr < 4; pr++) {
            float a = hv[2 * pr], c = hv[2 * pr + 1];
            qe = fmaf(a, wv8[2 * pr], qe);
            qe = fmaf(c, wv8[2 * pr + 1], qe);
            pair_split(a, c, hw[pr], lw[pr]);
        }
        Qhi[ks] = pack4(hw[0], hw[1], hw[2], hw[3]);
        Qlo[ks] = pack4(lw[0], lw[1], lw[2], lw[3]);
    }
    qe += __shfl_xor(qe, 16);
    qe += __shfl_xor(qe, 32);
    if (w == 0 && lane < 16) qeL[lane] = qe;   // qe for t = lane
    __syncthreads();
    float qe_r[4];
#pragma unroll
    for (int r = 0; r < 4; r++) qe_r[r] = qeL[quad * 4 + r];
    float we_d[2];
#pragma unroll
    for (int nt2 = 0; nt2 < 2; nt2++) we_d[nt2] = We[h * DHEAD + (w * 2 + nt2) * 16 + nl];

    // ---- QK^T: wave's 4 s-tiles (global st = w*4 + st') ----
    fx4 S[4];
#pragma unroll
    for (int st = 0; st < 4; st++) S[st] = (fx4){0.f, 0.f, 0.f, 0.f};
#pragma unroll
    for (int ks = 0; ks < 2; ks++) {
#pragma unroll
        for (int st = 0; st < 4; st++) {
            long off = (long)(b * NN + (w * 4 + st) * 16 + nl) * HD + h * DHEAD + quad * 8 + 32 * ks;
            short8 bh8 = *(const short8*)(khi + off);
            short8 bl8 = *(const short8*)(klo + off);
            S[st] = __builtin_amdgcn_mfma_f32_16x16x32_bf16(Qhi[ks], bh8, S[st], 0, 0, 0);
            S[st] = __builtin_amdgcn_mfma_f32_16x16x32_bf16(Qlo[ks], bh8, S[st], 0, 0, 0);
            S[st] = __builtin_amdgcn_mfma_f32_16x16x32_bf16(Qhi[ks], bl8, S[st], 0, 0, 0);
        }
    }

    // ---- masked logits (D-layout: row t = quad*4+r, col s = (w*4+st)*16+nl)
    float av[4][4];
#pragma unroll
    for (int st = 0; st < 4; st++)
#pragma unroll
        for (int r = 0; r < 4; r++)
            av[st][r] = adjvT[(b * NN + t0 + quad * 4 + r) * NN + (w * 4 + st) * 16 + nl];
#pragma unroll
    for (int st = 0; st < 4; st++)
#pragma unroll
        for (int r = 0; r < 4; r++) {
            float a = av[st][r];
            S[st][r] = (a != 0.f) ? (S[st][r] + a * qe_r[r]) * 0.125f : -1e30f;
        }

    // ---- partial row max, combine across waves ----
    float mxp[4];
#pragma unroll
    for (int r = 0; r < 4; r++) {
        float m = S[0][r];
#pragma unroll
        for (int st = 1; st < 4; st++) m = fmaxf(m, S[st][r]);
#pragma unroll
        for (int mm = 1; mm < 16; mm <<= 1) m = fmaxf(m, __shfl_xor(m, mm));
        mxp[r] = m;
    }
    if (nl == 0) {
#pragma unroll
        for (int r = 0; r < 4; r++) mxL[w][quad * 4 + r] = mxp[r];
    }
    __syncthreads();
    float mx[4];
#pragma unroll
    for (int r = 0; r < 4; r++)
        mx[r] = fmaxf(mxL[0][quad * 4 + r], mxL[1][quad * 4 + r]);

    // ---- e = exp(S - mx); partial den & e.av, combine ----
    float dnp[4] = {0.f, 0.f, 0.f, 0.f}, ebp[4] = {0.f, 0.f, 0.f, 0.f};
#pragma unroll
    for (int st = 0; st < 4; st++)
#pragma unroll
        for (int r = 0; r < 4; r++) {
            float e = (av[st][r] != 0.f) ? __expf(S[st][r] - mx[r]) : 0.f;
            S[st][r] = e;
            dnp[r] += e;
            ebp[r] = fmaf(e, av[st][r], ebp[r]);
        }
#pragma unroll
    for (int r = 0; r < 4; r++) {
#pragma unroll
        for (int mm = 1; mm < 16; mm <<= 1) {
            dnp[r] += __shfl_xor(dnp[r], mm);
            ebp[r] += __shfl_xor(ebp[r], mm);
        }
    }
    if (nl == 0) {
#pragma unroll
        for (int r = 0; r < 4; r++) {
            dnL[w][quad * 4 + r] = dnp[r];
            ebL[w][quad * 4 + r] = ebp[r];
        }
    }
    __syncthreads();
    float rden[4], beta[4];
#pragma unroll
    for (int r = 0; r < 4; r++) {
        int row = quad * 4 + r;
        float d = dnL[0][row] + dnL[1][row];
        rden[r] = 1.f / fmaxf(d, 1e-16f);
        beta[r] = (ebL[0][row] + ebL[1][row]) * rden[r];
    }

    // ---- alpha -> aL (wave writes its 64-column half) ----
#pragma unroll
    for (int st = 0; st < 4; st++)
#pragma unroll
        for (int r = 0; r < 4; r++)
            aL[quad * 4 + r][(w * 4 + st) * 16 + nl] = S[st][r] * rden[r];
    __syncthreads();

    // ---- A-frags over full s range ----
    short8 Ah[4];
#pragma unroll
    for (int ks = 0; ks < 4; ks++) {
        const float* p = &aL[nl][quad * 8 + 32 * ks];
        float4 a0 = *(const float4*)p;
        float4 a1 = *(const float4*)(p + 4);
        float hv[8] = {a0.x, a0.y, a0.z, a0.w, a1.x, a1.y, a1.z, a1.w};
        uint_t ww[4];
#pragma unroll
        for (int pr = 0; pr < 4; pr++) ww[pr] = pair_hi(hv[2 * pr], hv[2 * pr + 1]);
        Ah[ks] = pack4(ww[0], ww[1], ww[2], ww[3]);
    }

    // ---- PV: wave's output-d half (nt = w*2 + nt2) ----
    fx4 G[2];
#pragma unroll
    for (int nt2 = 0; nt2 < 2; nt2++) {
        fx4 g;
#pragma unroll
        for (int r = 0; r < 4; r++) g[r] = beta[r] * we_d[nt2];
        G[nt2] = g;
    }
#pragma unroll
    for (int ks = 0; ks < 4; ks++) {
#pragma unroll
        for (int nt2 = 0; nt2 < 2; nt2++) {
            long dg = (long)(b * 256 + h * DHEAD + (w * 2 + nt2) * 16 + nl);
            const short8 vh = *(const short8*)(vThi + dg * NN + quad * 8 + 32 * ks);
            const short8 vl = *(const short8*)(vTlo + dg * NN + quad * 8 + 32 * ks);
            G[nt2] = __builtin_amdgcn_mfma_f32_16x16x32_bf16(Ah[ks], vh, G[nt2], 0, 0, 0);
            G[nt2] = __builtin_amdgcn_mfma_f32_16x16x32_bf16(Ah[ks], vl, G[nt2], 0, 0, 0);
        }
    }

    // ---- epilogue ----
    if (agentp == nullptr) {
        // layer 1: full relu(out + skip) -> xout
#pragma unroll
        for (int nt2 = 0; nt2 < 2; nt2++)
#pragma unroll
            for (int r = 0; r < 4; r++) {
                int gi = (b * NN + t0 + quad * 4 + r) * HD + h * DHEAD + (w * 2 + nt2) * 16 + nl;
                xout[gi] = fmaxf(G[nt2][r] + skip[gi], 0.f);
            }
    } else {
        // layer 2 + fused gather: only the agent row reaches the output
        int ag = agentp[b];
#pragma unroll
        for (int nt2 = 0; nt2 < 2; nt2++)
#pragma unroll
            for (int r = 0; r < 4; r++) {
                int t = t0 + quad * 4 + r;
                if (t == ag) {
                    int d = h * DHEAD + (w * 2 + nt2) * 16 + nl;
                    int gi = (b * NN + t) * HD + d;
                    outp[b * HD + d] = fmaxf(G[nt2][r] + skip[gi], 0.f);
                }
            }
    }
}

// ---------------- launch ----------------
extern "C" void kernel_launch(void* const* d_in, const int* in_sizes, int n_in,
                              void* d_out, int out_size, void* d_ws, size_t ws_size,
                              hipStream_t stream) {
    float* out = (float*)d_out;
    (void)hipGetLastError();

    bool ok = (n_in == 31) && in_sizes[0] == BB * NN * FF && in_sizes[2] == BB * NN * NN
              && in_sizes[5] == (FF + EE + 1) * HH && in_sizes[13] == HH * HD
              && in_sizes[22] == HD * HD && out_size == BB * HD;
    if (!ok) { k_sent<<<32, 256, 0, stream>>>(out, -30000.f); return; }

    const size_t WS_NEED = (size_t)8912896 * 4;
    if (ws_size < WS_NEED) { k_sent<<<32, 256, 0, stream>>>(out, -20000.f); return; }

    const float* nf    = (const float*)d_in[0];
    const int*   et    = (const int*)d_in[1];
    const float* adj   = (const float*)d_in[2];
    const int*   agent = (const int*)d_in[3];
    const float* emb   = (const float*)d_in[4];
    const float* W1    = (const float*)d_in[5];
    const float* b1    = (const float*)d_in[6];
    const float* g1    = (const float*)d_in[7];
    const float* be1   = (const float*)d_in[8];
    const float* Wh    = (const float*)d_in[9];
    const float* bh    = (const float*)d_in[10];
    const float* gh    = (const float*)d_in[11];
    const float* beh   = (const float*)d_in[12];
    const float* Wq1   = (const float*)d_in[13];
    const float* bq1   = (const float*)d_in[14];
    const float* Wk1   = (const float*)d_in[15];
    const float* bk1   = (const float*)d_in[16];
    const float* Wv1   = (const float*)d_in[17];
    const float* bv1   = (const float*)d_in[18];
    const float* We1   = (const float*)d_in[19];
    const float* Ws1   = (const float*)d_in[20];
    const float* bs1   = (const float*)d_in[21];
    const float* Wq2   = (const float*)d_in[22];
    const float* bq2   = (const float*)d_in[23];
    const float* Wk2   = (const float*)d_in[24];
    const float* bk2   = (const float*)d_in[25];
    const float* Wv2   = (const float*)d_in[26];
    const float* bv2   = (const float*)d_in[27];
    const float* We2   = (const float*)d_in[28];
    const float* Ws2   = (const float*)d_in[29];
    const float* bs2   = (const float*)d_in[30];

    float* ws   = (float*)d_ws;
    float* slav = ws;                              // 524288 f region (sl_av)
    float* base = ws + 524288;                     // 524288 f
    float* x0   = base + BB * NN * HH;             // 524288 f
    float* q    = x0 + BB * NN * HH;               // 1048576 f
    float* kreg = q + BB * NN * HD;                // 1048576 f -> khi/klo
    float* vreg = kreg + BB * NN * HD;             // 1048576 f -> vThi/vTlo
    float* skip = vreg + BB * NN * HD;             // 1048576 f
    float* areg = skip + BB * NN * HD;             // 1048576 f -> planes + adjvT + sl_s
    float* x1   = areg + BB * NN * HD;
    float* x2   = x1 + BB * NN * HD;

    // econv prep planes in q region (q first written AFTER econv)
    ushort_t* BhiG = (ushort_t*)q;
    ushort_t* BloG = BhiG + HH * HH;
    float*    W1sW = q + 16384;
    float*    cbW  = q + 16512;
    int*      cnts = (int*)(q + 17024);            // 8192 ints, free q space

    // K / vT planes
    ushort_t* khi  = (ushort_t*)kreg;              // 1048576 ush
    ushort_t* klo  = khi + BB * NN * HD;           // 1048576 ush
    ushort_t* vThi = (ushort_t*)vreg;
    ushort_t* vTlo = vThi + BB * NN * HD;

    // qkvs weight planes + adjvT + sl_s in areg (4 MB):
    // planes 1.5 MB + adjvT 2 MB + sl_s 0.5 MB = 4 MB exactly
    ushort_t* WhA = (ushort_t*)areg;               // 4*256*128 ush
    ushort_t* WlA = WhA + 4 * 256 * HH;
    ushort_t* WhB = WlA + 4 * 256 * HH;            // 4*256*256 ush
    ushort_t* WlB = WhB + 4 * 256 * HD;
    float* adjvT  = areg + 393216;                 // 524288 f, past planes
    uchar_t* sl_s = (uchar_t*)(areg + 917504);     // 524288 uchars, tail

    int fail = 0;
    hipError_t e;
#define CHK(stage) do { e = hipGetLastError(); if (e != hipSuccess && fail == 0) fail = (stage); } while (0)

    k_prep_all<<<2080, 256, 0, stream>>>(
        adj, adjvT, sl_s, slav, cnts,
        nf, et, emb, W1, b1, base, x0,
        Wh, g1, be1, bh, BhiG, BloG, W1sW, cbW,
        Wq1, Wk1, Wv1, Ws1, WhA, WlA,
        Wq2, Wk2, Wv2, Ws2, WhB, WlB);                                               CHK(1);

    k_econv_mfma<<<512, 256, 0, stream>>>(sl_s, slav, cnts, base, W1,
                                          BhiG, BloG, W1sW, cbW, gh, beh, x0);       CHK(2);

    k_qkvs_mfma<HH><<<512, 256, 0, stream>>>(x0, WhA, WlA, bq1, bk1, bv1, bs1,
                                             q, skip, khi, klo, vThi, vTlo);         CHK(3);
    k_attn_mfma<<<1024, 128, 0, stream>>>(q, khi, klo, vThi, vTlo, adjvT, We1,
                                          skip, x1, nullptr, nullptr);               CHK(4);

    k_qkvs_mfma<HD><<<512, 256, 0, stream>>>(x1, WhB, WlB, bq2, bk2, bv2, bs2,
                                             q, skip, khi, klo, vThi, vTlo);         CHK(5);
    k_attn_mfma<<<1024, 128, 0, stream>>>(q, khi, klo, vThi, vTlo, adjvT, We2,
                                          skip, x2, agent, out);                     CHK(6);
#undef CHK

    if (fail != 0)
        k_sent<<<32, 256, 0, stream>>>(out, -(1000.f + 500.f * (float)fail));
}

// Round 8
// 247.014 us; speedup vs baseline: 2.2930x; 1.0157x over previous
//
#include <hip/hip_runtime.h>
#include <hip/hip_bf16.h>

typedef __hip_bfloat16 bf16;
typedef unsigned short ushort_t;
typedef unsigned char uchar_t;
typedef unsigned int uint_t;
typedef __attribute__((ext_vector_type(8))) short short8;
typedef __attribute__((ext_vector_type(4))) float fx4;
typedef __attribute__((ext_vector_type(4))) unsigned int uintx4;

#define BB 32
#define NN 128
#define FF 9
#define EE 8
#define HH 128
#define HD 256
#define NHEAD 4
#define DHEAD 64

__device__ __forceinline__ float us2f(ushort_t u) {
    return __uint_as_float(((unsigned int)u) << 16);
}
// truncation split: hi = trunc16(v), lo = v - hi (lo exact in f32)
__device__ __forceinline__ ushort_t f2us_tr(float f) {
    return (ushort_t)(__float_as_uint(f) >> 16);
}
__device__ __forceinline__ short8 pack4(uint_t w0, uint_t w1, uint_t w2, uint_t w3) {
    uintx4 u = (uintx4){w0, w1, w2, w3};
    return __builtin_bit_cast(short8, u);
}
// pair split: a -> low short of word, c -> high short (bit-identical to
// per-element f2us_tr path: keep = bits & 0xffff0000 == us2f(f2us_tr(x)))
__device__ __forceinline__ void pair_split(float a, float c, uint_t& hw, uint_t& lw) {
    uint_t ua = __float_as_uint(a), uc = __float_as_uint(c);
    uint_t ka = ua & 0xffff0000u, kc = uc & 0xffff0000u;
    float la = a - __uint_as_float(ka);
    float lc = c - __uint_as_float(kc);
    hw = (ua >> 16) | kc;
    lw = (__float_as_uint(la) >> 16) | (__float_as_uint(lc) & 0xffff0000u);
}
__device__ __forceinline__ uint_t pair_hi(float a, float c) {
    return (__float_as_uint(a) >> 16) | (__float_as_uint(c) & 0xffff0000u);
}

__global__ void TransformerConvNet_85315230367963_kernel() {}

__global__ void k_sent(float* out, float val) {
    out[blockIdx.x * 256 + threadIdx.x] = val;
}

// ---------------- K_prep_all: all independent prep work, ONE launch -------
// blocks [0,256):      adjvT (masked transpose) + ballot-compacted s-lists
// blocks [256,1280):   base = src @ W1[:17] + b1          (1024 blocks)
// blocks [1280,1536):  zero x0                            (256 blocks)
// blocks [1536,1568):  Wh' split hi/lo + W1s/cb           (32 blocks, 4 n/blk)
// blocks [1568,1824):  prepw layer1 (IN=128)              (256 blocks, 4 keys/blk)
// blocks [1824,2080):  prepw layer2 (IN=256)              (256 blocks, 4 keys/blk)
__global__ void __launch_bounds__(256) k_prep_all(
    const float* adj, float* adjvT, uchar_t* sl_s, float* sl_av, int* cnts,
    const float* nf, const int* et, const float* emb, const float* W1,
    const float* b1, float* base, float* x0,
    const float* Wh, const float* g1, const float* be1, const float* bh,
    ushort_t* BhiG, ushort_t* BloG, float* W1s, float* cbv,
    const float* Wq1, const float* Wk1, const float* Wv1, const float* Ws1,
    ushort_t* WhA, ushort_t* WlA,
    const float* Wq2, const float* Wk2, const float* Wv2, const float* Ws2,
    ushort_t* WhB, ushort_t* WlB)
{
    int blk = blockIdx.x;
    int tid = threadIdx.x;

    if (blk < 256) {
        // ---- adjvT + slist (ballot compaction, ascending-s == serial order)
        int b = blk >> 3, sl = blk & 7;
        int wv = tid >> 6, lane = tid & 63;
#pragma unroll
        for (int j = 0; j < 8; j++) {
            int u = wv * 8 + j;               // 32 (t,sh) units per block
            int t = sl * 16 + (u >> 1);
            int sh = u & 1;
            int s = sh * 64 + lane;
            float a = adj[(b * NN + s) * NN + t];
            float av = (a > 0.f && a < 1.0f) ? a : 0.f;
            adjvT[(b * NN + t) * NN + s] = av;
            unsigned long long mask = __ballot(av != 0.f);
            int key = (b * NN + t) * 2 + sh;
            if (av != 0.f) {
                int pos = __popcll(mask & ((1ull << lane) - 1ull));
                sl_s[key * 64 + pos] = (uchar_t)s;
                sl_av[key * 64 + pos] = av;
            }
            if (lane == 0) {
                cnts[key] = (int)__popcll(mask);
                if (mask == 0ull) { sl_s[key * 64] = 0; sl_av[key * 64] = 0.f; }
            }
        }
    } else if (blk < 1280) {
        // ---- base rows (4 per block)
        int bblk = blk - 256;
        int c = tid & 127;
#pragma unroll
        for (int rr = 0; rr < 2; rr++) {
            int bs = bblk * 4 + rr * 2 + (tid >> 7);
            int ty = et[bs];
            float acc = b1[c];
            for (int f = 0; f < FF; f++)
                acc += nf[bs * FF + f] * W1[f * HH + c];
            for (int e2 = 0; e2 < EE; e2++)
                acc += emb[ty * EE + e2] * W1[(FF + e2) * HH + c];
            base[bs * HH + c] = acc;
        }
    } else if (blk < 1536) {
        // ---- zero x0 (524288 floats = 131072 float4)
        int zblk = blk - 1280;
        float4* p = (float4*)x0 + zblk * 512 + tid * 2;
        p[0] = (float4){0.f, 0.f, 0.f, 0.f};
        p[1] = (float4){0.f, 0.f, 0.f, 0.f};
    } else if (blk < 1568) {
        // ---- Wh' = g1*Wh split bf16 hi/lo, swizzled; W1s/cb (wave per n)
        int n = (blk - 1536) * 4 + (tid >> 6);
        int t = tid & 63;
        int sw = 8 * (n & 15);
        float s1 = 0.f, s2 = 0.f;
#pragma unroll
        for (int kk = 0; kk < 2; kk++) {
            int k = t + kk * 64;
            float w = Wh[k * HH + n];
            float wp = g1[k] * w;
            ushort_t hb = f2us_tr(wp);
            float lo = wp - us2f(hb);
            BhiG[n * HH + (k ^ sw)] = hb;
            BloG[n * HH + (k ^ sw)] = f2us_tr(lo);
            s1 += wp;
            s2 += be1[k] * w;
        }
        for (int m = 1; m < 64; m <<= 1) {
            s1 += __shfl_xor(s1, m);
            s2 += __shfl_xor(s2, m);
        }
        if (t == 0) { W1s[n] = s1; cbv[n] = s2 + bh[n]; }
    } else if (blk < 1824) {
        // ---- prepw layer 1 (IN = HH), key = (mat,n), wave per key
        int key = (blk - 1568) * 4 + (tid >> 6);
        int lane = tid & 63;
        int mat = key >> 8, n = key & 255;
        const float* W = (mat == 0) ? Wq1 : (mat == 1) ? Wk1 : (mat == 2) ? Wv1 : Ws1;
        ushort_t* hi = WhA + mat * 256 * HH;
        ushort_t* lo = WlA + mat * 256 * HH;
        int sw = 8 * (n & 15);
        for (int k = lane; k < HH; k += 64) {
            float w = W[k * HD + n];
            ushort_t hb = f2us_tr(w);
            float l = w - us2f(hb);
            hi[n * HH + (k ^ sw)] = hb;
            lo[n * HH + (k ^ sw)] = f2us_tr(l);
        }
    } else {
        // ---- prepw layer 2 (IN = HD)
        int key = (blk - 1824) * 4 + (tid >> 6);
        int lane = tid & 63;
        int mat = key >> 8, n = key & 255;
        const float* W = (mat == 0) ? Wq2 : (mat == 1) ? Wk2 : (mat == 2) ? Wv2 : Ws2;
        ushort_t* hi = WhB + mat * 256 * HD;
        ushort_t* lo = WlB + mat * 256 * HD;
        int sw = 8 * (n & 15);
        for (int k = lane; k < HD; k += 64) {
            float w = W[k * HD + n];
            ushort_t hb = f2us_tr(w);
            float l = w - us2f(hb);
            hi[n * HD + (k ^ sw)] = hb;
            lo[n * HD + (k ^ sw)] = f2us_tr(l);
        }
    }
}

// ---------------- K3: embed conv, MFMA, compacted s-lists ------------------
// D[n][t] = Wh'^T (LDS, A-op) x raw relu(h1)^T (regs, B-op).  B col = t = nl.
// Per column t, only UNMASKED s are processed (p(mask)=0.5): lane walks its
// own compacted list; wave wv takes contiguous quarter (bit-identical order;
// skipped entries contributed exactly 0 via fmaf(0,h2,acc)).
// LN1 applied POST-mfma: pre2 = r1*Graw + nm*W1s[n] + cb[n]  (nm = -m1*r1).
__global__ void __launch_bounds__(256) k_econv_mfma(
    const uchar_t* sl_s, const float* sl_av, const int* cnts,
    const float* base, const float* W1,
    const ushort_t* BhiG, const ushort_t* BloG,
    const float* W1sg, const float* cbv,
    const float* ghp, const float* behp, float* x0)
{
    __shared__ __align__(16) ushort_t PhiPlo[2 * HH * HH];   // 64 KB
    ushort_t* Phi = PhiPlo;
    ushort_t* Plo = PhiPlo + HH * HH;

    int blk = blockIdx.x;
    int b  = blk >> 4;
    int tt = (blk >> 1) & 7;
    int sh = blk & 1;
    int t0 = tt * 16;
    int tid = threadIdx.x;
    int wv  = tid >> 6;
    int lane = tid & 63;
    int nl = lane & 15;
    int quad = lane >> 4;

    {
        const uint4* srcH = (const uint4*)BhiG;
        const uint4* srcL = (const uint4*)BloG;
        uint4* dstH = (uint4*)Phi;
        uint4* dstL = (uint4*)Plo;
        for (int i = tid; i < HH * HH / 8; i += 256) {
            dstH[i] = srcH[i];
            dstL[i] = srcL[i];
        }
    }

    float w17v[4][8];
#pragma unroll
    for (int st = 0; st < 4; st++) {
        const float* p = W1 + 17 * HH + quad * 8 + 32 * st;
        float4 a = *(const float4*)p;
        float4 bq = *(const float4*)(p + 4);
        w17v[st][0] = a.x;  w17v[st][1] = a.y;  w17v[st][2] = a.z;  w17v[st][3] = a.w;
        w17v[st][4] = bq.x; w17v[st][5] = bq.y; w17v[st][6] = bq.z; w17v[st][7] = bq.w;
    }

    // per-lane (col t) compacted list
    int key = ((b * NN) + t0 + nl) * 2 + sh;
    int cnt = cnts[key];
    int q = (cnt + 3) >> 2;              // per-wave chunk
    int mq = q;
#pragma unroll
    for (int m = 1; m < 16; m <<= 1) mq = max(mq, __shfl_xor(mq, m));
    const uchar_t* lst_s = sl_s + key * 64;
    const float*   lst_a = sl_av + key * 64;
    int i0 = wv * q;

    fx4 acc1[8];                 // sum_s mask*r2*h2   (per n, per t=nl)
#pragma unroll
    for (int tile = 0; tile < 8; tile++) acc1[tile] = (fx4){0.f, 0.f, 0.f, 0.f};
    float c0 = 0.f;              // sum_s mask
    float c1 = 0.f;              // sum_s mask*r2*mean2

    __syncthreads();

    for (int i = 0; i < mq; i++) {
        int idx = i0 + i;
        bool val = (i < q) && (idx < cnt);
        int ridx = (idx < cnt) ? idx : (cnt > 0 ? cnt - 1 : 0);
        int s = lst_s[ridx];
        float avv = val ? lst_a[ridx] : 0.f;
        const float* brow = base + (b * NN + s) * HH;

        // one pass: vv = relu(base + avv*w17); stats + pair-packed hi/lo
        short8 Hhi[4], Hlo[4];
        float sm = 0.f, s2 = 0.f;
#pragma unroll
        for (int st = 0; st < 4; st++) {
            const float* p = brow + quad * 8 + 32 * st;
            float4 b0 = *(const float4*)p;
            float4 b1q = *(const float4*)(p + 4);
            float h[8] = {b0.x, b0.y, b0.z, b0.w, b1q.x, b1q.y, b1q.z, b1q.w};
            uint_t hw[4], lw[4];
#pragma unroll
            for (int pr = 0; pr < 4; pr++) {
                float a = fmaxf(fmaf(avv, w17v[st][2 * pr], h[2 * pr]), 0.f);
                float c = fmaxf(fmaf(avv, w17v[st][2 * pr + 1], h[2 * pr + 1]), 0.f);
                sm += a; sm += c;
                s2 = fmaf(a, a, s2);
                s2 = fmaf(c, c, s2);
                pair_split(a, c, hw[pr], lw[pr]);
            }
            Hhi[st] = pack4(hw[0], hw[1], hw[2], hw[3]);
            Hlo[st] = pack4(lw[0], lw[1], lw[2], lw[3]);
        }
        sm += __shfl_xor(sm, 16); sm += __shfl_xor(sm, 32);
        s2 += __shfl_xor(s2, 16); s2 += __shfl_xor(s2, 32);
        float m1 = sm * (1.f / 128.f);
        float r1 = rsqrtf(s2 * (1.f / 128.f) - m1 * m1 + 1e-5f);
        float nm = -m1 * r1;

        // Graw = Wh'^T @ vv
        fx4 G[8];
#pragma unroll
        for (int tile = 0; tile < 8; tile++) G[tile] = (fx4){0.f, 0.f, 0.f, 0.f};
#pragma unroll
        for (int st = 0; st < 4; st++) {
            int koff = quad * 8 + 32 * st;
#pragma unroll
            for (int tile = 0; tile < 8; tile++) {
                int off = (tile * 16 + nl) * HH + (koff ^ (nl * 8));
                short8 ph = *(const short8*)(&Phi[off]);
                short8 pl = *(const short8*)(&Plo[off]);
                G[tile] = __builtin_amdgcn_mfma_f32_16x16x32_bf16(ph, Hhi[st], G[tile], 0, 0, 0);
                G[tile] = __builtin_amdgcn_mfma_f32_16x16x32_bf16(pl, Hhi[st], G[tile], 0, 0, 0);
                G[tile] = __builtin_amdgcn_mfma_f32_16x16x32_bf16(ph, Hlo[st], G[tile], 0, 0, 0);
            }
        }

        // LN1 correction + relu; LN2 stats (in-lane over 32 n + 2 shuffles)
        float sm2 = 0.f, ss2 = 0.f;
#pragma unroll
        for (int tile = 0; tile < 8; tile++) {
            float4 w4 = *(const float4*)(W1sg + tile * 16 + quad * 4);
            float4 c4 = *(const float4*)(cbv + tile * 16 + quad * 4);
            float wa[4] = {w4.x, w4.y, w4.z, w4.w};
            float ca[4] = {c4.x, c4.y, c4.z, c4.w};
#pragma unroll
            for (int r = 0; r < 4; r++) {
                float pre = fmaf(r1, G[tile][r], fmaf(nm, wa[r], ca[r]));
                float h2 = fmaxf(pre, 0.f);
                G[tile][r] = h2;
                sm2 += h2;
                ss2 = fmaf(h2, h2, ss2);
            }
        }
        sm2 += __shfl_xor(sm2, 16); sm2 += __shfl_xor(sm2, 32);
        ss2 += __shfl_xor(ss2, 16); ss2 += __shfl_xor(ss2, 32);
        float mean2 = sm2 * (1.f / 128.f);
        float r2 = rsqrtf(ss2 * (1.f / 128.f) - mean2 * mean2 + 1e-5f);
        float msk = val ? 1.f : 0.f;
        float mr2 = msk * r2;

#pragma unroll
        for (int tile = 0; tile < 8; tile++)
#pragma unroll
            for (int r = 0; r < 4; r++)
                acc1[tile][r] = fmaf(mr2, G[tile][r], acc1[tile][r]);
        c0 += msk;
        c1 = fmaf(mr2, mean2, c1);
    }

    // ---- epilogue: xv = gh*(acc1 - c1) + beh*c0 ;  cross-wave LDS reduce,
    //      then coalesced atomics (consecutive lanes -> consecutive n) ----
    __syncthreads();                       // Phi/Plo dead; reuse as f32 slab
    float* slab = (float*)PhiPlo;          // [4 waves][16 t][stride 132]
#pragma unroll
    for (int tile = 0; tile < 8; tile++) {
        float4 g4 = *(const float4*)(ghp + tile * 16 + quad * 4);
        float4 be4 = *(const float4*)(behp + tile * 16 + quad * 4);
        float gv[4] = {g4.x, g4.y, g4.z, g4.w};
        float bv[4] = {be4.x, be4.y, be4.z, be4.w};
#pragma unroll
        for (int r = 0; r < 4; r++) {
            float xv = fmaf(gv[r], acc1[tile][r] - c1, bv[r] * c0);
            slab[(wv * 16 + nl) * 132 + tile * 16 + quad * 4 + r] = xv;
        }
    }
    __syncthreads();
    for (int e = tid; e < 16 * HH; e += 256) {
        int t = e >> 7, n = e & 127;
        float vsum = slab[t * 132 + n] + slab[(16 + t) * 132 + n]
                   + slab[(32 + t) * 132 + n] + slab[(48 + t) * 132 + n];
        atomicAdd(&x0[(b * NN + t0 + t) * HH + n], vsum);
    }
}

// ---------------- K5: qkvs via MFMA, 512 blocks (32-col n slices) ---------
// agentp != nullptr (layer 2): q (mat 0) and skip (mat 3) are consumed only
// at row t = agent[b]; waves whose 16-row tile lacks the agent row skip
// those mats entirely (wave-uniform).  K/V (mats 1,2) always full.
template <int IN>
__global__ void __launch_bounds__(256) k_qkvs_mfma(
    const float* x, const ushort_t* Whi, const ushort_t* Wlo,
    const float* b0, const float* b1, const float* b2, const float* b3,
    float* q, float* skipo,
    ushort_t* khi, ushort_t* klo, ushort_t* vThi, ushort_t* vTlo,
    const int* agentp)
{
    const int ST = IN / 32;
    int blk = blockIdx.x;             // 512 = 64 m-blocks * 8 col slices
    int m0 = (blk >> 3) * 64;
    int nsl = blk & 7;                // 32-col slice
    int tid = threadIdx.x;
    int wv = tid >> 6;
    int lane = tid & 63;
    int nl = lane & 15;
    int quad = lane >> 4;
    int row = m0 + wv * 16 + nl;

    short8 Ahi[ST], Alo[ST];
    const float* xrow = x + (long)row * IN;
#pragma unroll
    for (int st = 0; st < ST; st++) {
        const float* p = xrow + quad * 8 + 32 * st;
        float4 a4 = *(const float4*)p;
        float4 b4 = *(const float4*)(p + 4);
        float h[8] = {a4.x, a4.y, a4.z, a4.w, b4.x, b4.y, b4.z, b4.w};
        uint_t hw[4], lw[4];
#pragma unroll
        for (int pr = 0; pr < 4; pr++)
            pair_split(h[2 * pr], h[2 * pr + 1], hw[pr], lw[pr]);
        Ahi[st] = pack4(hw[0], hw[1], hw[2], hw[3]);
        Alo[st] = pack4(lw[0], lw[1], lw[2], lw[3]);
    }

    const float* bs_[4] = {b0, b1, b2, b3};
    int rw0 = m0 + wv * 16;                  // wave's 16-row tile start
    bool agset = (agentp != nullptr);
    int agrow = agset ? agentp[rw0 >> 7] : -1;
    bool havea = agset && ((agrow >> 4) == ((rw0 & 127) >> 4));

#pragma unroll
    for (int mat = 0; mat < 4; mat++) {
        if ((mat == 0 || mat == 3) && agset && !havea) continue;
        const ushort_t* Bh = Whi + (mat * 256 + nsl * 32) * IN;
        const ushort_t* Bl = Wlo + (mat * 256 + nsl * 32) * IN;
        fx4 G[2];
#pragma unroll
        for (int tile = 0; tile < 2; tile++) {
            float bc = bs_[mat][nsl * 32 + tile * 16 + nl];
            G[tile] = (fx4){bc, bc, bc, bc};
        }
#pragma unroll
        for (int st = 0; st < ST; st++) {
            int koff = quad * 8 + 32 * st;
#pragma unroll
            for (int tile = 0; tile < 2; tile++) {
                int off = (tile * 16 + nl) * IN + (koff ^ (nl * 8));
                short8 bh8 = *(const short8*)(Bh + off);
                short8 bl8 = *(const short8*)(Bl + off);
                G[tile] = __builtin_amdgcn_mfma_f32_16x16x32_bf16(Ahi[st], bh8, G[tile], 0, 0, 0);
                G[tile] = __builtin_amdgcn_mfma_f32_16x16x32_bf16(Alo[st], bh8, G[tile], 0, 0, 0);
                G[tile] = __builtin_amdgcn_mfma_f32_16x16x32_bf16(Ahi[st], bl8, G[tile], 0, 0, 0);
            }
        }
        int row0 = m0 + wv * 16 + quad * 4;          // rows r=0..3
        if (mat == 0 || mat == 3) {
            float* om = (mat == 0) ? q : skipo;
#pragma unroll
            for (int tile = 0; tile < 2; tile++)
#pragma unroll
                for (int r = 0; r < 4; r++)
                    om[(row0 + r) * HD + nsl * 32 + tile * 16 + nl] = G[tile][r];
        } else if (mat == 1) {
            // K planes, layout [row=b*128+s][256]
#pragma unroll
            for (int tile = 0; tile < 2; tile++) {
                int col = nsl * 32 + tile * 16 + nl;
#pragma unroll
                for (int r = 0; r < 4; r++) {
                    float gv = G[tile][r];
                    ushort_t hb = f2us_tr(gv);
                    khi[(row0 + r) * HD + col] = hb;
                    klo[(row0 + r) * HD + col] = f2us_tr(gv - us2f(hb));
                }
            }
        } else {
            // vT planes: vT[dg = b*256 + col][128 s], 4 consecutive s packed
            int bb = row0 >> 7;
            int s0 = row0 & 127;
#pragma unroll
            for (int tile = 0; tile < 2; tile++) {
                int col = nsl * 32 + tile * 16 + nl;
                int dg = bb * 256 + col;
                ushort4 h4, l4;
                float g0 = G[tile][0], g1 = G[tile][1], g2 = G[tile][2], g3 = G[tile][3];
                ushort_t h0 = f2us_tr(g0), h1 = f2us_tr(g1), h2 = f2us_tr(g2), h3 = f2us_tr(g3);
                h4.x = h0; h4.y = h1; h4.z = h2; h4.w = h3;
                l4.x = f2us_tr(g0 - us2f(h0));
                l4.y = f2us_tr(g1 - us2f(h1));
                l4.z = f2us_tr(g2 - us2f(h2));
                l4.w = f2us_tr(g3 - us2f(h3));
                *(ushort4*)&vThi[dg * NN + s0] = h4;
                *(ushort4*)&vTlo[dg * NN + s0] = l4;
            }
        }
    }
}

// ---------------- K6: attention via MFMA, 2 waves per (b,h,16-t tile) ------
// wave w: QK^T s-tiles {4w..4w+3}; softmax stats combined via LDS (max is
// exact under any order; den/beta reassociation ~1ulp); PV output-d half.
// agentp==nullptr: layer-1, grid 1024 (b,h,tt), full xout.
// agentp!=nullptr: layer-2, grid 128 (b,h), tt = agent[b]>>4; agent row only,
// written directly to outp (fused gather) -- same math, bit-identical row.
__global__ void __launch_bounds__(128) k_attn_mfma(
    const float* qb, const ushort_t* khi, const ushort_t* klo,
    const ushort_t* vThi, const ushort_t* vTlo,
    const float* adjvT, const float* We, const float* skip, float* xout,
    const int* agentp, float* outp)
{
    __shared__ float aL[16][132];     // alpha C->A round-trip (8.4 KB)
    __shared__ float qeL[16];
    __shared__ float mxL[2][16];
    __shared__ float dnL[2][16];
    __shared__ float ebL[2][16];

    int blk = blockIdx.x;
    int b, h, tt;
    if (agentp == nullptr) {          // 1024 = 32b*4h*8tt
        b = blk >> 5; h = (blk >> 3) & 3; tt = blk & 7;
    } else {                          // 128 = 32b*4h
        b = blk >> 2; h = blk & 3; tt = agentp[b] >> 4;
    }
    int t0 = tt * 16;
    int tid = threadIdx.x;
    int w   = tid >> 6;               // wave 0/1
    int lane = tid & 63;
    int nl = lane & 15;
    int quad = lane >> 4;

    // ---- Q A-frags (split hi/lo) + qe partial (q . we) ----
    short8 Qhi[2], Qlo[2];
    float qe = 0.f;
#pragma unroll
    for (int ks = 0; ks < 2; ks++) {
        const float* p = qb + (b * NN + t0 + nl) * HD + h * DHEAD + quad * 8 + 32 * ks;
        const float* wp = We + h * DHEAD + quad * 8 + 32 * ks;
        float4 a0 = *(const float4*)p;
        float4 a1 = *(const float4*)(p + 4);
        float4 w0 = *(const float4*)wp;
        float4 w1 = *(const float4*)(wp + 4);
        float hv[8] = {a0.x, a0.y, a0.z, a0.w, a1.x, a1.y, a1.z, a1.w};
        float wv8[8] = {w0.x, w0.y, w0.z, w0.w, w1.x, w1.y, w1.z, w1.w};
        uint_t hw[4], lw[4];
#pragma unroll
        for (int pr = 0; pr < 4; pr++) {
            float a = hv[2 * pr], c = hv[2 * pr + 1];
            qe = fmaf(a, wv8[2 * pr], qe);
            qe = fmaf(c, wv8[2 * pr + 1], qe);
            pair_split(a, c, hw[pr], lw[pr]);
        }
        Qhi[ks] = pack4(hw[0], hw[1], hw[2], hw[3]);
        Qlo[ks] = pack4(lw[0], lw[1], lw[2], lw[3]);
    }
    qe += __shfl_xor(qe, 16);
    qe += __shfl_xor(qe, 32);
    if (w == 0 && lane < 16) qeL[lane] = qe;   // qe for t = lane
    __syncthreads();
    float qe_r[4];
#pragma unroll
    for (int r = 0; r < 4; r++) qe_r[r] = qeL[quad * 4 + r];
    float we_d[2];
#pragma unroll
    for (int nt2 = 0; nt2 < 2; nt2++) we_d[nt2] = We[h * DHEAD + (w * 2 + nt2) * 16 + nl];

    // ---- QK^T: wave's 4 s-tiles (global st = w*4 + st') ----
    fx4 S[4];
#pragma unroll
    for (int st = 0; st < 4; st++) S[st] = (fx4){0.f, 0.f, 0.f, 0.f};
#pragma unroll
    for (int ks = 0; ks < 2; ks++) {
#pragma unroll
        for (int st = 0; st < 4; st++) {
            long off = (long)(b * NN + (w * 4 + st) * 16 + nl) * HD + h * DHEAD + quad * 8 + 32 * ks;
            short8 bh8 = *(const short8*)(khi + off);
            short8 bl8 = *(const short8*)(klo + off);
            S[st] = __builtin_amdgcn_mfma_f32_16x16x32_bf16(Qhi[ks], bh8, S[st], 0, 0, 0);
            S[st] = __builtin_amdgcn_mfma_f32_16x16x32_bf16(Qlo[ks], bh8, S[st], 0, 0, 0);
            S[st] = __builtin_amdgcn_mfma_f32_16x16x32_bf16(Qhi[ks], bl8, S[st], 0, 0, 0);
        }
    }

    // ---- masked logits (D-layout: row t = quad*4+r, col s = (w*4+st)*16+nl)
    float av[4][4];
#pragma unroll
    for (int st = 0; st < 4; st++)
#pragma unroll
        for (int r = 0; r < 4; r++)
            av[st][r] = adjvT[(b * NN + t0 + quad * 4 + r) * NN + (w * 4 + st) * 16 + nl];
#pragma unroll
    for (int st = 0; st < 4; st++)
#pragma unroll
        for (int r = 0; r < 4; r++) {
            float a = av[st][r];
            S[st][r] = (a != 0.f) ? (S[st][r] + a * qe_r[r]) * 0.125f : -1e30f;
        }

    // ---- partial row max, combine across waves ----
    float mxp[4];
#pragma unroll
    for (int r = 0; r < 4; r++) {
        float m = S[0][r];
#pragma unroll
        for (int st = 1; st < 4; st++) m = fmaxf(m, S[st][r]);
#pragma unroll
        for (int mm = 1; mm < 16; mm <<= 1) m = fmaxf(m, __shfl_xor(m, mm));
        mxp[r] = m;
    }
    if (nl == 0) {
#pragma unroll
        for (int r = 0; r < 4; r++) mxL[w][quad * 4 + r] = mxp[r];
    }
    __syncthreads();
    float mx[4];
#pragma unroll
    for (int r = 0; r < 4; r++)
        mx[r] = fmaxf(mxL[0][quad * 4 + r], mxL[1][quad * 4 + r]);

    // ---- e = exp(S - mx); partial den & e.av, combine ----
    float dnp[4] = {0.f, 0.f, 0.f, 0.f}, ebp[4] = {0.f, 0.f, 0.f, 0.f};
#pragma unroll
    for (int st = 0; st < 4; st++)
#pragma unroll
        for (int r = 0; r < 4; r++) {
            float e = (av[st][r] != 0.f) ? __expf(S[st][r] - mx[r]) : 0.f;
            S[st][r] = e;
            dnp[r] += e;
            ebp[r] = fmaf(e, av[st][r], ebp[r]);
        }
#pragma unroll
    for (int r = 0; r < 4; r++) {
#pragma unroll
        for (int mm = 1; mm < 16; mm <<= 1) {
            dnp[r] += __shfl_xor(dnp[r], mm);
            ebp[r] += __shfl_xor(ebp[r], mm);
        }
    }
    if (nl == 0) {
#pragma unroll
        for (int r = 0; r < 4; r++) {
            dnL[w][quad * 4 + r] = dnp[r];
            ebL[w][quad * 4 + r] = ebp[r];
        }
    }
    __syncthreads();
    float rden[4], beta[4];
#pragma unroll
    for (int r = 0; r < 4; r++) {
        int row = quad * 4 + r;
        float d = dnL[0][row] + dnL[1][row];
        rden[r] = 1.f / fmaxf(d, 1e-16f);
        beta[r] = (ebL[0][row] + ebL[1][row]) * rden[r];
    }

    // ---- alpha -> aL (wave writes its 64-column half) ----
#pragma unroll
    for (int st = 0; st < 4; st++)
#pragma unroll
        for (int r = 0; r < 4; r++)
            aL[quad * 4 + r][(w * 4 + st) * 16 + nl] = S[st][r] * rden[r];
    __syncthreads();

    // ---- A-frags over full s range ----
    short8 Ah[4];
#pragma unroll
    for (int ks = 0; ks < 4; ks++) {
        const float* p = &aL[nl][quad * 8 + 32 * ks];
        float4 a0 = *(const float4*)p;
        float4 a1 = *(const float4*)(p + 4);
        float hv[8] = {a0.x, a0.y, a0.z, a0.w, a1.x, a1.y, a1.z, a1.w};
        uint_t ww[4];
#pragma unroll
        for (int pr = 0; pr < 4; pr++) ww[pr] = pair_hi(hv[2 * pr], hv[2 * pr + 1]);
        Ah[ks] = pack4(ww[0], ww[1], ww[2], ww[3]);
    }

    // ---- PV: wave's output-d half (nt = w*2 + nt2) ----
    fx4 G[2];
#pragma unroll
    for (int nt2 = 0; nt2 < 2; nt2++) {
        fx4 g;
#pragma unroll
        for (int r = 0; r < 4; r++) g[r] = beta[r] * we_d[nt2];
        G[nt2] = g;
    }
#pragma unroll
    for (int ks = 0; ks < 4; ks++) {
#pragma unroll
        for (int nt2 = 0; nt2 < 2; nt2++) {
            long dg = (long)(b * 256 + h * DHEAD + (w * 2 + nt2) * 16 + nl);
            const short8 vh = *(const short8*)(vThi + dg * NN + quad * 8 + 32 * ks);
            const short8 vl = *(const short8*)(vTlo + dg * NN + quad * 8 + 32 * ks);
            G[nt2] = __builtin_amdgcn_mfma_f32_16x16x32_bf16(Ah[ks], vh, G[nt2], 0, 0, 0);
            G[nt2] = __builtin_amdgcn_mfma_f32_16x16x32_bf16(Ah[ks], vl, G[nt2], 0, 0, 0);
        }
    }

    // ---- epilogue ----
    if (agentp == nullptr) {
        // layer 1: full relu(out + skip) -> xout
#pragma unroll
        for (int nt2 = 0; nt2 < 2; nt2++)
#pragma unroll
            for (int r = 0; r < 4; r++) {
                int gi = (b * NN + t0 + quad * 4 + r) * HD + h * DHEAD + (w * 2 + nt2) * 16 + nl;
                xout[gi] = fmaxf(G[nt2][r] + skip[gi], 0.f);
            }
    } else {
        // layer 2 + fused gather: only the agent row reaches the output
        int ag = agentp[b];
#pragma unroll
        for (int nt2 = 0; nt2 < 2; nt2++)
#pragma unroll
            for (int r = 0; r < 4; r++) {
                int t = t0 + quad * 4 + r;
                if (t == ag) {
                    int d = h * DHEAD + (w * 2 + nt2) * 16 + nl;
                    int gi = (b * NN + t) * HD + d;
                    outp[b * HD + d] = fmaxf(G[nt2][r] + skip[gi], 0.f);
                }
            }
    }
}

// ---------------- launch ----------------
extern "C" void kernel_launch(void* const* d_in, const int* in_sizes, int n_in,
                              void* d_out, int out_size, void* d_ws, size_t ws_size,
                              hipStream_t stream) {
    float* out = (float*)d_out;
    (void)hipGetLastError();

    bool ok = (n_in == 31) && in_sizes[0] == BB * NN * FF && in_sizes[2] == BB * NN * NN
              && in_sizes[5] == (FF + EE + 1) * HH && in_sizes[13] == HH * HD
              && in_sizes[22] == HD * HD && out_size == BB * HD;
    if (!ok) { k_sent<<<32, 256, 0, stream>>>(out, -30000.f); return; }

    const size_t WS_NEED = (size_t)8912896 * 4;
    if (ws_size < WS_NEED) { k_sent<<<32, 256, 0, stream>>>(out, -20000.f); return; }

    const float* nf    = (const float*)d_in[0];
    const int*   et    = (const int*)d_in[1];
    const float* adj   = (const float*)d_in[2];
    const int*   agent = (const int*)d_in[3];
    const float* emb   = (const float*)d_in[4];
    const float* W1    = (const float*)d_in[5];
    const float* b1    = (const float*)d_in[6];
    const float* g1    = (const float*)d_in[7];
    const float* be1   = (const float*)d_in[8];
    const float* Wh    = (const float*)d_in[9];
    const float* bh    = (const float*)d_in[10];
    const float* gh    = (const float*)d_in[11];
    const float* beh   = (const float*)d_in[12];
    const float* Wq1   = (const float*)d_in[13];
    const float* bq1   = (const float*)d_in[14];
    const float* Wk1   = (const float*)d_in[15];
    const float* bk1   = (const float*)d_in[16];
    const float* Wv1   = (const float*)d_in[17];
    const float* bv1   = (const float*)d_in[18];
    const float* We1   = (const float*)d_in[19];
    const float* Ws1   = (const float*)d_in[20];
    const float* bs1   = (const float*)d_in[21];
    const float* Wq2   = (const float*)d_in[22];
    const float* bq2   = (const float*)d_in[23];
    const float* Wk2   = (const float*)d_in[24];
    const float* bk2   = (const float*)d_in[25];
    const float* Wv2   = (const float*)d_in[26];
    const float* bv2   = (const float*)d_in[27];
    const float* We2   = (const float*)d_in[28];
    const float* Ws2   = (const float*)d_in[29];
    const float* bs2   = (const float*)d_in[30];

    float* ws   = (float*)d_ws;
    float* slav = ws;                              // 524288 f region (sl_av)
    float* base = ws + 524288;                     // 524288 f
    float* x0   = base + BB * NN * HH;             // 524288 f
    float* q    = x0 + BB * NN * HH;               // 1048576 f
    float* kreg = q + BB * NN * HD;                // 1048576 f -> khi/klo
    float* vreg = kreg + BB * NN * HD;             // 1048576 f -> vThi/vTlo
    float* skip = vreg + BB * NN * HD;             // 1048576 f
    float* areg = skip + BB * NN * HD;             // 1048576 f -> planes + adjvT + sl_s
    float* x1   = areg + BB * NN * HD;
    float* x2   = x1 + BB * NN * HD;

    // econv prep planes in q region (q first written AFTER econv)
    ushort_t* BhiG = (ushort_t*)q;
    ushort_t* BloG = BhiG + HH * HH;
    float*    W1sW = q + 16384;
    float*    cbW  = q + 16512;
    int*      cnts = (int*)(q + 17024);            // 8192 ints, free q space

    // K / vT planes
    ushort_t* khi  = (ushort_t*)kreg;              // 1048576 ush
    ushort_t* klo  = khi + BB * NN * HD;           // 1048576 ush
    ushort_t* vThi = (ushort_t*)vreg;
    ushort_t* vTlo = vThi + BB * NN * HD;

    // qkvs weight planes + adjvT + sl_s in areg (4 MB):
    // planes 1.5 MB + adjvT 2 MB + sl_s 0.5 MB = 4 MB exactly
    ushort_t* WhA = (ushort_t*)areg;               // 4*256*128 ush
    ushort_t* WlA = WhA + 4 * 256 * HH;
    ushort_t* WhB = WlA + 4 * 256 * HH;            // 4*256*256 ush
    ushort_t* WlB = WhB + 4 * 256 * HD;
    float* adjvT  = areg + 393216;                 // 524288 f, past planes
    uchar_t* sl_s = (uchar_t*)(areg + 917504);     // 524288 uchars, tail

    int fail = 0;
    hipError_t e;
#define CHK(stage) do { e = hipGetLastError(); if (e != hipSuccess && fail == 0) fail = (stage); } while (0)

    k_prep_all<<<2080, 256, 0, stream>>>(
        adj, adjvT, sl_s, slav, cnts,
        nf, et, emb, W1, b1, base, x0,
        Wh, g1, be1, bh, BhiG, BloG, W1sW, cbW,
        Wq1, Wk1, Wv1, Ws1, WhA, WlA,
        Wq2, Wk2, Wv2, Ws2, WhB, WlB);                                               CHK(1);

    k_econv_mfma<<<512, 256, 0, stream>>>(sl_s, slav, cnts, base, W1,
                                          BhiG, BloG, W1sW, cbW, gh, beh, x0);       CHK(2);

    k_qkvs_mfma<HH><<<512, 256, 0, stream>>>(x0, WhA, WlA, bq1, bk1, bv1, bs1,
                                             q, skip, khi, klo, vThi, vTlo,
                                             nullptr);                               CHK(3);
    k_attn_mfma<<<1024, 128, 0, stream>>>(q, khi, klo, vThi, vTlo, adjvT, We1,
                                          skip, x1, nullptr, nullptr);               CHK(4);

    k_qkvs_mfma<HD><<<512, 256, 0, stream>>>(x1, WhB, WlB, bq2, bk2, bv2, bs2,
                                             q, skip, khi, klo, vThi, vTlo,
                                             agent);                                 CHK(5);
    k_attn_mfma<<<128, 128, 0, stream>>>(q, khi, klo, vThi, vTlo, adjvT, We2,
                                         skip, x2, agent, out);                      CHK(6);
#undef CHK

    if (fail != 0)
        k_sent<<<32, 256, 0, stream>>>(out, -(1000.f + 500.f * (float)fail));
}